// Round 9
// baseline (432.897 us; speedup 1.0000x reference)
//
#include <hip/hip_runtime.h>
#include <hip/hip_bf16.h>

typedef unsigned short u16;
typedef __attribute__((ext_vector_type(8))) short short8;
typedef __attribute__((ext_vector_type(4))) float floatx4;

#define B_ 16
#define S_ 2048
#define NNODE 257
#define E_ 4096
#define ETR_ 768
#define H_ 512
#define D_ 528
#define KPAD 544          // K padded to a BK multiple for MFMA GEMMs
#define NC 3
#define NROW (B_*NNODE)   // 4112
#define DD (D_*D_)

#define BM 128
#define BN 128
#define BK 32

__device__ inline u16 f2b(float x) {
    __hip_bfloat16 h = __float2bfloat16(x);
    return *(u16*)&h;
}
__device__ inline float b2f(u16 u) {
    return __uint_as_float(((unsigned)u) << 16);
}

// async global->LDS, 16B per lane (m97 structure). LDS dest must be linear:
// HW writes wave-uniform base + lane*16.
__device__ inline void gll16(const u16* g, u16* l) {
    __builtin_amdgcn_global_load_lds(
        (const __attribute__((address_space(1))) void*)g,
        (__attribute__((address_space(3))) void*)l,
        16, 0, 0);
}

__device__ inline int clampi(int v, int hi) { return v < hi ? v : hi; }

__global__ void cvt_bf16(const float* __restrict__ in, u16* __restrict__ out, int n4)
{
    const int i = blockIdx.x * 256 + threadIdx.x;
    if (i < n4) {
        const float4 f = ((const float4*)in)[i];
        ushort4 o;
        o.x = f2b(f.x); o.y = f2b(f.y); o.z = f2b(f.z); o.w = f2b(f.w);
        ((ushort4*)out)[i] = o;
    }
}

// in f32 [R][C] (z-batched) -> out bf16 [C][R] with out pitch opitch (>= R)
__global__ void transpose_cvt(const float* __restrict__ in, u16* __restrict__ out,
                              int R, int Cc, size_t instride, size_t outstride,
                              int opitch)
{
    __shared__ float t[32][33];
    const int z = blockIdx.z;
    const int tx = threadIdx.x & 31, ty = threadIdx.x >> 5;  // 32 x 8
    const int c0 = blockIdx.x * 32, r0 = blockIdx.y * 32;
    const float* ip = in + z * instride;
    u16* op = out + z * outstride;
#pragma unroll
    for (int i = 0; i < 4; i++) {
        const int r = r0 + ty + i * 8, c = c0 + tx;
        if (r < R && c < Cc) t[ty + i * 8][tx] = ip[(size_t)r * Cc + c];
    }
    __syncthreads();
#pragma unroll
    for (int i = 0; i < 4; i++) {
        const int c = c0 + ty + i * 8, r = r0 + tx;
        if (c < Cc && r < R) op[(size_t)c * opitch + r] = f2b(t[tx][ty + i * 8]);
    }
}

// ---------------------------------------------------------------------------
// bf16 MFMA GEMM, m97 structure: 128x128 tile, BK=32, linear 16KB LDS,
// global_load_lds width-16 staging BOTH operands, 2 barriers per K-step.
// LDS chunk-swizzle (rule #21): gll16 dest stays linear; the global SOURCE
// chunk is permuted (slot c holds chunk c ^ ((row>>1)&3)) and the ds_read
// applies the same XOR -> 8-way bank conflict becomes 2-way (free).
// A[M][K], Wt[N][K] bf16 (row pitch K, K % 32 == 0), z-batched.
// SWZ: XCD-locality remap (gridDim.x==4). OB16: bf16 output.
// Epilogue: C = acc*scale + bias[z][n]; row pitch cpitch, z-stride cstride.
// ---------------------------------------------------------------------------
template<int SWZ, int OB16>
__global__ __launch_bounds__(256)
void gemm_mfma(const u16* __restrict__ A, const u16* __restrict__ Wt,
               const float* __restrict__ bias_base, size_t bias_stride,
               void* __restrict__ Cv, int M, int N, int K, float scale,
               size_t astride, size_t wstride, size_t cstride, int cpitch)
{
    __shared__ u16 SS[8192];  // A tile [128][32] @ 0, B tile [128][32] @ 4096 (u16 units)
    const int tid = threadIdx.x;
    const int wave = tid >> 6, lane = tid & 63;
    const int quad = lane >> 4, l16 = lane & 15;
    const int z = blockIdx.z;
    int bx = blockIdx.x, by = blockIdx.y;
    if (SWZ) {   // gridDim.x==4: keep the 4 col-blocks of a row-block on one XCD
        const int lin = blockIdx.x + (blockIdx.y << 2);
        bx = (lin >> 3) & 3;
        by = (lin & 7) + ((lin >> 5) << 3);
    }
    const int m0 = by * BM, n0 = bx * BN;

    floatx4 acc[2][8];
#pragma unroll
    for (int t = 0; t < 2; t++)
#pragma unroll
        for (int u = 0; u < 8; u++)
#pragma unroll
            for (int r = 0; r < 4; r++) acc[t][u][r] = 0.f;

    // staging map: LDS slot (tid&3) of row (tid>>2) receives GLOBAL chunk
    // (tid&3) ^ ((row>>1)&3) -- the bank-conflict swizzle, applied at the source.
    const int srow = tid >> 2;                                   // 0..63
    const int scol = (((tid & 3) ^ ((srow >> 1) & 3))) * 8;      // swizzled chunk
    const u16* aP0 = A + z * astride + (size_t)clampi(m0 + srow,      M - 1) * K + scol;
    const u16* aP1 = A + z * astride + (size_t)clampi(m0 + 64 + srow, M - 1) * K + scol;
    const u16* bP0 = Wt + z * wstride + (size_t)clampi(n0 + srow,      N - 1) * K + scol;
    const u16* bP1 = Wt + z * wstride + (size_t)clampi(n0 + 64 + srow, N - 1) * K + scol;
    u16* const ls = &SS[0] + wave * 512;   // per-wave linear LDS base (u16 units)

    // read-side swizzle term: all fragment rows reduce to sw = (l16>>1)&3
    const int sw8 = ((l16 >> 1) & 3) * 8;

    for (int k0 = 0; k0 < K; k0 += BK) {
        gll16(aP0 + k0, ls);            // A rows   0..63
        gll16(aP1 + k0, ls + 2048);     // A rows  64..127
        gll16(bP0 + k0, ls + 4096);     // B rows   0..63
        gll16(bP1 + k0, ls + 6144);     // B rows  64..127
        __syncthreads();                // compiler drains vmcnt before barrier
        short8 af[2], bfv[8];
        af[0] = *(const short8*)&SS[(wave * 32 + l16) * 32 + ((quad * 8) ^ sw8)];
        af[1] = *(const short8*)&SS[(wave * 32 + 16 + l16) * 32 + ((quad * 8) ^ sw8)];
#pragma unroll
        for (int u = 0; u < 8; u++)
            bfv[u] = *(const short8*)&SS[4096 + (u * 16 + l16) * 32 + ((quad * 8) ^ sw8)];
#pragma unroll
        for (int t = 0; t < 2; t++)
#pragma unroll
            for (int u = 0; u < 8; u++)
                acc[t][u] = __builtin_amdgcn_mfma_f32_16x16x32_bf16(af[t], bfv[u], acc[t][u], 0, 0, 0);
        __syncthreads();
    }

    const float* bias = bias_base ? (bias_base + z * bias_stride) : nullptr;
#pragma unroll
    for (int t = 0; t < 2; t++) {
#pragma unroll
        for (int r = 0; r < 4; r++) {
            const int m = m0 + wave * 32 + t * 16 + quad * 4 + r;
            if (m >= M) continue;
#pragma unroll
            for (int u = 0; u < 8; u++) {
                const int n = n0 + u * 16 + l16;
                if (n < N) {
                    const float v = acc[t][u][r] * scale + (bias ? bias[n] : 0.f);
                    if (OB16) {
                        u16* Cb = (u16*)Cv;
                        Cb[z * cstride + (size_t)m * cpitch + n] = f2b(v);
                    } else {
                        float* Cf = (float*)Cv;
                        Cf[z * cstride + (size_t)m * cpitch + n] = v;
                    }
                }
            }
        }
    }
}

// ---------------------------------------------------------------------------
// fp32 64x64 GEMM (fallback path only)
// ---------------------------------------------------------------------------
template<int MODE>
__global__ __launch_bounds__(256)
void gemm64(const float* __restrict__ A, const float* __restrict__ W,
            const float* __restrict__ bias, float* __restrict__ C,
            int M, int N, int K, float scale,
            const int* __restrict__ segidx, float* __restrict__ segout)
{
    __shared__ float Asl[16][68];
    __shared__ float Bsl[16][64];
    const int tid = threadIdx.x;
    const int tx = tid & 15, ty = tid >> 4;
    const int m0 = blockIdx.y * 64, n0 = blockIdx.x * 64;
    const int arow = tid >> 2, acol = (tid & 3) * 4;
    const int brow = tid >> 4, bcol = (tid & 15) * 4;

    float acc[4][4];
#pragma unroll
    for (int i = 0; i < 4; i++)
#pragma unroll
        for (int j = 0; j < 4; j++) acc[i][j] = 0.f;

    for (int kk = 0; kk < K; kk += 16) {
        float4 av = make_float4(0.f, 0.f, 0.f, 0.f);
        if (m0 + arow < M) av = *(const float4*)(A + (size_t)(m0 + arow) * K + kk + acol);
        Asl[acol + 0][arow] = av.x; Asl[acol + 1][arow] = av.y;
        Asl[acol + 2][arow] = av.z; Asl[acol + 3][arow] = av.w;
        float4 bv = make_float4(0.f, 0.f, 0.f, 0.f);
        if (n0 + bcol < N) bv = *(const float4*)(W + (size_t)(kk + brow) * N + n0 + bcol);
        *(float4*)&Bsl[brow][bcol] = bv;
        __syncthreads();
#pragma unroll
        for (int k = 0; k < 16; k++) {
            const float4 a = *(const float4*)&Asl[k][ty * 4];
            const float4 b = *(const float4*)&Bsl[k][tx * 4];
            const float af[4] = { a.x, a.y, a.z, a.w };
            const float bfv[4] = { b.x, b.y, b.z, b.w };
#pragma unroll
            for (int i = 0; i < 4; i++)
#pragma unroll
                for (int j = 0; j < 4; j++) acc[i][j] += af[i] * bfv[j];
        }
        __syncthreads();
    }

#pragma unroll
    for (int i = 0; i < 4; i++) {
        const int m = m0 + ty * 4 + i;
        if (m >= M) continue;
        if (MODE == 1) {
            const int bb = m >> 11;
            const int idx = segidx[m];
            float* const srow = segout + (((size_t)bb * NNODE + idx) << 9);
#pragma unroll
            for (int j = 0; j < 4; j++) {
                const int n = n0 + tx * 4 + j;
                const float v = acc[i][j] + (bias ? bias[n] : 0.f);
                atomicMax(((int*)srow) + n, __float_as_int(v));
            }
        } else {
#pragma unroll
            for (int j = 0; j < 4; j++) {
                const int n = n0 + tx * 4 + j;
                if (n < N) {
                    const float v = acc[i][j] * scale + (bias ? bias[n] : 0.f);
                    C[(size_t)m * N + n] = v;
                }
            }
        }
    }
}

// ---------------------------------------------------------------------------
// Merged CSR build: (A) row buckets over (batch,node) for segment ownership,
// (B) class CSR over (class,dst) + packed {src, coef}. One block per batch.
// ---------------------------------------------------------------------------
__global__ void csr_all(const int* __restrict__ ent_indices,
                        int* __restrict__ rptr, int* __restrict__ rlist,
                        const int* __restrict__ edge_index, const int* __restrict__ edge_attr,
                        float* __restrict__ degf, int* __restrict__ csr_ptr,
                        int2* __restrict__ csr_sc)
{
    __shared__ int cnt[NC * NNODE];
    __shared__ float dinvl[NC * NNODE];
    const int b = blockIdx.x;
    const int tid = threadIdx.x;

    // ---- phase A: row buckets ----
    const int* idx = ent_indices + (size_t)b * S_;
    for (int i = tid; i < NNODE; i += 256) cnt[i] = 0;
    __syncthreads();
    for (int r = tid; r < S_; r += 256) atomicAdd(&cnt[idx[r]], 1);
    __syncthreads();
    if (tid == 0) {
        int run = 0;
        for (int i = 0; i < NNODE; i++) { const int c = cnt[i]; cnt[i] = run; run += c; }
    }
    __syncthreads();
    for (int i = tid; i < NNODE; i += 256) rptr[b * (NNODE + 1) + i] = cnt[i];
    if (tid == 0) rptr[b * (NNODE + 1) + NNODE] = S_;
    __syncthreads();
    for (int r = tid; r < S_; r += 256) {
        const int pos = atomicAdd(&cnt[idx[r]], 1);
        rlist[(size_t)b * S_ + pos] = r;
    }
    __syncthreads();

    // ---- phase B: class CSR ----
    const int* src = edge_index + (size_t)b * 2 * E_;
    const int* dst = src + E_;
    const int* attr = edge_attr + (size_t)b * E_;
    for (int i = tid; i < NC * NNODE; i += 256) cnt[i] = 0;
    __syncthreads();
    for (int e = tid; e < E_; e += 256) atomicAdd(&cnt[attr[e] * NNODE + dst[e]], 1);
    __syncthreads();
    for (int i = tid; i < NC * NNODE; i += 256) {
        const float d = (float)cnt[i] + 1.0f;
        degf[(size_t)b * NC * NNODE + i] = d;
        dinvl[i] = rsqrtf(d);
    }
    __syncthreads();
    if (tid == 0) {
        int run = 0;
        for (int i = 0; i < NC * NNODE; i++) { const int c = cnt[i]; cnt[i] = run; run += c; }
    }
    __syncthreads();
    for (int i = tid; i < NC * NNODE; i += 256) csr_ptr[(size_t)b * NC * NNODE + i] = cnt[i];
    __syncthreads();
    for (int e = tid; e < E_; e += 256) {
        const int a = attr[e], d = dst[e], s = src[e];
        const int pos = atomicAdd(&cnt[a * NNODE + d], 1);
        const float cf = dinvl[a * NNODE + s] * dinvl[a * NNODE + d];
        csr_sc[(size_t)b * E_ + pos] = make_int2(s, __float_as_int(cf));
    }
}

// ---------------------------------------------------------------------------
// Fused segment-max (bf16 redC) + x0 build. One block owns one (batch,node):
// no atomics. x0b row = [label 16 | relu(max+bias) 512 | pad 16] bf16, pitch 544.
// ---------------------------------------------------------------------------
__global__ __launch_bounds__(256)
void segmax_x0(const u16* __restrict__ redC, const int* __restrict__ rptr,
               const int* __restrict__ rlist, const float* __restrict__ b_red,
               const int* __restrict__ ent_labels, const float* __restrict__ tbl,
               u16* __restrict__ x0b)
{
    const int bn = blockIdx.x;           // b*NNODE + n
    const int b = bn / NNODE, n = bn % NNODE;
    const int tid = threadIdx.x;
    const int c0 = tid * 2;              // two adjacent bf16 cols per thread
    const int start = rptr[b * (NNODE + 1) + n];
    const int end   = (n == 0) ? start : rptr[b * (NNODE + 1) + n + 1];
    float m0 = -INFINITY, m1 = -INFINITY;
    const int* rl = rlist + (size_t)b * S_;
    for (int i = start; i < end; i++) {
        const u16* row = redC + ((size_t)b * S_ + rl[i]) * H_;
        const unsigned v = *(const unsigned*)(row + c0);
        m0 = fmaxf(m0, __uint_as_float((v & 0xffffu) << 16));
        m1 = fmaxf(m1, __uint_as_float(v & 0xffff0000u));
    }
    float h0, h1;
    if (n == 0) { h0 = 0.f; h1 = 0.f; }
    else {
        h0 = fmaxf(m0 + b_red[c0], 0.f);
        h1 = fmaxf(m1 + b_red[c0 + 1], 0.f);
    }
    u16* orow = x0b + (size_t)bn * KPAD;
    *(unsigned*)(orow + 16 + c0) = (unsigned)f2b(h0) | ((unsigned)f2b(h1) << 16);
    if (tid < 16) {
        float v;
        if (n == 0) v = tbl[tid];
        else {
            const int lab = ent_labels[b * (NNODE - 1) + (n - 1)];
            v = (lab != 0) ? tbl[lab * 16 + tid] : 0.f;
        }
        orow[tid] = f2b(v);
    } else if (tid < 32) {
        orow[512 + tid] = 0;             // K-pad cols 528..543
    }
}

template<int OUTB>
__global__ void build_x0(const float* __restrict__ seg, const int* __restrict__ ent_labels,
                         const float* __restrict__ tbl, float* __restrict__ x0f,
                         u16* __restrict__ x0b)
{
    const int bn = blockIdx.x;
    const int b = bn / NNODE, n = bn % NNODE;
    const int CMAX = OUTB ? KPAD : D_;
    for (int col = threadIdx.x; col < CMAX; col += blockDim.x) {
        float v;
        if (col >= D_) {
            v = 0.f;
        } else if (col < 16) {
            if (n == 0) v = tbl[col];
            else {
                const int lab = ent_labels[b * (NNODE - 1) + (n - 1)];
                v = (lab != 0) ? tbl[lab * 16 + col] : 0.f;
            }
        } else {
            v = (n == 0) ? 0.f : seg[(((size_t)b * NNODE + n) << 9) + (col - 16)];
        }
        if (OUTB) x0b[(size_t)bn * KPAD + col] = f2b(v);
        else      x0f[(size_t)bn * D_ + col] = v;
    }
}

// OUT: 0 bf16 write (z-strided, pitch KPAD, zero K-pad); 1 fp32 +=;
//      2 fp32 = (z-strided via ostride, pitch D_)
template<int OUT>
__global__ __launch_bounds__(256)
void gcn_gather(const float* __restrict__ h, size_t hstride,
                const float* __restrict__ degf,
                const int* __restrict__ csr_ptr, const int2* __restrict__ csr_sc,
                const float* __restrict__ bias_base, size_t bias_stride,
                float* __restrict__ outf, u16* __restrict__ outb, size_t ostride,
                int cls0)
{
    const int bn = blockIdx.x;
    const int cls = cls0 + blockIdx.y;
    const int b = bn / NNODE, n = bn % NNODE;
    const int tid = threadIdx.x;
    const int base = b * NC * NNODE + cls * NNODE + n;
    const float d = degf[base];
    const int start = csr_ptr[base];
    const int cnt = (int)d - 1;
    const float inv = 1.0f / d;
    const float* hp = h + blockIdx.y * hstride;
    const float* bias = bias_base + cls * bias_stride;
    const float* hrow = hp + (size_t)bn * D_;
    const int c0 = tid, c1 = tid + 256, c2 = tid + 512;
    float a0 = hrow[c0] * inv + bias[c0];
    float a1 = hrow[c1] * inv + bias[c1];
    float a2 = (c2 < D_) ? hrow[c2] * inv + bias[c2] : 0.f;
    const int2* scp = csr_sc + (size_t)b * E_ + start;
    int2 sc = (cnt > 0) ? scp[0] : make_int2(0, 0);
    for (int i = 0; i < cnt; i++) {
        const int2 cur = sc;
        if (i + 1 < cnt) sc = scp[i + 1];     // prefetch: break dependent chain
        const float cf = __int_as_float(cur.y);
        const float* hs = hp + ((size_t)b * NNODE + cur.x) * D_;
        a0 += cf * hs[c0];
        a1 += cf * hs[c1];
        if (c2 < D_) a2 += cf * hs[c2];
    }
    if (OUT == 0) {
        u16* orow = outb + blockIdx.y * ostride + (size_t)bn * KPAD;
        orow[c0] = f2b(a0); orow[c1] = f2b(a1); if (c2 < D_) orow[c2] = f2b(a2);
        if (tid >= 16 && tid < 32) orow[512 + tid] = 0;   // zero K-pad 528..543
    } else if (OUT == 1) {
        float* orow = outf + (size_t)bn * D_;
        orow[c0] += a0; orow[c1] += a1; if (c2 < D_) orow[c2] += a2;
    } else {
        float* orow = outf + blockIdx.y * ostride + (size_t)bn * D_;
        orow[c0] = a0; orow[c1] = a1; if (c2 < D_) orow[c2] = a2;
    }
}

__global__ void rowdot3(const float* __restrict__ x, const float* __restrict__ w,
                        float* __restrict__ out)
{
    const int row = blockIdx.x;
    const int lane = threadIdx.x;
    float a0 = 0.f, a1 = 0.f, a2 = 0.f;
    for (int d = lane; d < D_; d += 64) {
        const float xv = x[(size_t)row * D_ + d];
        a0 += xv * w[d * 3 + 0];
        a1 += xv * w[d * 3 + 1];
        a2 += xv * w[d * 3 + 2];
    }
#pragma unroll
    for (int off = 32; off > 0; off >>= 1) {
        a0 += __shfl_down(a0, off, 64);
        a1 += __shfl_down(a1, off, 64);
        a2 += __shfl_down(a2, off, 64);
    }
    if (lane == 0) {
        out[(size_t)row * 3 + 0] = a0;
        out[(size_t)row * 3 + 1] = a1;
        out[(size_t)row * 3 + 2] = a2;
    }
}

// one kernel: Whw = W_head@W_out, Wtw = W_tail@W_out, bias6 = {b_head,b_tail}@W_out
__global__ void prep_heads(const float* __restrict__ W_head, const float* __restrict__ W_tail,
                           const float* __restrict__ b_head, const float* __restrict__ b_tail,
                           const float* __restrict__ W_out,
                           float* __restrict__ Whw, float* __restrict__ Wtw,
                           float* __restrict__ bias6)
{
    const int r = blockIdx.x;            // 0..2*D_+1
    const int lane = threadIdx.x;
    const float* x; float* o;
    if (r < D_)            { x = W_head + (size_t)r * D_;        o = Whw + (size_t)r * 3; }
    else if (r < 2 * D_)   { x = W_tail + (size_t)(r - D_) * D_; o = Wtw + (size_t)(r - D_) * 3; }
    else if (r == 2 * D_)  { x = b_head;                         o = bias6; }
    else                   { x = b_tail;                         o = bias6 + 3; }
    float a0 = 0.f, a1 = 0.f, a2 = 0.f;
    for (int d = lane; d < D_; d += 64) {
        const float xv = x[d];
        a0 += xv * W_out[d * 3 + 0];
        a1 += xv * W_out[d * 3 + 1];
        a2 += xv * W_out[d * 3 + 2];
    }
#pragma unroll
    for (int off = 32; off > 0; off >>= 1) {
        a0 += __shfl_down(a0, off, 64);
        a1 += __shfl_down(a1, off, 64);
        a2 += __shfl_down(a2, off, 64);
    }
    if (lane == 0) { o[0] = a0; o[1] = a1; o[2] = a2; }
}

// hw/tw from 3 class planes: x = (p0+p1+p2)/3; 4 rows per block (1 wave each)
__global__ __launch_bounds__(256)
void rowdot6(const float* __restrict__ x3, size_t zstride,
             const float* __restrict__ Whw, const float* __restrict__ Wtw,
             const float* __restrict__ bias6,
             float* __restrict__ hw, float* __restrict__ tw)
{
    const int row = blockIdx.x * 4 + (threadIdx.x >> 6);
    const int lane = threadIdx.x & 63;
    const float* p0 = x3 + (size_t)row * D_;
    const float* p1 = p0 + zstride;
    const float* p2 = p1 + zstride;
    float h0 = 0.f, h1 = 0.f, h2 = 0.f, t0 = 0.f, t1 = 0.f, t2 = 0.f;
    for (int d = lane; d < D_; d += 64) {
        const float xv = (p0[d] + p1[d] + p2[d]) * (1.f / 3.f);
        h0 += xv * Whw[d * 3 + 0]; h1 += xv * Whw[d * 3 + 1]; h2 += xv * Whw[d * 3 + 2];
        t0 += xv * Wtw[d * 3 + 0]; t1 += xv * Wtw[d * 3 + 1]; t2 += xv * Wtw[d * 3 + 2];
    }
#pragma unroll
    for (int off = 32; off > 0; off >>= 1) {
        h0 += __shfl_down(h0, off, 64); h1 += __shfl_down(h1, off, 64); h2 += __shfl_down(h2, off, 64);
        t0 += __shfl_down(t0, off, 64); t1 += __shfl_down(t1, off, 64); t2 += __shfl_down(t2, off, 64);
    }
    if (lane == 0) {
        hw[(size_t)row * 3 + 0] = h0 + bias6[0];
        hw[(size_t)row * 3 + 1] = h1 + bias6[1];
        hw[(size_t)row * 3 + 2] = h2 + bias6[2];
        tw[(size_t)row * 3 + 0] = t0 + bias6[3];
        tw[(size_t)row * 3 + 1] = t1 + bias6[4];
        tw[(size_t)row * 3 + 2] = t2 + bias6[5];
    }
}

__global__ __launch_bounds__(256)
void final_logits(const float* __restrict__ hw, const float* __restrict__ tw,
                  const int* __restrict__ cands, const float* __restrict__ b_out,
                  float* __restrict__ out)
{
    const int bi = blockIdx.x;
    const int b = bi / NNODE;
    const int j = threadIdx.x;
    const float h0 = hw[bi * 3 + 0], h1 = hw[bi * 3 + 1], h2 = hw[bi * 3 + 2];
    const int tj = b * NNODE + 1 + j;
    const float t0 = tw[tj * 3 + 0], t1 = tw[tj * 3 + 1], t2 = tw[tj * 3 + 2];
    const float m = (cands[(size_t)bi * NNODE + 1 + j] != 0) ? 1.f : 0.f;
    const float bo0 = b_out[0], bo1 = b_out[1], bo2 = b_out[2];
    const size_t o = ((size_t)bi * 256 + j) * 3;
    out[o + 0] = (h0 + t0) * m + bo0;
    out[o + 1] = (h1 + t1) * m + bo1;
    out[o + 2] = (h2 + t2) * m + bo2;
}

extern "C" void kernel_launch(void* const* d_in, const int* in_sizes, int n_in,
                              void* d_out, int out_size, void* d_ws, size_t ws_size,
                              hipStream_t stream)
{
    const float* emb       = (const float*)d_in[0];
    const int* ent_indices = (const int*)d_in[1];
    const int* ent_labels  = (const int*)d_in[2];
    const int* edge_index  = (const int*)d_in[3];
    const int* edge_attr   = (const int*)d_in[4];
    const int* cands       = (const int*)d_in[5];
    const float* W_red     = (const float*)d_in[6];
    const float* b_red     = (const float*)d_in[7];
    const float* tbl       = (const float*)d_in[8];
    const float* W_gcn     = (const float*)d_in[9];
    const float* b_gcn     = (const float*)d_in[10];
    const float* W_head    = (const float*)d_in[11];
    const float* b_head    = (const float*)d_in[12];
    const float* W_tail    = (const float*)d_in[13];
    const float* b_tail    = (const float*)d_in[14];
    const float* W_out     = (const float*)d_in[15];
    const float* b_out     = (const float*)d_in[16];

    char* ws = (char*)d_ws;
    size_t off = 0;
    auto alloc = [&](size_t nbytes) -> char* {
        char* p = ws + off; off = (off + nbytes + 255) & ~(size_t)255; return p;
    };
    const size_t ROWB  = (size_t)NROW * D_ * sizeof(float);
    const size_t RD    = (size_t)NROW * D_;         // f32 plane stride (pitch 528)
    const size_t RD2   = (size_t)NROW * KPAD;       // bf16 plane stride (pitch 544)
    const size_t WGZ   = (size_t)2 * D_ * KPAD;     // wgcnT z-stride (2 layers)

    // region R0: emb_bf (phase 1), then hbuf[3 planes f32] + x1b[3 planes bf16]
    char* R0      = alloc((size_t)B_ * S_ * ETR_ * sizeof(u16)); // 50.3 MB
    u16*  emb_bf  = (u16*)R0;
    float* hbuf   = (float*)R0;                                  // [3][NROW][528] f32 = 26.05 MB
    u16*  x1b     = (u16*)(R0 + 3 * ROWB);                       // [3][NROW][544] bf16 = 13.4 MB
    // region R1: redC bf16 (phase 1), then result3 [3][NROW][528] f32 (epilogue)
    char* R1      = alloc((size_t)B_ * S_ * H_ * sizeof(u16));   // 33.6 MB
    u16*  redC    = (u16*)R1;
    float* result3 = (float*)R1;                                 // 26.1 MB fits
    int*  rptr    = (int*)alloc((size_t)B_ * (NNODE + 1) * 4);
    int*  rlist   = (int*)alloc((size_t)B_ * S_ * 4);
    u16*  x0b     = (u16*)alloc((size_t)NROW * KPAD * sizeof(u16));
    u16*  wredT   = (u16*)alloc((size_t)H_ * ETR_ * sizeof(u16));    // [512][768]
    u16*  wgcnT   = (u16*)alloc((size_t)NC * WGZ * sizeof(u16));     // [3][2][528][544]
    float* Whw    = (float*)alloc((size_t)D_ * 3 * 4);
    float* Wtw    = (float*)alloc((size_t)D_ * 3 * 4);
    float* bias6  = (float*)alloc(6 * 4);
    float* degf   = (float*)alloc((size_t)B_ * NC * NNODE * 4);
    float* hwp    = (float*)alloc((size_t)NROW * 3 * 4);
    float* twp    = (float*)alloc((size_t)NROW * 3 * 4);
    int* csr_ptr  = (int*)alloc((size_t)B_ * NC * NNODE * 4);
    int2* csr_sc  = (int2*)alloc((size_t)B_ * E_ * 8);
    const bool fast = (ws_size >= off);

    if (fast) {
        const int n4e = (B_ * S_ * ETR_) / 4;
        cvt_bf16<<<(n4e + 255) / 256, 256, 0, stream>>>(emb, emb_bf, n4e);
        transpose_cvt<<<dim3(16, 24, 1), 256, 0, stream>>>(W_red, wredT, ETR_, H_, 0, 0, ETR_);
        hipMemsetAsync(wgcnT, 0, (size_t)NC * WGZ * sizeof(u16), stream);  // K-pad zeros
        transpose_cvt<<<dim3(17, 17, 6), 256, 0, stream>>>(W_gcn, wgcnT, D_, D_, DD, (size_t)D_ * KPAD, KPAD);

        // fused head/tail weights (single launch)
        prep_heads<<<2 * D_ + 2, 64, 0, stream>>>(W_head, W_tail, b_head, b_tail, W_out,
                                                  Whw, Wtw, bias6);

        // merged row-bucket CSR + class CSR (one launch)
        csr_all<<<B_, 256, 0, stream>>>(ent_indices, rptr, rlist,
                                        edge_index, edge_attr, degf, csr_ptr, csr_sc);

        // 1) reduction GEMM (bf16 gll16 both sides) -> bf16 redC
        gemm_mfma<1, 1><<<dim3(H_ / BN, (B_ * S_) / BM, 1), 256, 0, stream>>>(
            emb_bf, wredT, nullptr, 0, redC, B_ * S_, H_, ETR_, 1.f, 0, 0, 0, H_);
        // 2) fused exclusive-owner segment max + x0 build (zero atomics)
        segmax_x0<<<B_ * NNODE, 256, 0, stream>>>(redC, rptr, rlist, b_red,
                                                  ent_labels, tbl, x0b);

        // 3) GCN layer 1: GEMM on shared x0 plane (astride 0, L2-hot A), f32 h out
        dim3 gmm((D_ + BN - 1) / BN, (NROW + BM - 1) / BM, NC);   // 5 x 33 x 3
        gemm_mfma<0, 0><<<gmm, 256, 0, stream>>>(
            x0b, wgcnT, nullptr, 0, hbuf, NROW, D_, KPAD, 1.f, 0, WGZ, RD, D_);
        gcn_gather<0><<<dim3(NROW, NC), 256, 0, stream>>>(
            hbuf, RD, degf, csr_ptr, csr_sc, b_gcn, (size_t)2 * D_,
            nullptr, x1b, RD2, 0);
        // 4) GCN layer 2
        gemm_mfma<0, 0><<<gmm, 256, 0, stream>>>(
            x1b, wgcnT + (size_t)D_ * KPAD, nullptr, 0, hbuf, NROW, D_, KPAD, 1.f,
            RD2, WGZ, RD, D_);
        gcn_gather<2><<<dim3(NROW, NC), 256, 0, stream>>>(
            hbuf, RD, degf, csr_ptr, csr_sc, b_gcn + D_, (size_t)2 * D_,
            result3, nullptr, RD, 0);

        // 5) fused epilogue: sum 3 planes inside rowdot6 (no atomics, no memset)
        rowdot6<<<NROW / 4, 256, 0, stream>>>(result3, RD, Whw, Wtw, bias6, hwp, twp);
        final_logits<<<NROW, 256, 0, stream>>>(hwp, twp, cands, b_out, (float*)d_out);
        return;
    }

    // -------- fallback: proven fp32 pipeline --------
    off = 0;
    float* bufA = (float*)alloc(ROWB);
    float* bufB = (float*)alloc(ROWB);
    float* bufC = (float*)alloc(ROWB);
    float* bufD = (float*)alloc(ROWB);
    degf = (float*)alloc((size_t)B_ * NC * NNODE * 4);
    hwp  = (float*)alloc((size_t)NROW * 3 * 4);
    twp  = (float*)alloc((size_t)NROW * 3 * 4);
    csr_ptr = (int*)alloc((size_t)B_ * NC * NNODE * 4);
    csr_sc  = (int2*)alloc((size_t)B_ * E_ * 8);
    int* rptr2  = (int*)alloc((size_t)B_ * (NNODE + 1) * 4);
    int* rlist2 = (int*)alloc((size_t)B_ * S_ * 4);

    hipMemsetAsync(bufA, 0, (size_t)B_ * NNODE * H_ * 4, stream);
    hipMemsetAsync(bufD, 0, ROWB, stream);
    gemm64<1><<<dim3(H_ / 64, (B_ * S_) / 64), 256, 0, stream>>>(
        emb, W_red, b_red, nullptr, B_ * S_, H_, ETR_, 1.f, ent_indices, bufA);
    build_x0<0><<<NROW, 256, 0, stream>>>(bufA, ent_labels, tbl, bufB, nullptr);
    csr_all<<<B_, 256, 0, stream>>>(ent_indices, rptr2, rlist2,
                                    edge_index, edge_attr, degf, csr_ptr, csr_sc);
    dim3 gridG((D_ + 63) / 64, (NROW + 63) / 64);
    for (int c = 0; c < NC; c++) {
        gemm64<0><<<gridG, 256, 0, stream>>>(bufB, W_gcn + (size_t)(c * 2 + 0) * DD,
            nullptr, bufA, NROW, D_, D_, 1.f, nullptr, nullptr);
        gcn_gather<2><<<dim3(NROW, 1), 256, 0, stream>>>(bufA, 0, degf, csr_ptr, csr_sc,
            b_gcn, (size_t)2 * D_, bufC, nullptr, 0, c);
        gemm64<0><<<gridG, 256, 0, stream>>>(bufC, W_gcn + (size_t)(c * 2 + 1) * DD,
            nullptr, bufA, NROW, D_, D_, 1.f, nullptr, nullptr);
        gcn_gather<1><<<dim3(NROW, 1), 256, 0, stream>>>(bufA, 0, degf, csr_ptr, csr_sc,
            b_gcn + D_, (size_t)2 * D_, bufD, nullptr, 0, c);
    }
    gemm64<0><<<gridG, 256, 0, stream>>>(bufD, W_head, b_head, bufB,
        NROW, D_, D_, 1.f / 3.f, nullptr, nullptr);
    gemm64<0><<<gridG, 256, 0, stream>>>(bufD, W_tail, b_tail, bufC,
        NROW, D_, D_, 1.f / 3.f, nullptr, nullptr);
    rowdot3<<<NROW, 64, 0, stream>>>(bufB, W_out, hwp);
    rowdot3<<<NROW, 64, 0, stream>>>(bufC, W_out, twp);
    final_logits<<<NROW, 256, 0, stream>>>(hwp, twp, cands, b_out, (float*)d_out);
}

// Round 10
// 423.250 us; speedup vs baseline: 1.0228x; 1.0228x over previous
//
#include <hip/hip_runtime.h>
#include <hip/hip_bf16.h>

typedef unsigned short u16;
typedef __attribute__((ext_vector_type(8))) short short8;
typedef __attribute__((ext_vector_type(4))) float floatx4;

#define B_ 16
#define S_ 2048
#define NNODE 257
#define E_ 4096
#define ETR_ 768
#define H_ 512
#define D_ 528
#define KPAD 544          // K padded to a BK multiple for MFMA GEMMs
#define NC 3
#define NROW (B_*NNODE)   // 4112
#define DD (D_*D_)

#define BM 128
#define BN 128
#define BK 32

__device__ inline u16 f2b(float x) {
    __hip_bfloat16 h = __float2bfloat16(x);
    return *(u16*)&h;
}
__device__ inline float b2f(u16 u) {
    return __uint_as_float(((unsigned)u) << 16);
}

// async global->LDS, 16B per lane (m97 structure). LDS dest must be linear:
// HW writes wave-uniform base + lane*16.
__device__ inline void gll16(const u16* g, u16* l) {
    __builtin_amdgcn_global_load_lds(
        (const __attribute__((address_space(1))) void*)g,
        (__attribute__((address_space(3))) void*)l,
        16, 0, 0);
}

__device__ inline int clampi(int v, int hi) { return v < hi ? v : hi; }

__global__ void cvt_bf16(const float* __restrict__ in, u16* __restrict__ out, int n4)
{
    const int i = blockIdx.x * 256 + threadIdx.x;
    if (i < n4) {
        const float4 f = ((const float4*)in)[i];
        ushort4 o;
        o.x = f2b(f.x); o.y = f2b(f.y); o.z = f2b(f.z); o.w = f2b(f.w);
        ((ushort4*)out)[i] = o;
    }
}

// in f32 [R][C] (z-batched) -> out bf16 [C][R] with out pitch opitch (>= R)
__global__ void transpose_cvt(const float* __restrict__ in, u16* __restrict__ out,
                              int R, int Cc, size_t instride, size_t outstride,
                              int opitch)
{
    __shared__ float t[32][33];
    const int z = blockIdx.z;
    const int tx = threadIdx.x & 31, ty = threadIdx.x >> 5;  // 32 x 8
    const int c0 = blockIdx.x * 32, r0 = blockIdx.y * 32;
    const float* ip = in + z * instride;
    u16* op = out + z * outstride;
#pragma unroll
    for (int i = 0; i < 4; i++) {
        const int r = r0 + ty + i * 8, c = c0 + tx;
        if (r < R && c < Cc) t[ty + i * 8][tx] = ip[(size_t)r * Cc + c];
    }
    __syncthreads();
#pragma unroll
    for (int i = 0; i < 4; i++) {
        const int c = c0 + ty + i * 8, r = r0 + tx;
        if (c < Cc && r < R) op[(size_t)c * opitch + r] = f2b(t[tx][ty + i * 8]);
    }
}

// ---------------------------------------------------------------------------
// bf16 MFMA GEMM: 128x128 tile, BK=32, DOUBLE-BUFFERED 32KB LDS,
// global_load_lds width-16 staging both operands, prefetch-depth-1,
// ONE barrier per K-step (T3+T4 minimum 2-phase recipe):
//   issue STAGE(t+1, buf^1) -> ds_read+MFMA(t, buf) -> barrier (drains both).
// LDS chunk-swizzle (rule #21): gll16 dest linear; global SOURCE chunk is
// permuted (slot c holds chunk c ^ ((row>>1)&3)); ds_read applies same XOR.
// A[M][K], Wt[N][K] bf16 (row pitch K, K % 32 == 0), z-batched.
// SWZ: XCD-locality remap (gridDim.x==4). OB16: bf16 output.
// Epilogue: C = acc*scale + bias[z][n]; row pitch cpitch, z-stride cstride.
// ---------------------------------------------------------------------------
template<int SWZ, int OB16>
__global__ __launch_bounds__(256)
void gemm_mfma(const u16* __restrict__ A, const u16* __restrict__ Wt,
               const float* __restrict__ bias_base, size_t bias_stride,
               void* __restrict__ Cv, int M, int N, int K, float scale,
               size_t astride, size_t wstride, size_t cstride, int cpitch)
{
    __shared__ u16 SS[16384];  // two 16KB buffers: buf b at b*8192 (u16 units)
    const int tid = threadIdx.x;
    const int wave = tid >> 6, lane = tid & 63;
    const int quad = lane >> 4, l16 = lane & 15;
    const int z = blockIdx.z;
    int bx = blockIdx.x, by = blockIdx.y;
    if (SWZ) {   // gridDim.x==4: keep the 4 col-blocks of a row-block on one XCD
        const int lin = blockIdx.x + (blockIdx.y << 2);
        bx = (lin >> 3) & 3;
        by = (lin & 7) + ((lin >> 5) << 3);
    }
    const int m0 = by * BM, n0 = bx * BN;

    floatx4 acc[2][8];
#pragma unroll
    for (int t = 0; t < 2; t++)
#pragma unroll
        for (int u = 0; u < 8; u++)
#pragma unroll
            for (int r = 0; r < 4; r++) acc[t][u][r] = 0.f;

    // staging map: LDS slot (tid&3) of row (tid>>2) receives GLOBAL chunk
    // (tid&3) ^ ((row>>1)&3) -- the bank-conflict swizzle, applied at the source.
    const int srow = tid >> 2;                                   // 0..63
    const int scol = (((tid & 3) ^ ((srow >> 1) & 3))) * 8;      // swizzled chunk
    const u16* aP0 = A + z * astride + (size_t)clampi(m0 + srow,      M - 1) * K + scol;
    const u16* aP1 = A + z * astride + (size_t)clampi(m0 + 64 + srow, M - 1) * K + scol;
    const u16* bP0 = Wt + z * wstride + (size_t)clampi(n0 + srow,      N - 1) * K + scol;
    const u16* bP1 = Wt + z * wstride + (size_t)clampi(n0 + 64 + srow, N - 1) * K + scol;
    const int lsw = wave * 512;       // per-wave offset within a buffer (u16)

    // read-side swizzle term: all fragment rows reduce to sw = (l16>>1)&3
    const int sw8 = ((l16 >> 1) & 3) * 8;

    // prologue: stage K-tile 0 into buffer 0
    {
        u16* d = &SS[lsw];
        gll16(aP0, d);
        gll16(aP1, d + 2048);
        gll16(bP0, d + 4096);
        gll16(bP1, d + 6144);
    }
    __syncthreads();

    const int nt = K / BK;
    int cur = 0;
    for (int t = 0; t < nt; ++t) {
        // issue next-tile loads FIRST: latency hides under this tile's compute
        if (t + 1 < nt) {
            const int kn = (t + 1) * BK;
            u16* d = &SS[(cur ^ 1) * 8192 + lsw];
            gll16(aP0 + kn, d);
            gll16(aP1 + kn, d + 2048);
            gll16(bP0 + kn, d + 4096);
            gll16(bP1 + kn, d + 6144);
        }
        const u16* Sb = &SS[cur * 8192];
        short8 af[2], bfv[8];
        af[0] = *(const short8*)&Sb[(wave * 32 + l16) * 32 + ((quad * 8) ^ sw8)];
        af[1] = *(const short8*)&Sb[(wave * 32 + 16 + l16) * 32 + ((quad * 8) ^ sw8)];
#pragma unroll
        for (int u = 0; u < 8; u++)
            bfv[u] = *(const short8*)&Sb[4096 + (u * 16 + l16) * 32 + ((quad * 8) ^ sw8)];
#pragma unroll
        for (int t2 = 0; t2 < 2; t2++)
#pragma unroll
            for (int u = 0; u < 8; u++)
                acc[t2][u] = __builtin_amdgcn_mfma_f32_16x16x32_bf16(af[t2], bfv[u], acc[t2][u], 0, 0, 0);
        __syncthreads();   // drains this tile's reads AND next tile's writes
        cur ^= 1;
    }

    const float* bias = bias_base ? (bias_base + z * bias_stride) : nullptr;
#pragma unroll
    for (int t = 0; t < 2; t++) {
#pragma unroll
        for (int r = 0; r < 4; r++) {
            const int m = m0 + wave * 32 + t * 16 + quad * 4 + r;
            if (m >= M) continue;
#pragma unroll
            for (int u = 0; u < 8; u++) {
                const int n = n0 + u * 16 + l16;
                if (n < N) {
                    const float v = acc[t][u][r] * scale + (bias ? bias[n] : 0.f);
                    if (OB16) {
                        u16* Cb = (u16*)Cv;
                        Cb[z * cstride + (size_t)m * cpitch + n] = f2b(v);
                    } else {
                        float* Cf = (float*)Cv;
                        Cf[z * cstride + (size_t)m * cpitch + n] = v;
                    }
                }
            }
        }
    }
}

// ---------------------------------------------------------------------------
// fp32 64x64 GEMM (fallback path only)
// ---------------------------------------------------------------------------
template<int MODE>
__global__ __launch_bounds__(256)
void gemm64(const float* __restrict__ A, const float* __restrict__ W,
            const float* __restrict__ bias, float* __restrict__ C,
            int M, int N, int K, float scale,
            const int* __restrict__ segidx, float* __restrict__ segout)
{
    __shared__ float Asl[16][68];
    __shared__ float Bsl[16][64];
    const int tid = threadIdx.x;
    const int tx = tid & 15, ty = tid >> 4;
    const int m0 = blockIdx.y * 64, n0 = blockIdx.x * 64;
    const int arow = tid >> 2, acol = (tid & 3) * 4;
    const int brow = tid >> 4, bcol = (tid & 15) * 4;

    float acc[4][4];
#pragma unroll
    for (int i = 0; i < 4; i++)
#pragma unroll
        for (int j = 0; j < 4; j++) acc[i][j] = 0.f;

    for (int kk = 0; kk < K; kk += 16) {
        float4 av = make_float4(0.f, 0.f, 0.f, 0.f);
        if (m0 + arow < M) av = *(const float4*)(A + (size_t)(m0 + arow) * K + kk + acol);
        Asl[acol + 0][arow] = av.x; Asl[acol + 1][arow] = av.y;
        Asl[acol + 2][arow] = av.z; Asl[acol + 3][arow] = av.w;
        float4 bv = make_float4(0.f, 0.f, 0.f, 0.f);
        if (n0 + bcol < N) bv = *(const float4*)(W + (size_t)(kk + brow) * N + n0 + bcol);
        *(float4*)&Bsl[brow][bcol] = bv;
        __syncthreads();
#pragma unroll
        for (int k = 0; k < 16; k++) {
            const float4 a = *(const float4*)&Asl[k][ty * 4];
            const float4 b = *(const float4*)&Bsl[k][tx * 4];
            const float af[4] = { a.x, a.y, a.z, a.w };
            const float bfv[4] = { b.x, b.y, b.z, b.w };
#pragma unroll
            for (int i = 0; i < 4; i++)
#pragma unroll
                for (int j = 0; j < 4; j++) acc[i][j] += af[i] * bfv[j];
        }
        __syncthreads();
    }

#pragma unroll
    for (int i = 0; i < 4; i++) {
        const int m = m0 + ty * 4 + i;
        if (m >= M) continue;
        if (MODE == 1) {
            const int bb = m >> 11;
            const int idx = segidx[m];
            float* const srow = segout + (((size_t)bb * NNODE + idx) << 9);
#pragma unroll
            for (int j = 0; j < 4; j++) {
                const int n = n0 + tx * 4 + j;
                const float v = acc[i][j] + (bias ? bias[n] : 0.f);
                atomicMax(((int*)srow) + n, __float_as_int(v));
            }
        } else {
#pragma unroll
            for (int j = 0; j < 4; j++) {
                const int n = n0 + tx * 4 + j;
                if (n < N) {
                    const float v = acc[i][j] * scale + (bias ? bias[n] : 0.f);
                    C[(size_t)m * N + n] = v;
                }
            }
        }
    }
}

// ---------------------------------------------------------------------------
// Merged CSR build: (A) row buckets over (batch,node) for segment ownership,
// (B) class CSR over (class,dst) + packed {src, coef}. One block per batch.
// ---------------------------------------------------------------------------
__global__ void csr_all(const int* __restrict__ ent_indices,
                        int* __restrict__ rptr, int* __restrict__ rlist,
                        const int* __restrict__ edge_index, const int* __restrict__ edge_attr,
                        float* __restrict__ degf, int* __restrict__ csr_ptr,
                        int2* __restrict__ csr_sc)
{
    __shared__ int cnt[NC * NNODE];
    __shared__ float dinvl[NC * NNODE];
    const int b = blockIdx.x;
    const int tid = threadIdx.x;

    // ---- phase A: row buckets ----
    const int* idx = ent_indices + (size_t)b * S_;
    for (int i = tid; i < NNODE; i += 256) cnt[i] = 0;
    __syncthreads();
    for (int r = tid; r < S_; r += 256) atomicAdd(&cnt[idx[r]], 1);
    __syncthreads();
    if (tid == 0) {
        int run = 0;
        for (int i = 0; i < NNODE; i++) { const int c = cnt[i]; cnt[i] = run; run += c; }
    }
    __syncthreads();
    for (int i = tid; i < NNODE; i += 256) rptr[b * (NNODE + 1) + i] = cnt[i];
    if (tid == 0) rptr[b * (NNODE + 1) + NNODE] = S_;
    __syncthreads();
    for (int r = tid; r < S_; r += 256) {
        const int pos = atomicAdd(&cnt[idx[r]], 1);
        rlist[(size_t)b * S_ + pos] = r;
    }
    __syncthreads();

    // ---- phase B: class CSR ----
    const int* src = edge_index + (size_t)b * 2 * E_;
    const int* dst = src + E_;
    const int* attr = edge_attr + (size_t)b * E_;
    for (int i = tid; i < NC * NNODE; i += 256) cnt[i] = 0;
    __syncthreads();
    for (int e = tid; e < E_; e += 256) atomicAdd(&cnt[attr[e] * NNODE + dst[e]], 1);
    __syncthreads();
    for (int i = tid; i < NC * NNODE; i += 256) {
        const float d = (float)cnt[i] + 1.0f;
        degf[(size_t)b * NC * NNODE + i] = d;
        dinvl[i] = rsqrtf(d);
    }
    __syncthreads();
    if (tid == 0) {
        int run = 0;
        for (int i = 0; i < NC * NNODE; i++) { const int c = cnt[i]; cnt[i] = run; run += c; }
    }
    __syncthreads();
    for (int i = tid; i < NC * NNODE; i += 256) csr_ptr[(size_t)b * NC * NNODE + i] = cnt[i];
    __syncthreads();
    for (int e = tid; e < E_; e += 256) {
        const int a = attr[e], d = dst[e], s = src[e];
        const int pos = atomicAdd(&cnt[a * NNODE + d], 1);
        const float cf = dinvl[a * NNODE + s] * dinvl[a * NNODE + d];
        csr_sc[(size_t)b * E_ + pos] = make_int2(s, __float_as_int(cf));
    }
}

// ---------------------------------------------------------------------------
// Fused segment-max (bf16 redC) + x0 build. One block owns one (batch,node):
// no atomics. x0b row = [label 16 | relu(max+bias) 512 | pad 16] bf16, pitch 544.
// ---------------------------------------------------------------------------
__global__ __launch_bounds__(256)
void segmax_x0(const u16* __restrict__ redC, const int* __restrict__ rptr,
               const int* __restrict__ rlist, const float* __restrict__ b_red,
               const int* __restrict__ ent_labels, const float* __restrict__ tbl,
               u16* __restrict__ x0b)
{
    const int bn = blockIdx.x;           // b*NNODE + n
    const int b = bn / NNODE, n = bn % NNODE;
    const int tid = threadIdx.x;
    const int c0 = tid * 2;              // two adjacent bf16 cols per thread
    const int start = rptr[b * (NNODE + 1) + n];
    const int end   = (n == 0) ? start : rptr[b * (NNODE + 1) + n + 1];
    float m0 = -INFINITY, m1 = -INFINITY;
    const int* rl = rlist + (size_t)b * S_;
    for (int i = start; i < end; i++) {
        const u16* row = redC + ((size_t)b * S_ + rl[i]) * H_;
        const unsigned v = *(const unsigned*)(row + c0);
        m0 = fmaxf(m0, __uint_as_float((v & 0xffffu) << 16));
        m1 = fmaxf(m1, __uint_as_float(v & 0xffff0000u));
    }
    float h0, h1;
    if (n == 0) { h0 = 0.f; h1 = 0.f; }
    else {
        h0 = fmaxf(m0 + b_red[c0], 0.f);
        h1 = fmaxf(m1 + b_red[c0 + 1], 0.f);
    }
    u16* orow = x0b + (size_t)bn * KPAD;
    *(unsigned*)(orow + 16 + c0) = (unsigned)f2b(h0) | ((unsigned)f2b(h1) << 16);
    if (tid < 16) {
        float v;
        if (n == 0) v = tbl[tid];
        else {
            const int lab = ent_labels[b * (NNODE - 1) + (n - 1)];
            v = (lab != 0) ? tbl[lab * 16 + tid] : 0.f;
        }
        orow[tid] = f2b(v);
    } else if (tid < 32) {
        orow[512 + tid] = 0;             // K-pad cols 528..543
    }
}

template<int OUTB>
__global__ void build_x0(const float* __restrict__ seg, const int* __restrict__ ent_labels,
                         const float* __restrict__ tbl, float* __restrict__ x0f,
                         u16* __restrict__ x0b)
{
    const int bn = blockIdx.x;
    const int b = bn / NNODE, n = bn % NNODE;
    const int CMAX = OUTB ? KPAD : D_;
    for (int col = threadIdx.x; col < CMAX; col += blockDim.x) {
        float v;
        if (col >= D_) {
            v = 0.f;
        } else if (col < 16) {
            if (n == 0) v = tbl[col];
            else {
                const int lab = ent_labels[b * (NNODE - 1) + (n - 1)];
                v = (lab != 0) ? tbl[lab * 16 + col] : 0.f;
            }
        } else {
            v = (n == 0) ? 0.f : seg[(((size_t)b * NNODE + n) << 9) + (col - 16)];
        }
        if (OUTB) x0b[(size_t)bn * KPAD + col] = f2b(v);
        else      x0f[(size_t)bn * D_ + col] = v;
    }
}

// OUT: 0 bf16 write (z-strided, pitch KPAD, zero K-pad); 1 fp32 +=;
//      2 fp32 = (z-strided via ostride, pitch D_)
template<int OUT>
__global__ __launch_bounds__(256)
void gcn_gather(const float* __restrict__ h, size_t hstride,
                const float* __restrict__ degf,
                const int* __restrict__ csr_ptr, const int2* __restrict__ csr_sc,
                const float* __restrict__ bias_base, size_t bias_stride,
                float* __restrict__ outf, u16* __restrict__ outb, size_t ostride,
                int cls0)
{
    const int bn = blockIdx.x;
    const int cls = cls0 + blockIdx.y;
    const int b = bn / NNODE, n = bn % NNODE;
    const int tid = threadIdx.x;
    const int base = b * NC * NNODE + cls * NNODE + n;
    const float d = degf[base];
    const int start = csr_ptr[base];
    const int cnt = (int)d - 1;
    const float inv = 1.0f / d;
    const float* hp = h + blockIdx.y * hstride;
    const float* bias = bias_base + cls * bias_stride;
    const float* hrow = hp + (size_t)bn * D_;
    const int c0 = tid, c1 = tid + 256, c2 = tid + 512;
    float a0 = hrow[c0] * inv + bias[c0];
    float a1 = hrow[c1] * inv + bias[c1];
    float a2 = (c2 < D_) ? hrow[c2] * inv + bias[c2] : 0.f;
    const int2* scp = csr_sc + (size_t)b * E_ + start;
    int2 sc = (cnt > 0) ? scp[0] : make_int2(0, 0);
    for (int i = 0; i < cnt; i++) {
        const int2 cur = sc;
        if (i + 1 < cnt) sc = scp[i + 1];     // prefetch: break dependent chain
        const float cf = __int_as_float(cur.y);
        const float* hs = hp + ((size_t)b * NNODE + cur.x) * D_;
        a0 += cf * hs[c0];
        a1 += cf * hs[c1];
        if (c2 < D_) a2 += cf * hs[c2];
    }
    if (OUT == 0) {
        u16* orow = outb + blockIdx.y * ostride + (size_t)bn * KPAD;
        orow[c0] = f2b(a0); orow[c1] = f2b(a1); if (c2 < D_) orow[c2] = f2b(a2);
        if (tid >= 16 && tid < 32) orow[512 + tid] = 0;   // zero K-pad 528..543
    } else if (OUT == 1) {
        float* orow = outf + (size_t)bn * D_;
        orow[c0] += a0; orow[c1] += a1; if (c2 < D_) orow[c2] += a2;
    } else {
        float* orow = outf + blockIdx.y * ostride + (size_t)bn * D_;
        orow[c0] = a0; orow[c1] = a1; if (c2 < D_) orow[c2] = a2;
    }
}

__global__ void rowdot3(const float* __restrict__ x, const float* __restrict__ w,
                        float* __restrict__ out)
{
    const int row = blockIdx.x;
    const int lane = threadIdx.x;
    float a0 = 0.f, a1 = 0.f, a2 = 0.f;
    for (int d = lane; d < D_; d += 64) {
        const float xv = x[(size_t)row * D_ + d];
        a0 += xv * w[d * 3 + 0];
        a1 += xv * w[d * 3 + 1];
        a2 += xv * w[d * 3 + 2];
    }
#pragma unroll
    for (int off = 32; off > 0; off >>= 1) {
        a0 += __shfl_down(a0, off, 64);
        a1 += __shfl_down(a1, off, 64);
        a2 += __shfl_down(a2, off, 64);
    }
    if (lane == 0) {
        out[(size_t)row * 3 + 0] = a0;
        out[(size_t)row * 3 + 1] = a1;
        out[(size_t)row * 3 + 2] = a2;
    }
}

// one kernel: Whw = W_head@W_out, Wtw = W_tail@W_out, bias6 = {b_head,b_tail}@W_out
__global__ void prep_heads(const float* __restrict__ W_head, const float* __restrict__ W_tail,
                           const float* __restrict__ b_head, const float* __restrict__ b_tail,
                           const float* __restrict__ W_out,
                           float* __restrict__ Whw, float* __restrict__ Wtw,
                           float* __restrict__ bias6)
{
    const int r = blockIdx.x;            // 0..2*D_+1
    const int lane = threadIdx.x;
    const float* x; float* o;
    if (r < D_)            { x = W_head + (size_t)r * D_;        o = Whw + (size_t)r * 3; }
    else if (r < 2 * D_)   { x = W_tail + (size_t)(r - D_) * D_; o = Wtw + (size_t)(r - D_) * 3; }
    else if (r == 2 * D_)  { x = b_head;                         o = bias6; }
    else                   { x = b_tail;                         o = bias6 + 3; }
    float a0 = 0.f, a1 = 0.f, a2 = 0.f;
    for (int d = lane; d < D_; d += 64) {
        const float xv = x[d];
        a0 += xv * W_out[d * 3 + 0];
        a1 += xv * W_out[d * 3 + 1];
        a2 += xv * W_out[d * 3 + 2];
    }
#pragma unroll
    for (int off = 32; off > 0; off >>= 1) {
        a0 += __shfl_down(a0, off, 64);
        a1 += __shfl_down(a1, off, 64);
        a2 += __shfl_down(a2, off, 64);
    }
    if (lane == 0) { o[0] = a0; o[1] = a1; o[2] = a2; }
}

// hw/tw from 3 class planes: x = (p0+p1+p2)/3; 4 rows per block (1 wave each)
__global__ __launch_bounds__(256)
void rowdot6(const float* __restrict__ x3, size_t zstride,
             const float* __restrict__ Whw, const float* __restrict__ Wtw,
             const float* __restrict__ bias6,
             float* __restrict__ hw, float* __restrict__ tw)
{
    const int row = blockIdx.x * 4 + (threadIdx.x >> 6);
    const int lane = threadIdx.x & 63;
    const float* p0 = x3 + (size_t)row * D_;
    const float* p1 = p0 + zstride;
    const float* p2 = p1 + zstride;
    float h0 = 0.f, h1 = 0.f, h2 = 0.f, t0 = 0.f, t1 = 0.f, t2 = 0.f;
    for (int d = lane; d < D_; d += 64) {
        const float xv = (p0[d] + p1[d] + p2[d]) * (1.f / 3.f);
        h0 += xv * Whw[d * 3 + 0]; h1 += xv * Whw[d * 3 + 1]; h2 += xv * Whw[d * 3 + 2];
        t0 += xv * Wtw[d * 3 + 0]; t1 += xv * Wtw[d * 3 + 1]; t2 += xv * Wtw[d * 3 + 2];
    }
#pragma unroll
    for (int off = 32; off > 0; off >>= 1) {
        h0 += __shfl_down(h0, off, 64); h1 += __shfl_down(h1, off, 64); h2 += __shfl_down(h2, off, 64);
        t0 += __shfl_down(t0, off, 64); t1 += __shfl_down(t1, off, 64); t2 += __shfl_down(t2, off, 64);
    }
    if (lane == 0) {
        hw[(size_t)row * 3 + 0] = h0 + bias6[0];
        hw[(size_t)row * 3 + 1] = h1 + bias6[1];
        hw[(size_t)row * 3 + 2] = h2 + bias6[2];
        tw[(size_t)row * 3 + 0] = t0 + bias6[3];
        tw[(size_t)row * 3 + 1] = t1 + bias6[4];
        tw[(size_t)row * 3 + 2] = t2 + bias6[5];
    }
}

__global__ __launch_bounds__(256)
void final_logits(const float* __restrict__ hw, const float* __restrict__ tw,
                  const int* __restrict__ cands, const float* __restrict__ b_out,
                  float* __restrict__ out)
{
    const int bi = blockIdx.x;
    const int b = bi / NNODE;
    const int j = threadIdx.x;
    const float h0 = hw[bi * 3 + 0], h1 = hw[bi * 3 + 1], h2 = hw[bi * 3 + 2];
    const int tj = b * NNODE + 1 + j;
    const float t0 = tw[tj * 3 + 0], t1 = tw[tj * 3 + 1], t2 = tw[tj * 3 + 2];
    const float m = (cands[(size_t)bi * NNODE + 1 + j] != 0) ? 1.f : 0.f;
    const float bo0 = b_out[0], bo1 = b_out[1], bo2 = b_out[2];
    const size_t o = ((size_t)bi * 256 + j) * 3;
    out[o + 0] = (h0 + t0) * m + bo0;
    out[o + 1] = (h1 + t1) * m + bo1;
    out[o + 2] = (h2 + t2) * m + bo2;
}

extern "C" void kernel_launch(void* const* d_in, const int* in_sizes, int n_in,
                              void* d_out, int out_size, void* d_ws, size_t ws_size,
                              hipStream_t stream)
{
    const float* emb       = (const float*)d_in[0];
    const int* ent_indices = (const int*)d_in[1];
    const int* ent_labels  = (const int*)d_in[2];
    const int* edge_index  = (const int*)d_in[3];
    const int* edge_attr   = (const int*)d_in[4];
    const int* cands       = (const int*)d_in[5];
    const float* W_red     = (const float*)d_in[6];
    const float* b_red     = (const float*)d_in[7];
    const float* tbl       = (const float*)d_in[8];
    const float* W_gcn     = (const float*)d_in[9];
    const float* b_gcn     = (const float*)d_in[10];
    const float* W_head    = (const float*)d_in[11];
    const float* b_head    = (const float*)d_in[12];
    const float* W_tail    = (const float*)d_in[13];
    const float* b_tail    = (const float*)d_in[14];
    const float* W_out     = (const float*)d_in[15];
    const float* b_out     = (const float*)d_in[16];

    char* ws = (char*)d_ws;
    size_t off = 0;
    auto alloc = [&](size_t nbytes) -> char* {
        char* p = ws + off; off = (off + nbytes + 255) & ~(size_t)255; return p;
    };
    const size_t ROWB  = (size_t)NROW * D_ * sizeof(float);
    const size_t RD    = (size_t)NROW * D_;         // f32 plane stride (pitch 528)
    const size_t RD2   = (size_t)NROW * KPAD;       // bf16 plane stride (pitch 544)
    const size_t WGZ   = (size_t)2 * D_ * KPAD;     // wgcnT z-stride (2 layers)

    // region R0: emb_bf (phase 1), then hbuf[3 planes f32] + x1b[3 planes bf16]
    char* R0      = alloc((size_t)B_ * S_ * ETR_ * sizeof(u16)); // 50.3 MB
    u16*  emb_bf  = (u16*)R0;
    float* hbuf   = (float*)R0;                                  // [3][NROW][528] f32 = 26.05 MB
    u16*  x1b     = (u16*)(R0 + 3 * ROWB);                       // [3][NROW][544] bf16 = 13.4 MB
    // region R1: redC bf16 (phase 1), then result3 [3][NROW][528] f32 (epilogue)
    char* R1      = alloc((size_t)B_ * S_ * H_ * sizeof(u16));   // 33.6 MB
    u16*  redC    = (u16*)R1;
    float* result3 = (float*)R1;                                 // 26.1 MB fits
    int*  rptr    = (int*)alloc((size_t)B_ * (NNODE + 1) * 4);
    int*  rlist   = (int*)alloc((size_t)B_ * S_ * 4);
    u16*  x0b     = (u16*)alloc((size_t)NROW * KPAD * sizeof(u16));
    u16*  wredT   = (u16*)alloc((size_t)H_ * ETR_ * sizeof(u16));    // [512][768]
    u16*  wgcnT   = (u16*)alloc((size_t)NC * WGZ * sizeof(u16));     // [3][2][528][544]
    float* Whw    = (float*)alloc((size_t)D_ * 3 * 4);
    float* Wtw    = (float*)alloc((size_t)D_ * 3 * 4);
    float* bias6  = (float*)alloc(6 * 4);
    float* degf   = (float*)alloc((size_t)B_ * NC * NNODE * 4);
    float* hwp    = (float*)alloc((size_t)NROW * 3 * 4);
    float* twp    = (float*)alloc((size_t)NROW * 3 * 4);
    int* csr_ptr  = (int*)alloc((size_t)B_ * NC * NNODE * 4);
    int2* csr_sc  = (int2*)alloc((size_t)B_ * E_ * 8);
    const bool fast = (ws_size >= off);

    if (fast) {
        const int n4e = (B_ * S_ * ETR_) / 4;
        cvt_bf16<<<(n4e + 255) / 256, 256, 0, stream>>>(emb, emb_bf, n4e);
        transpose_cvt<<<dim3(16, 24, 1), 256, 0, stream>>>(W_red, wredT, ETR_, H_, 0, 0, ETR_);
        hipMemsetAsync(wgcnT, 0, (size_t)NC * WGZ * sizeof(u16), stream);  // K-pad zeros
        transpose_cvt<<<dim3(17, 17, 6), 256, 0, stream>>>(W_gcn, wgcnT, D_, D_, DD, (size_t)D_ * KPAD, KPAD);

        // fused head/tail weights (single launch)
        prep_heads<<<2 * D_ + 2, 64, 0, stream>>>(W_head, W_tail, b_head, b_tail, W_out,
                                                  Whw, Wtw, bias6);

        // merged row-bucket CSR + class CSR (one launch)
        csr_all<<<B_, 256, 0, stream>>>(ent_indices, rptr, rlist,
                                        edge_index, edge_attr, degf, csr_ptr, csr_sc);

        // 1) reduction GEMM (bf16 gll16 both sides, dbuf pipeline) -> bf16 redC
        gemm_mfma<1, 1><<<dim3(H_ / BN, (B_ * S_) / BM, 1), 256, 0, stream>>>(
            emb_bf, wredT, nullptr, 0, redC, B_ * S_, H_, ETR_, 1.f, 0, 0, 0, H_);
        // 2) fused exclusive-owner segment max + x0 build (zero atomics)
        segmax_x0<<<B_ * NNODE, 256, 0, stream>>>(redC, rptr, rlist, b_red,
                                                  ent_labels, tbl, x0b);

        // 3) GCN layer 1: GEMM on shared x0 plane (astride 0, L2-hot A), f32 h out
        dim3 gmm((D_ + BN - 1) / BN, (NROW + BM - 1) / BM, NC);   // 5 x 33 x 3
        gemm_mfma<0, 0><<<gmm, 256, 0, stream>>>(
            x0b, wgcnT, nullptr, 0, hbuf, NROW, D_, KPAD, 1.f, 0, WGZ, RD, D_);
        gcn_gather<0><<<dim3(NROW, NC), 256, 0, stream>>>(
            hbuf, RD, degf, csr_ptr, csr_sc, b_gcn, (size_t)2 * D_,
            nullptr, x1b, RD2, 0);
        // 4) GCN layer 2
        gemm_mfma<0, 0><<<gmm, 256, 0, stream>>>(
            x1b, wgcnT + (size_t)D_ * KPAD, nullptr, 0, hbuf, NROW, D_, KPAD, 1.f,
            RD2, WGZ, RD, D_);
        gcn_gather<2><<<dim3(NROW, NC), 256, 0, stream>>>(
            hbuf, RD, degf, csr_ptr, csr_sc, b_gcn + D_, (size_t)2 * D_,
            result3, nullptr, RD, 0);

        // 5) fused epilogue: sum 3 planes inside rowdot6 (no atomics, no memset)
        rowdot6<<<NROW / 4, 256, 0, stream>>>(result3, RD, Whw, Wtw, bias6, hwp, twp);
        final_logits<<<NROW, 256, 0, stream>>>(hwp, twp, cands, b_out, (float*)d_out);
        return;
    }

    // -------- fallback: proven fp32 pipeline --------
    off = 0;
    float* bufA = (float*)alloc(ROWB);
    float* bufB = (float*)alloc(ROWB);
    float* bufC = (float*)alloc(ROWB);
    float* bufD = (float*)alloc(ROWB);
    degf = (float*)alloc((size_t)B_ * NC * NNODE * 4);
    hwp  = (float*)alloc((size_t)NROW * 3 * 4);
    twp  = (float*)alloc((size_t)NROW * 3 * 4);
    csr_ptr = (int*)alloc((size_t)B_ * NC * NNODE * 4);
    csr_sc  = (int2*)alloc((size_t)B_ * E_ * 8);
    int* rptr2  = (int*)alloc((size_t)B_ * (NNODE + 1) * 4);
    int* rlist2 = (int*)alloc((size_t)B_ * S_ * 4);

    hipMemsetAsync(bufA, 0, (size_t)B_ * NNODE * H_ * 4, stream);
    hipMemsetAsync(bufD, 0, ROWB, stream);
    gemm64<1><<<dim3(H_ / 64, (B_ * S_) / 64), 256, 0, stream>>>(
        emb, W_red, b_red, nullptr, B_ * S_, H_, ETR_, 1.f, ent_indices, bufA);
    build_x0<0><<<NROW, 256, 0, stream>>>(bufA, ent_labels, tbl, bufB, nullptr);
    csr_all<<<B_, 256, 0, stream>>>(ent_indices, rptr2, rlist2,
                                    edge_index, edge_attr, degf, csr_ptr, csr_sc);
    dim3 gridG((D_ + 63) / 64, (NROW + 63) / 64);
    for (int c = 0; c < NC; c++) {
        gemm64<0><<<gridG, 256, 0, stream>>>(bufB, W_gcn + (size_t)(c * 2 + 0) * DD,
            nullptr, bufA, NROW, D_, D_, 1.f, nullptr, nullptr);
        gcn_gather<2><<<dim3(NROW, 1), 256, 0, stream>>>(bufA, 0, degf, csr_ptr, csr_sc,
            b_gcn, (size_t)2 * D_, bufC, nullptr, 0, c);
        gemm64<0><<<gridG, 256, 0, stream>>>(bufC, W_gcn + (size_t)(c * 2 + 1) * DD,
            nullptr, bufA, NROW, D_, D_, 1.f, nullptr, nullptr);
        gcn_gather<1><<<dim3(NROW, 1), 256, 0, stream>>>(bufA, 0, degf, csr_ptr, csr_sc,
            b_gcn + D_, (size_t)2 * D_, bufD, nullptr, 0, c);
    }
    gemm64<0><<<gridG, 256, 0, stream>>>(bufD, W_head, b_head, bufB,
        NROW, D_, D_, 1.f / 3.f, nullptr, nullptr);
    gemm64<0><<<gridG, 256, 0, stream>>>(bufD, W_tail, b_tail, bufC,
        NROW, D_, D_, 1.f / 3.f, nullptr, nullptr);
    rowdot3<<<NROW, 64, 0, stream>>>(bufB, W_out, hwp);
    rowdot3<<<NROW, 64, 0, stream>>>(bufC, W_out, twp);
    final_logits<<<NROW, 256, 0, stream>>>(hwp, twp, cands, b_out, (float*)d_out);
}

// Round 11
// 419.409 us; speedup vs baseline: 1.0322x; 1.0092x over previous
//
#include <hip/hip_runtime.h>
#include <hip/hip_bf16.h>

typedef unsigned short u16;
typedef __attribute__((ext_vector_type(8))) short short8;
typedef __attribute__((ext_vector_type(4))) float floatx4;

#define B_ 16
#define S_ 2048
#define NNODE 257
#define E_ 4096
#define ETR_ 768
#define H_ 512
#define D_ 528
#define KPAD 544          // K padded to a BK multiple for MFMA GEMMs
#define NC 3
#define NROW (B_*NNODE)   // 4112
#define DD (D_*D_)

#define BM 128
#define BN 128
#define BK 32

__device__ inline u16 f2b(float x) {
    __hip_bfloat16 h = __float2bfloat16(x);
    return *(u16*)&h;
}
__device__ inline float b2f(u16 u) {
    return __uint_as_float(((unsigned)u) << 16);
}
__device__ inline float b2f_lo(unsigned v) { return __uint_as_float(v << 16); }
__device__ inline float b2f_hi(unsigned v) { return __uint_as_float(v & 0xffff0000u); }

// async global->LDS, 16B per lane (m97 structure). LDS dest must be linear:
// HW writes wave-uniform base + lane*16.
__device__ inline void gll16(const u16* g, u16* l) {
    __builtin_amdgcn_global_load_lds(
        (const __attribute__((address_space(1))) void*)g,
        (__attribute__((address_space(3))) void*)l,
        16, 0, 0);
}

__device__ inline int clampi(int v, int hi) { return v < hi ? v : hi; }

__global__ void cvt_bf16(const float* __restrict__ in, u16* __restrict__ out, int n4)
{
    const int i = blockIdx.x * 256 + threadIdx.x;
    if (i < n4) {
        const float4 f = ((const float4*)in)[i];
        ushort4 o;
        o.x = f2b(f.x); o.y = f2b(f.y); o.z = f2b(f.z); o.w = f2b(f.w);
        ((ushort4*)out)[i] = o;
    }
}

// in f32 [R][C] (z-batched) -> out bf16 [C][R] with out pitch opitch (>= R)
__global__ void transpose_cvt(const float* __restrict__ in, u16* __restrict__ out,
                              int R, int Cc, size_t instride, size_t outstride,
                              int opitch)
{
    __shared__ float t[32][33];
    const int z = blockIdx.z;
    const int tx = threadIdx.x & 31, ty = threadIdx.x >> 5;  // 32 x 8
    const int c0 = blockIdx.x * 32, r0 = blockIdx.y * 32;
    const float* ip = in + z * instride;
    u16* op = out + z * outstride;
#pragma unroll
    for (int i = 0; i < 4; i++) {
        const int r = r0 + ty + i * 8, c = c0 + tx;
        if (r < R && c < Cc) t[ty + i * 8][tx] = ip[(size_t)r * Cc + c];
    }
    __syncthreads();
#pragma unroll
    for (int i = 0; i < 4; i++) {
        const int c = c0 + ty + i * 8, r = r0 + tx;
        if (c < Cc && r < R) op[(size_t)c * opitch + r] = f2b(t[tx][ty + i * 8]);
    }
}

// ---------------------------------------------------------------------------
// bf16 MFMA GEMM: 128x128 tile, BK=32, DOUBLE-BUFFERED 32KB LDS,
// global_load_lds width-16 staging both operands, prefetch-depth-1,
// ONE barrier per K-step. LDS chunk-swizzle (source-permuted, read-XOR).
// A[M][K], Wt[N][K] bf16 (row pitch K, K % 32 == 0), z-batched.
// SWZ: XCD-locality remap (gridDim.x==4). OB16: bf16 output.
// Epilogue: C = acc*scale + bias[z][n]; row pitch cpitch, z-stride cstride.
// ---------------------------------------------------------------------------
template<int SWZ, int OB16>
__global__ __launch_bounds__(256)
void gemm_mfma(const u16* __restrict__ A, const u16* __restrict__ Wt,
               const float* __restrict__ bias_base, size_t bias_stride,
               void* __restrict__ Cv, int M, int N, int K, float scale,
               size_t astride, size_t wstride, size_t cstride, int cpitch)
{
    __shared__ u16 SS[16384];  // two 16KB buffers: buf b at b*8192 (u16 units)
    const int tid = threadIdx.x;
    const int wave = tid >> 6, lane = tid & 63;
    const int quad = lane >> 4, l16 = lane & 15;
    const int z = blockIdx.z;
    int bx = blockIdx.x, by = blockIdx.y;
    if (SWZ) {   // gridDim.x==4: keep the 4 col-blocks of a row-block on one XCD
        const int lin = blockIdx.x + (blockIdx.y << 2);
        bx = (lin >> 3) & 3;
        by = (lin & 7) + ((lin >> 5) << 3);
    }
    const int m0 = by * BM, n0 = bx * BN;

    floatx4 acc[2][8];
#pragma unroll
    for (int t = 0; t < 2; t++)
#pragma unroll
        for (int u = 0; u < 8; u++)
#pragma unroll
            for (int r = 0; r < 4; r++) acc[t][u][r] = 0.f;

    // staging map: LDS slot (tid&3) of row (tid>>2) receives GLOBAL chunk
    // (tid&3) ^ ((row>>1)&3) -- the bank-conflict swizzle, applied at the source.
    const int srow = tid >> 2;                                   // 0..63
    const int scol = (((tid & 3) ^ ((srow >> 1) & 3))) * 8;      // swizzled chunk
    const u16* aP0 = A + z * astride + (size_t)clampi(m0 + srow,      M - 1) * K + scol;
    const u16* aP1 = A + z * astride + (size_t)clampi(m0 + 64 + srow, M - 1) * K + scol;
    const u16* bP0 = Wt + z * wstride + (size_t)clampi(n0 + srow,      N - 1) * K + scol;
    const u16* bP1 = Wt + z * wstride + (size_t)clampi(n0 + 64 + srow, N - 1) * K + scol;
    const int lsw = wave * 512;       // per-wave offset within a buffer (u16)

    // read-side swizzle term: all fragment rows reduce to sw = (l16>>1)&3
    const int sw8 = ((l16 >> 1) & 3) * 8;

    // prologue: stage K-tile 0 into buffer 0
    {
        u16* d = &SS[lsw];
        gll16(aP0, d);
        gll16(aP1, d + 2048);
        gll16(bP0, d + 4096);
        gll16(bP1, d + 6144);
    }
    __syncthreads();

    const int nt = K / BK;
    int cur = 0;
    for (int t = 0; t < nt; ++t) {
        // issue next-tile loads FIRST: latency hides under this tile's compute
        if (t + 1 < nt) {
            const int kn = (t + 1) * BK;
            u16* d = &SS[(cur ^ 1) * 8192 + lsw];
            gll16(aP0 + kn, d);
            gll16(aP1 + kn, d + 2048);
            gll16(bP0 + kn, d + 4096);
            gll16(bP1 + kn, d + 6144);
        }
        const u16* Sb = &SS[cur * 8192];
        short8 af[2], bfv[8];
        af[0] = *(const short8*)&Sb[(wave * 32 + l16) * 32 + ((quad * 8) ^ sw8)];
        af[1] = *(const short8*)&Sb[(wave * 32 + 16 + l16) * 32 + ((quad * 8) ^ sw8)];
#pragma unroll
        for (int u = 0; u < 8; u++)
            bfv[u] = *(const short8*)&Sb[4096 + (u * 16 + l16) * 32 + ((quad * 8) ^ sw8)];
#pragma unroll
        for (int t2 = 0; t2 < 2; t2++)
#pragma unroll
            for (int u = 0; u < 8; u++)
                acc[t2][u] = __builtin_amdgcn_mfma_f32_16x16x32_bf16(af[t2], bfv[u], acc[t2][u], 0, 0, 0);
        __syncthreads();   // drains this tile's reads AND next tile's writes
        cur ^= 1;
    }

    const float* bias = bias_base ? (bias_base + z * bias_stride) : nullptr;
#pragma unroll
    for (int t = 0; t < 2; t++) {
#pragma unroll
        for (int r = 0; r < 4; r++) {
            const int m = m0 + wave * 32 + t * 16 + quad * 4 + r;
            if (m >= M) continue;
#pragma unroll
            for (int u = 0; u < 8; u++) {
                const int n = n0 + u * 16 + l16;
                if (n < N) {
                    const float v = acc[t][u][r] * scale + (bias ? bias[n] : 0.f);
                    if (OB16) {
                        u16* Cb = (u16*)Cv;
                        Cb[z * cstride + (size_t)m * cpitch + n] = f2b(v);
                    } else {
                        float* Cf = (float*)Cv;
                        Cf[z * cstride + (size_t)m * cpitch + n] = v;
                    }
                }
            }
        }
    }
}

// ---------------------------------------------------------------------------
// fp32 64x64 GEMM (fallback path only)
// ---------------------------------------------------------------------------
template<int MODE>
__global__ __launch_bounds__(256)
void gemm64(const float* __restrict__ A, const float* __restrict__ W,
            const float* __restrict__ bias, float* __restrict__ C,
            int M, int N, int K, float scale,
            const int* __restrict__ segidx, float* __restrict__ segout)
{
    __shared__ float Asl[16][68];
    __shared__ float Bsl[16][64];
    const int tid = threadIdx.x;
    const int tx = tid & 15, ty = tid >> 4;
    const int m0 = blockIdx.y * 64, n0 = blockIdx.x * 64;
    const int arow = tid >> 2, acol = (tid & 3) * 4;
    const int brow = tid >> 4, bcol = (tid & 15) * 4;

    float acc[4][4];
#pragma unroll
    for (int i = 0; i < 4; i++)
#pragma unroll
        for (int j = 0; j < 4; j++) acc[i][j] = 0.f;

    for (int kk = 0; kk < K; kk += 16) {
        float4 av = make_float4(0.f, 0.f, 0.f, 0.f);
        if (m0 + arow < M) av = *(const float4*)(A + (size_t)(m0 + arow) * K + kk + acol);
        Asl[acol + 0][arow] = av.x; Asl[acol + 1][arow] = av.y;
        Asl[acol + 2][arow] = av.z; Asl[acol + 3][arow] = av.w;
        float4 bv = make_float4(0.f, 0.f, 0.f, 0.f);
        if (n0 + bcol < N) bv = *(const float4*)(W + (size_t)(kk + brow) * N + n0 + bcol);
        *(float4*)&Bsl[brow][bcol] = bv;
        __syncthreads();
#pragma unroll
        for (int k = 0; k < 16; k++) {
            const float4 a = *(const float4*)&Asl[k][ty * 4];
            const float4 b = *(const float4*)&Bsl[k][tx * 4];
            const float af[4] = { a.x, a.y, a.z, a.w };
            const float bfv[4] = { b.x, b.y, b.z, b.w };
#pragma unroll
            for (int i = 0; i < 4; i++)
#pragma unroll
                for (int j = 0; j < 4; j++) acc[i][j] += af[i] * bfv[j];
        }
        __syncthreads();
    }

#pragma unroll
    for (int i = 0; i < 4; i++) {
        const int m = m0 + ty * 4 + i;
        if (m >= M) continue;
        if (MODE == 1) {
            const int bb = m >> 11;
            const int idx = segidx[m];
            float* const srow = segout + (((size_t)bb * NNODE + idx) << 9);
#pragma unroll
            for (int j = 0; j < 4; j++) {
                const int n = n0 + tx * 4 + j;
                const float v = acc[i][j] + (bias ? bias[n] : 0.f);
                atomicMax(((int*)srow) + n, __float_as_int(v));
            }
        } else {
#pragma unroll
            for (int j = 0; j < 4; j++) {
                const int n = n0 + tx * 4 + j;
                if (n < N) {
                    const float v = acc[i][j] * scale + (bias ? bias[n] : 0.f);
                    C[(size_t)m * N + n] = v;
                }
            }
        }
    }
}

// ---------------------------------------------------------------------------
// Merged CSR build: (A) row buckets over (batch,node) for segment ownership,
// (B) class CSR over (class,dst) + packed {src, coef}. One block per batch.
// ---------------------------------------------------------------------------
__global__ void csr_all(const int* __restrict__ ent_indices,
                        int* __restrict__ rptr, int* __restrict__ rlist,
                        const int* __restrict__ edge_index, const int* __restrict__ edge_attr,
                        float* __restrict__ degf, int* __restrict__ csr_ptr,
                        int2* __restrict__ csr_sc)
{
    __shared__ int cnt[NC * NNODE];
    __shared__ float dinvl[NC * NNODE];
    const int b = blockIdx.x;
    const int tid = threadIdx.x;

    // ---- phase A: row buckets ----
    const int* idx = ent_indices + (size_t)b * S_;
    for (int i = tid; i < NNODE; i += 256) cnt[i] = 0;
    __syncthreads();
    for (int r = tid; r < S_; r += 256) atomicAdd(&cnt[idx[r]], 1);
    __syncthreads();
    if (tid == 0) {
        int run = 0;
        for (int i = 0; i < NNODE; i++) { const int c = cnt[i]; cnt[i] = run; run += c; }
    }
    __syncthreads();
    for (int i = tid; i < NNODE; i += 256) rptr[b * (NNODE + 1) + i] = cnt[i];
    if (tid == 0) rptr[b * (NNODE + 1) + NNODE] = S_;
    __syncthreads();
    for (int r = tid; r < S_; r += 256) {
        const int pos = atomicAdd(&cnt[idx[r]], 1);
        rlist[(size_t)b * S_ + pos] = r;
    }
    __syncthreads();

    // ---- phase B: class CSR ----
    const int* src = edge_index + (size_t)b * 2 * E_;
    const int* dst = src + E_;
    const int* attr = edge_attr + (size_t)b * E_;
    for (int i = tid; i < NC * NNODE; i += 256) cnt[i] = 0;
    __syncthreads();
    for (int e = tid; e < E_; e += 256) atomicAdd(&cnt[attr[e] * NNODE + dst[e]], 1);
    __syncthreads();
    for (int i = tid; i < NC * NNODE; i += 256) {
        const float d = (float)cnt[i] + 1.0f;
        degf[(size_t)b * NC * NNODE + i] = d;
        dinvl[i] = rsqrtf(d);
    }
    __syncthreads();
    if (tid == 0) {
        int run = 0;
        for (int i = 0; i < NC * NNODE; i++) { const int c = cnt[i]; cnt[i] = run; run += c; }
    }
    __syncthreads();
    for (int i = tid; i < NC * NNODE; i += 256) csr_ptr[(size_t)b * NC * NNODE + i] = cnt[i];
    __syncthreads();
    for (int e = tid; e < E_; e += 256) {
        const int a = attr[e], d = dst[e], s = src[e];
        const int pos = atomicAdd(&cnt[a * NNODE + d], 1);
        const float cf = dinvl[a * NNODE + s] * dinvl[a * NNODE + d];
        csr_sc[(size_t)b * E_ + pos] = make_int2(s, __float_as_int(cf));
    }
}

// ---------------------------------------------------------------------------
// Fused segment-max (bf16 redC) + x0 build. One block owns one (batch,node):
// no atomics. x0b row = [label 16 | relu(max+bias) 512 | pad 16] bf16, pitch 544.
// ---------------------------------------------------------------------------
__global__ __launch_bounds__(256)
void segmax_x0(const u16* __restrict__ redC, const int* __restrict__ rptr,
               const int* __restrict__ rlist, const float* __restrict__ b_red,
               const int* __restrict__ ent_labels, const float* __restrict__ tbl,
               u16* __restrict__ x0b)
{
    const int bn = blockIdx.x;           // b*NNODE + n
    const int b = bn / NNODE, n = bn % NNODE;
    const int tid = threadIdx.x;
    const int c0 = tid * 2;              // two adjacent bf16 cols per thread
    const int start = rptr[b * (NNODE + 1) + n];
    const int end   = (n == 0) ? start : rptr[b * (NNODE + 1) + n + 1];
    float m0 = -INFINITY, m1 = -INFINITY;
    const int* rl = rlist + (size_t)b * S_;
    for (int i = start; i < end; i++) {
        const u16* row = redC + ((size_t)b * S_ + rl[i]) * H_;
        const unsigned v = *(const unsigned*)(row + c0);
        m0 = fmaxf(m0, b2f_lo(v & 0xffffu));
        m1 = fmaxf(m1, b2f_hi(v));
    }
    float h0, h1;
    if (n == 0) { h0 = 0.f; h1 = 0.f; }
    else {
        h0 = fmaxf(m0 + b_red[c0], 0.f);
        h1 = fmaxf(m1 + b_red[c0 + 1], 0.f);
    }
    u16* orow = x0b + (size_t)bn * KPAD;
    *(unsigned*)(orow + 16 + c0) = (unsigned)f2b(h0) | ((unsigned)f2b(h1) << 16);
    if (tid < 16) {
        float v;
        if (n == 0) v = tbl[tid];
        else {
            const int lab = ent_labels[b * (NNODE - 1) + (n - 1)];
            v = (lab != 0) ? tbl[lab * 16 + tid] : 0.f;
        }
        orow[tid] = f2b(v);
    } else if (tid < 32) {
        orow[512 + tid] = 0;             // K-pad cols 528..543
    }
}

template<int OUTB>
__global__ void build_x0(const float* __restrict__ seg, const int* __restrict__ ent_labels,
                         const float* __restrict__ tbl, float* __restrict__ x0f,
                         u16* __restrict__ x0b)
{
    const int bn = blockIdx.x;
    const int b = bn / NNODE, n = bn % NNODE;
    const int CMAX = OUTB ? KPAD : D_;
    for (int col = threadIdx.x; col < CMAX; col += blockDim.x) {
        float v;
        if (col >= D_) {
            v = 0.f;
        } else if (col < 16) {
            if (n == 0) v = tbl[col];
            else {
                const int lab = ent_labels[b * (NNODE - 1) + (n - 1)];
                v = (lab != 0) ? tbl[lab * 16 + col] : 0.f;
            }
        } else {
            v = (n == 0) ? 0.f : seg[(((size_t)b * NNODE + n) << 9) + (col - 16)];
        }
        if (OUTB) x0b[(size_t)bn * KPAD + col] = f2b(v);
        else      x0f[(size_t)bn * D_ + col] = v;
    }
}

// ---------------------------------------------------------------------------
// GCN gather on bf16 h planes (pitch KPAD, z-strided). Paired-u32 loads:
// thread t owns cols {2t, 2t+1}; threads 0..7 additionally own {512+2t, 513+2t}.
// OUT: 0 bf16 write (pitch KPAD, zero K-pad); 2 f32 write (pitch D_, z-strided)
// ---------------------------------------------------------------------------
template<int OUT>
__global__ __launch_bounds__(256)
void gcn_gather(const u16* __restrict__ h, size_t hstride,
                const float* __restrict__ degf,
                const int* __restrict__ csr_ptr, const int2* __restrict__ csr_sc,
                const float* __restrict__ bias_base, size_t bias_stride,
                float* __restrict__ outf, u16* __restrict__ outb, size_t ostride)
{
    const int bn = blockIdx.x;
    const int cls = blockIdx.y;
    const int b = bn / NNODE, n = bn % NNODE;
    const int tid = threadIdx.x;
    const int base = b * NC * NNODE + cls * NNODE + n;
    const float d = degf[base];
    const int start = csr_ptr[base];
    const int cnt = (int)d - 1;
    const float inv = 1.0f / d;
    const u16* hp = h + cls * hstride;
    const float* bias = bias_base + cls * bias_stride;
    const u16* hrow = hp + (size_t)bn * KPAD;
    const int c0 = 2 * tid;                 // cols 0..511
    const int c1 = 512 + 2 * tid;           // cols 512..527 (tid < 8)
    const bool hi = (tid < 8);
    unsigned v = *(const unsigned*)(hrow + c0);
    float a0 = b2f_lo(v & 0xffffu) * inv + bias[c0];
    float a1 = b2f_hi(v) * inv + bias[c0 + 1];
    float a2 = 0.f, a3 = 0.f;
    if (hi) {
        v = *(const unsigned*)(hrow + c1);
        a2 = b2f_lo(v & 0xffffu) * inv + bias[c1];
        a3 = b2f_hi(v) * inv + bias[c1 + 1];
    }
    const int2* scp = csr_sc + (size_t)b * E_ + start;
    int2 sc = (cnt > 0) ? scp[0] : make_int2(0, 0);
    for (int i = 0; i < cnt; i++) {
        const int2 cur = sc;
        if (i + 1 < cnt) sc = scp[i + 1];     // prefetch: break dependent chain
        const float cf = __int_as_float(cur.y);
        const u16* hs = hp + ((size_t)b * NNODE + cur.x) * KPAD;
        v = *(const unsigned*)(hs + c0);
        a0 += cf * b2f_lo(v & 0xffffu);
        a1 += cf * b2f_hi(v);
        if (hi) {
            v = *(const unsigned*)(hs + c1);
            a2 += cf * b2f_lo(v & 0xffffu);
            a3 += cf * b2f_hi(v);
        }
    }
    if (OUT == 0) {
        u16* orow = outb + cls * ostride + (size_t)bn * KPAD;
        *(unsigned*)(orow + c0) = (unsigned)f2b(a0) | ((unsigned)f2b(a1) << 16);
        if (hi) *(unsigned*)(orow + c1) = (unsigned)f2b(a2) | ((unsigned)f2b(a3) << 16);
        if (tid >= 8 && tid < 16)                   // zero K-pad cols 528..543
            *(unsigned*)(orow + 528 + 2 * (tid - 8)) = 0;
    } else {
        float* orow = outf + cls * ostride + (size_t)bn * D_;
        orow[c0] = a0; orow[c0 + 1] = a1;
        if (hi) { orow[c1] = a2; orow[c1 + 1] = a3; }
    }
}

// fallback-only gather on f32 h planes. OUT: 1 fp32 +=; 2 fp32 =
template<int OUT>
__global__ __launch_bounds__(256)
void gcn_gather_f32(const float* __restrict__ h, size_t hstride,
                    const float* __restrict__ degf,
                    const int* __restrict__ csr_ptr, const int2* __restrict__ csr_sc,
                    const float* __restrict__ bias_base, size_t bias_stride,
                    float* __restrict__ outf, int cls0)
{
    const int bn = blockIdx.x;
    const int cls = cls0 + blockIdx.y;
    const int b = bn / NNODE, n = bn % NNODE;
    const int tid = threadIdx.x;
    const int base = b * NC * NNODE + cls * NNODE + n;
    const float d = degf[base];
    const int start = csr_ptr[base];
    const int cnt = (int)d - 1;
    const float inv = 1.0f / d;
    const float* hp = h + blockIdx.y * hstride;
    const float* bias = bias_base + cls * bias_stride;
    const float* hrow = hp + (size_t)bn * D_;
    const int c0 = tid, c1 = tid + 256, c2 = tid + 512;
    float a0 = hrow[c0] * inv + bias[c0];
    float a1 = hrow[c1] * inv + bias[c1];
    float a2 = (c2 < D_) ? hrow[c2] * inv + bias[c2] : 0.f;
    const int2* scp = csr_sc + (size_t)b * E_ + start;
    for (int i = 0; i < cnt; i++) {
        const int2 sc = scp[i];
        const float cf = __int_as_float(sc.y);
        const float* hs = hp + ((size_t)b * NNODE + sc.x) * D_;
        a0 += cf * hs[c0];
        a1 += cf * hs[c1];
        if (c2 < D_) a2 += cf * hs[c2];
    }
    if (OUT == 1) {
        float* orow = outf + (size_t)bn * D_;
        orow[c0] += a0; orow[c1] += a1; if (c2 < D_) orow[c2] += a2;
    } else {
        float* orow = outf + (size_t)bn * D_;
        orow[c0] = a0; orow[c1] = a1; if (c2 < D_) orow[c2] = a2;
    }
}

__global__ void rowdot3(const float* __restrict__ x, const float* __restrict__ w,
                        float* __restrict__ out)
{
    const int row = blockIdx.x;
    const int lane = threadIdx.x;
    float a0 = 0.f, a1 = 0.f, a2 = 0.f;
    for (int d = lane; d < D_; d += 64) {
        const float xv = x[(size_t)row * D_ + d];
        a0 += xv * w[d * 3 + 0];
        a1 += xv * w[d * 3 + 1];
        a2 += xv * w[d * 3 + 2];
    }
#pragma unroll
    for (int off = 32; off > 0; off >>= 1) {
        a0 += __shfl_down(a0, off, 64);
        a1 += __shfl_down(a1, off, 64);
        a2 += __shfl_down(a2, off, 64);
    }
    if (lane == 0) {
        out[(size_t)row * 3 + 0] = a0;
        out[(size_t)row * 3 + 1] = a1;
        out[(size_t)row * 3 + 2] = a2;
    }
}

// one kernel: Whw = W_head@W_out, Wtw = W_tail@W_out, bias6 = {b_head,b_tail}@W_out
__global__ void prep_heads(const float* __restrict__ W_head, const float* __restrict__ W_tail,
                           const float* __restrict__ b_head, const float* __restrict__ b_tail,
                           const float* __restrict__ W_out,
                           float* __restrict__ Whw, float* __restrict__ Wtw,
                           float* __restrict__ bias6)
{
    const int r = blockIdx.x;            // 0..2*D_+1
    const int lane = threadIdx.x;
    const float* x; float* o;
    if (r < D_)            { x = W_head + (size_t)r * D_;        o = Whw + (size_t)r * 3; }
    else if (r < 2 * D_)   { x = W_tail + (size_t)(r - D_) * D_; o = Wtw + (size_t)(r - D_) * 3; }
    else if (r == 2 * D_)  { x = b_head;                         o = bias6; }
    else                   { x = b_tail;                         o = bias6 + 3; }
    float a0 = 0.f, a1 = 0.f, a2 = 0.f;
    for (int d = lane; d < D_; d += 64) {
        const float xv = x[d];
        a0 += xv * W_out[d * 3 + 0];
        a1 += xv * W_out[d * 3 + 1];
        a2 += xv * W_out[d * 3 + 2];
    }
#pragma unroll
    for (int off = 32; off > 0; off >>= 1) {
        a0 += __shfl_down(a0, off, 64);
        a1 += __shfl_down(a1, off, 64);
        a2 += __shfl_down(a2, off, 64);
    }
    if (lane == 0) { o[0] = a0; o[1] = a1; o[2] = a2; }
}

// hw/tw from 3 class planes: x = (p0+p1+p2)/3; 4 rows per block (1 wave each)
__global__ __launch_bounds__(256)
void rowdot6(const float* __restrict__ x3, size_t zstride,
             const float* __restrict__ Whw, const float* __restrict__ Wtw,
             const float* __restrict__ bias6,
             float* __restrict__ hw, float* __restrict__ tw)
{
    const int row = blockIdx.x * 4 + (threadIdx.x >> 6);
    const int lane = threadIdx.x & 63;
    const float* p0 = x3 + (size_t)row * D_;
    const float* p1 = p0 + zstride;
    const float* p2 = p1 + zstride;
    float h0 = 0.f, h1 = 0.f, h2 = 0.f, t0 = 0.f, t1 = 0.f, t2 = 0.f;
    for (int d = lane; d < D_; d += 64) {
        const float xv = (p0[d] + p1[d] + p2[d]) * (1.f / 3.f);
        h0 += xv * Whw[d * 3 + 0]; h1 += xv * Whw[d * 3 + 1]; h2 += xv * Whw[d * 3 + 2];
        t0 += xv * Wtw[d * 3 + 0]; t1 += xv * Wtw[d * 3 + 1]; t2 += xv * Wtw[d * 3 + 2];
    }
#pragma unroll
    for (int off = 32; off > 0; off >>= 1) {
        h0 += __shfl_down(h0, off, 64); h1 += __shfl_down(h1, off, 64); h2 += __shfl_down(h2, off, 64);
        t0 += __shfl_down(t0, off, 64); t1 += __shfl_down(t1, off, 64); t2 += __shfl_down(t2, off, 64);
    }
    if (lane == 0) {
        hw[(size_t)row * 3 + 0] = h0 + bias6[0];
        hw[(size_t)row * 3 + 1] = h1 + bias6[1];
        hw[(size_t)row * 3 + 2] = h2 + bias6[2];
        tw[(size_t)row * 3 + 0] = t0 + bias6[3];
        tw[(size_t)row * 3 + 1] = t1 + bias6[4];
        tw[(size_t)row * 3 + 2] = t2 + bias6[5];
    }
}

__global__ __launch_bounds__(256)
void final_logits(const float* __restrict__ hw, const float* __restrict__ tw,
                  const int* __restrict__ cands, const float* __restrict__ b_out,
                  float* __restrict__ out)
{
    const int bi = blockIdx.x;
    const int b = bi / NNODE;
    const int j = threadIdx.x;
    const float h0 = hw[bi * 3 + 0], h1 = hw[bi * 3 + 1], h2 = hw[bi * 3 + 2];
    const int tj = b * NNODE + 1 + j;
    const float t0 = tw[tj * 3 + 0], t1 = tw[tj * 3 + 1], t2 = tw[tj * 3 + 2];
    const float m = (cands[(size_t)bi * NNODE + 1 + j] != 0) ? 1.f : 0.f;
    const float bo0 = b_out[0], bo1 = b_out[1], bo2 = b_out[2];
    const size_t o = ((size_t)bi * 256 + j) * 3;
    out[o + 0] = (h0 + t0) * m + bo0;
    out[o + 1] = (h1 + t1) * m + bo1;
    out[o + 2] = (h2 + t2) * m + bo2;
}

extern "C" void kernel_launch(void* const* d_in, const int* in_sizes, int n_in,
                              void* d_out, int out_size, void* d_ws, size_t ws_size,
                              hipStream_t stream)
{
    const float* emb       = (const float*)d_in[0];
    const int* ent_indices = (const int*)d_in[1];
    const int* ent_labels  = (const int*)d_in[2];
    const int* edge_index  = (const int*)d_in[3];
    const int* edge_attr   = (const int*)d_in[4];
    const int* cands       = (const int*)d_in[5];
    const float* W_red     = (const float*)d_in[6];
    const float* b_red     = (const float*)d_in[7];
    const float* tbl       = (const float*)d_in[8];
    const float* W_gcn     = (const float*)d_in[9];
    const float* b_gcn     = (const float*)d_in[10];
    const float* W_head    = (const float*)d_in[11];
    const float* b_head    = (const float*)d_in[12];
    const float* W_tail    = (const float*)d_in[13];
    const float* b_tail    = (const float*)d_in[14];
    const float* W_out     = (const float*)d_in[15];
    const float* b_out     = (const float*)d_in[16];

    char* ws = (char*)d_ws;
    size_t off = 0;
    auto alloc = [&](size_t nbytes) -> char* {
        char* p = ws + off; off = (off + nbytes + 255) & ~(size_t)255; return p;
    };
    const size_t ROWB  = (size_t)NROW * D_ * sizeof(float);
    const size_t RD    = (size_t)NROW * D_;         // f32 plane stride (pitch 528)
    const size_t RD2   = (size_t)NROW * KPAD;       // bf16 plane stride (pitch 544)
    const size_t WGZ   = (size_t)2 * D_ * KPAD;     // wgcnT z-stride (2 layers)

    // region R0: emb_bf (phase 1), then hbB[3 bf16 planes] + x1b[3 bf16 planes]
    char* R0      = alloc((size_t)B_ * S_ * ETR_ * sizeof(u16)); // 50.3 MB
    u16*  emb_bf  = (u16*)R0;
    u16*  hbB     = (u16*)R0;                                    // [3][NROW][544] bf16 = 13.4 MB
    u16*  x1b     = (u16*)(R0 + (size_t)16 * 1024 * 1024);       // [3][NROW][544] bf16 = 13.4 MB
    // region R1: redC bf16 (phase 1), then result3 [3][NROW][528] f32 (epilogue)
    char* R1      = alloc((size_t)B_ * S_ * H_ * sizeof(u16));   // 33.6 MB
    u16*  redC    = (u16*)R1;
    float* result3 = (float*)R1;                                 // 26.1 MB fits
    int*  rptr    = (int*)alloc((size_t)B_ * (NNODE + 1) * 4);
    int*  rlist   = (int*)alloc((size_t)B_ * S_ * 4);
    u16*  x0b     = (u16*)alloc((size_t)NROW * KPAD * sizeof(u16));
    u16*  wredT   = (u16*)alloc((size_t)H_ * ETR_ * sizeof(u16));    // [512][768]
    u16*  wgcnT   = (u16*)alloc((size_t)NC * WGZ * sizeof(u16));     // [3][2][528][544]
    float* Whw    = (float*)alloc((size_t)D_ * 3 * 4);
    float* Wtw    = (float*)alloc((size_t)D_ * 3 * 4);
    float* bias6  = (float*)alloc(6 * 4);
    float* degf   = (float*)alloc((size_t)B_ * NC * NNODE * 4);
    float* hwp    = (float*)alloc((size_t)NROW * 3 * 4);
    float* twp    = (float*)alloc((size_t)NROW * 3 * 4);
    int* csr_ptr  = (int*)alloc((size_t)B_ * NC * NNODE * 4);
    int2* csr_sc  = (int2*)alloc((size_t)B_ * E_ * 8);
    const bool fast = (ws_size >= off);

    if (fast) {
        const int n4e = (B_ * S_ * ETR_) / 4;
        cvt_bf16<<<(n4e + 255) / 256, 256, 0, stream>>>(emb, emb_bf, n4e);
        transpose_cvt<<<dim3(16, 24, 1), 256, 0, stream>>>(W_red, wredT, ETR_, H_, 0, 0, ETR_);
        hipMemsetAsync(wgcnT, 0, (size_t)NC * WGZ * sizeof(u16), stream);  // K-pad zeros
        transpose_cvt<<<dim3(17, 17, 6), 256, 0, stream>>>(W_gcn, wgcnT, D_, D_, DD, (size_t)D_ * KPAD, KPAD);

        // fused head/tail weights (single launch)
        prep_heads<<<2 * D_ + 2, 64, 0, stream>>>(W_head, W_tail, b_head, b_tail, W_out,
                                                  Whw, Wtw, bias6);

        // merged row-bucket CSR + class CSR (one launch)
        csr_all<<<B_, 256, 0, stream>>>(ent_indices, rptr, rlist,
                                        edge_index, edge_attr, degf, csr_ptr, csr_sc);

        // 1) reduction GEMM (bf16 gll16 both sides, dbuf pipeline) -> bf16 redC
        gemm_mfma<1, 1><<<dim3(H_ / BN, (B_ * S_) / BM, 1), 256, 0, stream>>>(
            emb_bf, wredT, nullptr, 0, redC, B_ * S_, H_, ETR_, 1.f, 0, 0, 0, H_);
        // 2) fused exclusive-owner segment max + x0 build (zero atomics)
        segmax_x0<<<B_ * NNODE, 256, 0, stream>>>(redC, rptr, rlist, b_red,
                                                  ent_labels, tbl, x0b);

        // 3) GCN layer 1: GEMM (shared x0 A-plane) -> bf16 h; gather on bf16 h
        dim3 gmm((D_ + BN - 1) / BN, (NROW + BM - 1) / BM, NC);   // 5 x 33 x 3
        gemm_mfma<0, 1><<<gmm, 256, 0, stream>>>(
            x0b, wgcnT, nullptr, 0, hbB, NROW, D_, KPAD, 1.f, 0, WGZ, RD2, KPAD);
        gcn_gather<0><<<dim3(NROW, NC), 256, 0, stream>>>(
            hbB, RD2, degf, csr_ptr, csr_sc, b_gcn, (size_t)2 * D_,
            nullptr, x1b, RD2);
        // 4) GCN layer 2
        gemm_mfma<0, 1><<<gmm, 256, 0, stream>>>(
            x1b, wgcnT + (size_t)D_ * KPAD, nullptr, 0, hbB, NROW, D_, KPAD, 1.f,
            RD2, WGZ, RD2, KPAD);
        gcn_gather<2><<<dim3(NROW, NC), 256, 0, stream>>>(
            hbB, RD2, degf, csr_ptr, csr_sc, b_gcn + D_, (size_t)2 * D_,
            result3, nullptr, RD);

        // 5) fused epilogue: sum 3 planes inside rowdot6 (no atomics, no memset)
        rowdot6<<<NROW / 4, 256, 0, stream>>>(result3, RD, Whw, Wtw, bias6, hwp, twp);
        final_logits<<<NROW, 256, 0, stream>>>(hwp, twp, cands, b_out, (float*)d_out);
        return;
    }

    // -------- fallback: proven fp32 pipeline --------
    off = 0;
    float* bufA = (float*)alloc(ROWB);
    float* bufB = (float*)alloc(ROWB);
    float* bufC = (float*)alloc(ROWB);
    float* bufD = (float*)alloc(ROWB);
    degf = (float*)alloc((size_t)B_ * NC * NNODE * 4);
    hwp  = (float*)alloc((size_t)NROW * 3 * 4);
    twp  = (float*)alloc((size_t)NROW * 3 * 4);
    csr_ptr = (int*)alloc((size_t)B_ * NC * NNODE * 4);
    csr_sc  = (int2*)alloc((size_t)B_ * E_ * 8);
    int* rptr2  = (int*)alloc((size_t)B_ * (NNODE + 1) * 4);
    int* rlist2 = (int*)alloc((size_t)B_ * S_ * 4);

    hipMemsetAsync(bufA, 0, (size_t)B_ * NNODE * H_ * 4, stream);
    hipMemsetAsync(bufD, 0, ROWB, stream);
    gemm64<1><<<dim3(H_ / 64, (B_ * S_) / 64), 256, 0, stream>>>(
        emb, W_red, b_red, nullptr, B_ * S_, H_, ETR_, 1.f, ent_indices, bufA);
    build_x0<0><<<NROW, 256, 0, stream>>>(bufA, ent_labels, tbl, bufB, nullptr);
    csr_all<<<B_, 256, 0, stream>>>(ent_indices, rptr2, rlist2,
                                    edge_index, edge_attr, degf, csr_ptr, csr_sc);
    dim3 gridG((D_ + 63) / 64, (NROW + 63) / 64);
    for (int c = 0; c < NC; c++) {
        gemm64<0><<<gridG, 256, 0, stream>>>(bufB, W_gcn + (size_t)(c * 2 + 0) * DD,
            nullptr, bufA, NROW, D_, D_, 1.f, nullptr, nullptr);
        gcn_gather_f32<2><<<dim3(NROW, 1), 256, 0, stream>>>(bufA, 0, degf, csr_ptr, csr_sc,
            b_gcn, (size_t)2 * D_, bufC, c);
        gemm64<0><<<gridG, 256, 0, stream>>>(bufC, W_gcn + (size_t)(c * 2 + 1) * DD,
            nullptr, bufA, NROW, D_, D_, 1.f, nullptr, nullptr);
        gcn_gather_f32<1><<<dim3(NROW, 1), 256, 0, stream>>>(bufA, 0, degf, csr_ptr, csr_sc,
            b_gcn + D_, (size_t)2 * D_, bufD, c);
    }
    gemm64<0><<<gridG, 256, 0, stream>>>(bufD, W_head, b_head, bufB,
        NROW, D_, D_, 1.f / 3.f, nullptr, nullptr);
    gemm64<0><<<gridG, 256, 0, stream>>>(bufD, W_tail, b_tail, bufC,
        NROW, D_, D_, 1.f / 3.f, nullptr, nullptr);
    rowdot3<<<NROW, 64, 0, stream>>>(bufB, W_out, hwp);
    rowdot3<<<NROW, 64, 0, stream>>>(bufC, W_out, twp);
    final_logits<<<NROW, 256, 0, stream>>>(hwp, twp, cands, b_out, (float*)d_out);
}

// Round 12
// 400.114 us; speedup vs baseline: 1.0819x; 1.0482x over previous
//
#include <hip/hip_runtime.h>
#include <hip/hip_bf16.h>

typedef unsigned short u16;
typedef __attribute__((ext_vector_type(8))) short short8;
typedef __attribute__((ext_vector_type(4))) float floatx4;

#define B_ 16
#define S_ 2048
#define NNODE 257
#define E_ 4096
#define ETR_ 768
#define H_ 512
#define D_ 528
#define KPAD 544          // K padded to a BK multiple for MFMA GEMMs
#define NC 3
#define NROW (B_*NNODE)   // 4112
#define DD (D_*D_)

#define BM 128
#define BN 128
#define BK 32

__device__ inline u16 f2b(float x) {
    __hip_bfloat16 h = __float2bfloat16(x);
    return *(u16*)&h;
}
__device__ inline float b2f(u16 u) {
    return __uint_as_float(((unsigned)u) << 16);
}
__device__ inline float b2f_lo(unsigned v) { return __uint_as_float(v << 16); }
__device__ inline float b2f_hi(unsigned v) { return __uint_as_float(v & 0xffff0000u); }

// async global->LDS, 16B per lane (m97 structure). LDS dest must be linear:
// HW writes wave-uniform base + lane*16.
__device__ inline void gll16(const u16* g, u16* l) {
    __builtin_amdgcn_global_load_lds(
        (const __attribute__((address_space(1))) void*)g,
        (__attribute__((address_space(3))) void*)l,
        16, 0, 0);
}

__device__ inline int clampi(int v, int hi) { return v < hi ? v : hi; }

// 256-thread in-place EXCLUSIVE prefix sum of cnt[0..n), n <= 1024.
// Two-level: per-thread 4-chunk + shfl wave-scan + wave offsets in wsums[4].
// Caller must __syncthreads() after return before consuming cnt.
__device__ inline void exscan_lds(int* cnt, int n, int tid, int* wsums)
{
    const int lane = tid & 63, wave = tid >> 6;
    int v[4];
    int ts = 0;
#pragma unroll
    for (int j = 0; j < 4; j++) {
        const int i = tid * 4 + j;
        v[j] = (i < n) ? cnt[i] : 0;
        ts += v[j];
    }
    int inc = ts;
#pragma unroll
    for (int off = 1; off < 64; off <<= 1) {
        const int o = __shfl_up(inc, off, 64);
        if (lane >= off) inc += o;
    }
    if (lane == 63) wsums[wave] = inc;
    __syncthreads();
    int woff = 0;
#pragma unroll
    for (int w = 0; w < 4; w++) if (w < wave) woff += wsums[w];
    int run = woff + inc - ts;           // exclusive base of this thread's chunk
#pragma unroll
    for (int j = 0; j < 4; j++) {
        const int i = tid * 4 + j;
        if (i < n) { const int c = v[j]; cnt[i] = run; run += c; }
    }
}

__global__ void cvt_bf16(const float* __restrict__ in, u16* __restrict__ out, int n4)
{
    const int i = blockIdx.x * 256 + threadIdx.x;
    if (i < n4) {
        const float4 f = ((const float4*)in)[i];
        ushort4 o;
        o.x = f2b(f.x); o.y = f2b(f.y); o.z = f2b(f.z); o.w = f2b(f.w);
        ((ushort4*)out)[i] = o;
    }
}

// in f32 [R][C] (z-batched) -> out bf16 [C][R] with out pitch opitch (>= R).
// Pad columns r in [R, opitch) are written as 0 (grid-y must cover opitch).
__global__ void transpose_cvt(const float* __restrict__ in, u16* __restrict__ out,
                              int R, int Cc, size_t instride, size_t outstride,
                              int opitch)
{
    __shared__ float t[32][33];
    const int z = blockIdx.z;
    const int tx = threadIdx.x & 31, ty = threadIdx.x >> 5;  // 32 x 8
    const int c0 = blockIdx.x * 32, r0 = blockIdx.y * 32;
    const float* ip = in + z * instride;
    u16* op = out + z * outstride;
#pragma unroll
    for (int i = 0; i < 4; i++) {
        const int r = r0 + ty + i * 8, c = c0 + tx;
        if (r < R && c < Cc) t[ty + i * 8][tx] = ip[(size_t)r * Cc + c];
    }
    __syncthreads();
#pragma unroll
    for (int i = 0; i < 4; i++) {
        const int c = c0 + ty + i * 8, r = r0 + tx;
        if (c < Cc && r < opitch) {
            const u16 val = (r < R) ? f2b(t[tx][ty + i * 8]) : (u16)0;
            op[(size_t)c * opitch + r] = val;
        }
    }
}

// ---------------------------------------------------------------------------
// bf16 MFMA GEMM: 128x128 tile, BK=32, DOUBLE-BUFFERED 32KB LDS,
// global_load_lds width-16 staging both operands, prefetch-depth-1,
// ONE barrier per K-step. LDS chunk-swizzle (source-permuted, read-XOR).
// A[M][K], Wt[N][K] bf16 (row pitch K, K % 32 == 0), z-batched.
// SWZ: XCD-locality remap (gridDim.x==4). OB16: bf16 output.
// Epilogue: C = acc*scale + bias[z][n]; row pitch cpitch, z-stride cstride.
// ---------------------------------------------------------------------------
template<int SWZ, int OB16>
__global__ __launch_bounds__(256)
void gemm_mfma(const u16* __restrict__ A, const u16* __restrict__ Wt,
               const float* __restrict__ bias_base, size_t bias_stride,
               void* __restrict__ Cv, int M, int N, int K, float scale,
               size_t astride, size_t wstride, size_t cstride, int cpitch)
{
    __shared__ u16 SS[16384];  // two 16KB buffers: buf b at b*8192 (u16 units)
    const int tid = threadIdx.x;
    const int wave = tid >> 6, lane = tid & 63;
    const int quad = lane >> 4, l16 = lane & 15;
    const int z = blockIdx.z;
    int bx = blockIdx.x, by = blockIdx.y;
    if (SWZ) {   // gridDim.x==4: keep the 4 col-blocks of a row-block on one XCD
        const int lin = blockIdx.x + (blockIdx.y << 2);
        bx = (lin >> 3) & 3;
        by = (lin & 7) + ((lin >> 5) << 3);
    }
    const int m0 = by * BM, n0 = bx * BN;

    floatx4 acc[2][8];
#pragma unroll
    for (int t = 0; t < 2; t++)
#pragma unroll
        for (int u = 0; u < 8; u++)
#pragma unroll
            for (int r = 0; r < 4; r++) acc[t][u][r] = 0.f;

    // staging map: LDS slot (tid&3) of row (tid>>2) receives GLOBAL chunk
    // (tid&3) ^ ((row>>1)&3) -- the bank-conflict swizzle, applied at the source.
    const int srow = tid >> 2;                                   // 0..63
    const int scol = (((tid & 3) ^ ((srow >> 1) & 3))) * 8;      // swizzled chunk
    const u16* aP0 = A + z * astride + (size_t)clampi(m0 + srow,      M - 1) * K + scol;
    const u16* aP1 = A + z * astride + (size_t)clampi(m0 + 64 + srow, M - 1) * K + scol;
    const u16* bP0 = Wt + z * wstride + (size_t)clampi(n0 + srow,      N - 1) * K + scol;
    const u16* bP1 = Wt + z * wstride + (size_t)clampi(n0 + 64 + srow, N - 1) * K + scol;
    const int lsw = wave * 512;       // per-wave offset within a buffer (u16)

    // read-side swizzle term: all fragment rows reduce to sw = (l16>>1)&3
    const int sw8 = ((l16 >> 1) & 3) * 8;

    // prologue: stage K-tile 0 into buffer 0
    {
        u16* d = &SS[lsw];
        gll16(aP0, d);
        gll16(aP1, d + 2048);
        gll16(bP0, d + 4096);
        gll16(bP1, d + 6144);
    }
    __syncthreads();

    const int nt = K / BK;
    int cur = 0;
    for (int t = 0; t < nt; ++t) {
        // issue next-tile loads FIRST: latency hides under this tile's compute
        if (t + 1 < nt) {
            const int kn = (t + 1) * BK;
            u16* d = &SS[(cur ^ 1) * 8192 + lsw];
            gll16(aP0 + kn, d);
            gll16(aP1 + kn, d + 2048);
            gll16(bP0 + kn, d + 4096);
            gll16(bP1 + kn, d + 6144);
        }
        const u16* Sb = &SS[cur * 8192];
        short8 af[2], bfv[8];
        af[0] = *(const short8*)&Sb[(wave * 32 + l16) * 32 + ((quad * 8) ^ sw8)];
        af[1] = *(const short8*)&Sb[(wave * 32 + 16 + l16) * 32 + ((quad * 8) ^ sw8)];
#pragma unroll
        for (int u = 0; u < 8; u++)
            bfv[u] = *(const short8*)&Sb[4096 + (u * 16 + l16) * 32 + ((quad * 8) ^ sw8)];
#pragma unroll
        for (int t2 = 0; t2 < 2; t2++)
#pragma unroll
            for (int u = 0; u < 8; u++)
                acc[t2][u] = __builtin_amdgcn_mfma_f32_16x16x32_bf16(af[t2], bfv[u], acc[t2][u], 0, 0, 0);
        __syncthreads();   // drains this tile's reads AND next tile's writes
        cur ^= 1;
    }

    const float* bias = bias_base ? (bias_base + z * bias_stride) : nullptr;
#pragma unroll
    for (int t = 0; t < 2; t++) {
#pragma unroll
        for (int r = 0; r < 4; r++) {
            const int m = m0 + wave * 32 + t * 16 + quad * 4 + r;
            if (m >= M) continue;
#pragma unroll
            for (int u = 0; u < 8; u++) {
                const int n = n0 + u * 16 + l16;
                if (n < N) {
                    const float v = acc[t][u][r] * scale + (bias ? bias[n] : 0.f);
                    if (OB16) {
                        u16* Cb = (u16*)Cv;
                        Cb[z * cstride + (size_t)m * cpitch + n] = f2b(v);
                    } else {
                        float* Cf = (float*)Cv;
                        Cf[z * cstride + (size_t)m * cpitch + n] = v;
                    }
                }
            }
        }
    }
}

// ---------------------------------------------------------------------------
// fp32 64x64 GEMM (fallback path only)
// ---------------------------------------------------------------------------
template<int MODE>
__global__ __launch_bounds__(256)
void gemm64(const float* __restrict__ A, const float* __restrict__ W,
            const float* __restrict__ bias, float* __restrict__ C,
            int M, int N, int K, float scale,
            const int* __restrict__ segidx, float* __restrict__ segout)
{
    __shared__ float Asl[16][68];
    __shared__ float Bsl[16][64];
    const int tid = threadIdx.x;
    const int tx = tid & 15, ty = tid >> 4;
    const int m0 = blockIdx.y * 64, n0 = blockIdx.x * 64;
    const int arow = tid >> 2, acol = (tid & 3) * 4;
    const int brow = tid >> 4, bcol = (tid & 15) * 4;

    float acc[4][4];
#pragma unroll
    for (int i = 0; i < 4; i++)
#pragma unroll
        for (int j = 0; j < 4; j++) acc[i][j] = 0.f;

    for (int kk = 0; kk < K; kk += 16) {
        float4 av = make_float4(0.f, 0.f, 0.f, 0.f);
        if (m0 + arow < M) av = *(const float4*)(A + (size_t)(m0 + arow) * K + kk + acol);
        Asl[acol + 0][arow] = av.x; Asl[acol + 1][arow] = av.y;
        Asl[acol + 2][arow] = av.z; Asl[acol + 3][arow] = av.w;
        float4 bv = make_float4(0.f, 0.f, 0.f, 0.f);
        if (n0 + bcol < N) bv = *(const float4*)(W + (size_t)(kk + brow) * N + n0 + bcol);
        *(float4*)&Bsl[brow][bcol] = bv;
        __syncthreads();
#pragma unroll
        for (int k = 0; k < 16; k++) {
            const float4 a = *(const float4*)&Asl[k][ty * 4];
            const float4 b = *(const float4*)&Bsl[k][tx * 4];
            const float af[4] = { a.x, a.y, a.z, a.w };
            const float bfv[4] = { b.x, b.y, b.z, b.w };
#pragma unroll
            for (int i = 0; i < 4; i++)
#pragma unroll
                for (int j = 0; j < 4; j++) acc[i][j] += af[i] * bfv[j];
        }
        __syncthreads();
    }

#pragma unroll
    for (int i = 0; i < 4; i++) {
        const int m = m0 + ty * 4 + i;
        if (m >= M) continue;
        if (MODE == 1) {
            const int bb = m >> 11;
            const int idx = segidx[m];
            float* const srow = segout + (((size_t)bb * NNODE + idx) << 9);
#pragma unroll
            for (int j = 0; j < 4; j++) {
                const int n = n0 + tx * 4 + j;
                const float v = acc[i][j] + (bias ? bias[n] : 0.f);
                atomicMax(((int*)srow) + n, __float_as_int(v));
            }
        } else {
#pragma unroll
            for (int j = 0; j < 4; j++) {
                const int n = n0 + tx * 4 + j;
                if (n < N) {
                    const float v = acc[i][j] * scale + (bias ? bias[n] : 0.f);
                    C[(size_t)m * N + n] = v;
                }
            }
        }
    }
}

// ---------------------------------------------------------------------------
// Merged CSR build: (A) row buckets over (batch,node) for segment ownership,
// (B) class CSR over (class,dst) + packed {src, coef}. One block per batch.
// Prefix sums via 256-thread two-level scan (was: serial thread-0 loops).
// ---------------------------------------------------------------------------
__global__ void csr_all(const int* __restrict__ ent_indices,
                        int* __restrict__ rptr, int* __restrict__ rlist,
                        const int* __restrict__ edge_index, const int* __restrict__ edge_attr,
                        float* __restrict__ degf, int* __restrict__ csr_ptr,
                        int2* __restrict__ csr_sc)
{
    __shared__ int cnt[NC * NNODE];
    __shared__ float dinvl[NC * NNODE];
    __shared__ int wsums[4];
    const int b = blockIdx.x;
    const int tid = threadIdx.x;

    // ---- phase A: row buckets ----
    const int* idx = ent_indices + (size_t)b * S_;
    for (int i = tid; i < NNODE; i += 256) cnt[i] = 0;
    __syncthreads();
    for (int r = tid; r < S_; r += 256) atomicAdd(&cnt[idx[r]], 1);
    __syncthreads();
    exscan_lds(cnt, NNODE, tid, wsums);
    __syncthreads();
    for (int i = tid; i < NNODE; i += 256) rptr[b * (NNODE + 1) + i] = cnt[i];
    if (tid == 0) rptr[b * (NNODE + 1) + NNODE] = S_;
    __syncthreads();
    for (int r = tid; r < S_; r += 256) {
        const int pos = atomicAdd(&cnt[idx[r]], 1);
        rlist[(size_t)b * S_ + pos] = r;
    }
    __syncthreads();

    // ---- phase B: class CSR ----
    const int* src = edge_index + (size_t)b * 2 * E_;
    const int* dst = src + E_;
    const int* attr = edge_attr + (size_t)b * E_;
    for (int i = tid; i < NC * NNODE; i += 256) cnt[i] = 0;
    __syncthreads();
    for (int e = tid; e < E_; e += 256) atomicAdd(&cnt[attr[e] * NNODE + dst[e]], 1);
    __syncthreads();
    for (int i = tid; i < NC * NNODE; i += 256) {
        const float d = (float)cnt[i] + 1.0f;
        degf[(size_t)b * NC * NNODE + i] = d;
        dinvl[i] = rsqrtf(d);
    }
    __syncthreads();
    exscan_lds(cnt, NC * NNODE, tid, wsums);
    __syncthreads();
    for (int i = tid; i < NC * NNODE; i += 256) csr_ptr[(size_t)b * NC * NNODE + i] = cnt[i];
    __syncthreads();
    for (int e = tid; e < E_; e += 256) {
        const int a = attr[e], d = dst[e], s = src[e];
        const int pos = atomicAdd(&cnt[a * NNODE + d], 1);
        const float cf = dinvl[a * NNODE + s] * dinvl[a * NNODE + d];
        csr_sc[(size_t)b * E_ + pos] = make_int2(s, __float_as_int(cf));
    }
}

// ---------------------------------------------------------------------------
// Fused segment-max (bf16 redC) + x0 build. One block owns one (batch,node):
// no atomics. x0b row = [label 16 | relu(max+bias) 512 | pad 16] bf16, pitch 544.
// ---------------------------------------------------------------------------
__global__ __launch_bounds__(256)
void segmax_x0(const u16* __restrict__ redC, const int* __restrict__ rptr,
               const int* __restrict__ rlist, const float* __restrict__ b_red,
               const int* __restrict__ ent_labels, const float* __restrict__ tbl,
               u16* __restrict__ x0b)
{
    const int bn = blockIdx.x;           // b*NNODE + n
    const int b = bn / NNODE, n = bn % NNODE;
    const int tid = threadIdx.x;
    const int c0 = tid * 2;              // two adjacent bf16 cols per thread
    const int start = rptr[b * (NNODE + 1) + n];
    const int end   = (n == 0) ? start : rptr[b * (NNODE + 1) + n + 1];
    float m0 = -INFINITY, m1 = -INFINITY;
    const int* rl = rlist + (size_t)b * S_;
    int nr = (start < end) ? rl[start] : 0;
    for (int i = start; i < end; i++) {
        const int r = nr;
        if (i + 1 < end) nr = rl[i + 1];          // prefetch: break dependent chain
        const u16* row = redC + ((size_t)b * S_ + r) * H_;
        const unsigned v = *(const unsigned*)(row + c0);
        m0 = fmaxf(m0, b2f_lo(v & 0xffffu));
        m1 = fmaxf(m1, b2f_hi(v));
    }
    float h0, h1;
    if (n == 0) { h0 = 0.f; h1 = 0.f; }
    else {
        h0 = fmaxf(m0 + b_red[c0], 0.f);
        h1 = fmaxf(m1 + b_red[c0 + 1], 0.f);
    }
    u16* orow = x0b + (size_t)bn * KPAD;
    *(unsigned*)(orow + 16 + c0) = (unsigned)f2b(h0) | ((unsigned)f2b(h1) << 16);
    if (tid < 16) {
        float v;
        if (n == 0) v = tbl[tid];
        else {
            const int lab = ent_labels[b * (NNODE - 1) + (n - 1)];
            v = (lab != 0) ? tbl[lab * 16 + tid] : 0.f;
        }
        orow[tid] = f2b(v);
    } else if (tid < 32) {
        orow[512 + tid] = 0;             // K-pad cols 528..543
    }
}

template<int OUTB>
__global__ void build_x0(const float* __restrict__ seg, const int* __restrict__ ent_labels,
                         const float* __restrict__ tbl, float* __restrict__ x0f,
                         u16* __restrict__ x0b)
{
    const int bn = blockIdx.x;
    const int b = bn / NNODE, n = bn % NNODE;
    const int CMAX = OUTB ? KPAD : D_;
    for (int col = threadIdx.x; col < CMAX; col += blockDim.x) {
        float v;
        if (col >= D_) {
            v = 0.f;
        } else if (col < 16) {
            if (n == 0) v = tbl[col];
            else {
                const int lab = ent_labels[b * (NNODE - 1) + (n - 1)];
                v = (lab != 0) ? tbl[lab * 16 + col] : 0.f;
            }
        } else {
            v = (n == 0) ? 0.f : seg[(((size_t)b * NNODE + n) << 9) + (col - 16)];
        }
        if (OUTB) x0b[(size_t)bn * KPAD + col] = f2b(v);
        else      x0f[(size_t)bn * D_ + col] = v;
    }
}

// ---------------------------------------------------------------------------
// GCN gather on bf16 h planes (pitch KPAD, z-strided). Paired-u32 loads:
// thread t owns cols {2t, 2t+1}; threads 0..7 additionally own {512+2t, 513+2t}.
// OUT: 0 bf16 write (pitch KPAD, zero K-pad); 2 f32 write (pitch D_, z-strided)
// ---------------------------------------------------------------------------
template<int OUT>
__global__ __launch_bounds__(256)
void gcn_gather(const u16* __restrict__ h, size_t hstride,
                const float* __restrict__ degf,
                const int* __restrict__ csr_ptr, const int2* __restrict__ csr_sc,
                const float* __restrict__ bias_base, size_t bias_stride,
                float* __restrict__ outf, u16* __restrict__ outb, size_t ostride)
{
    const int bn = blockIdx.x;
    const int cls = blockIdx.y;
    const int b = bn / NNODE, n = bn % NNODE;
    const int tid = threadIdx.x;
    const int base = b * NC * NNODE + cls * NNODE + n;
    const float d = degf[base];
    const int start = csr_ptr[base];
    const int cnt = (int)d - 1;
    const float inv = 1.0f / d;
    const u16* hp = h + cls * hstride;
    const float* bias = bias_base + cls * bias_stride;
    const u16* hrow = hp + (size_t)bn * KPAD;
    const int c0 = 2 * tid;                 // cols 0..511
    const int c1 = 512 + 2 * tid;           // cols 512..527 (tid < 8)
    const bool hi = (tid < 8);
    unsigned v = *(const unsigned*)(hrow + c0);
    float a0 = b2f_lo(v & 0xffffu) * inv + bias[c0];
    float a1 = b2f_hi(v) * inv + bias[c0 + 1];
    float a2 = 0.f, a3 = 0.f;
    if (hi) {
        v = *(const unsigned*)(hrow + c1);
        a2 = b2f_lo(v & 0xffffu) * inv + bias[c1];
        a3 = b2f_hi(v) * inv + bias[c1 + 1];
    }
    const int2* scp = csr_sc + (size_t)b * E_ + start;
    int2 sc = (cnt > 0) ? scp[0] : make_int2(0, 0);
    for (int i = 0; i < cnt; i++) {
        const int2 cur = sc;
        if (i + 1 < cnt) sc = scp[i + 1];     // prefetch: break dependent chain
        const float cf = __int_as_float(cur.y);
        const u16* hs = hp + ((size_t)b * NNODE + cur.x) * KPAD;
        v = *(const unsigned*)(hs + c0);
        a0 += cf * b2f_lo(v & 0xffffu);
        a1 += cf * b2f_hi(v);
        if (hi) {
            v = *(const unsigned*)(hs + c1);
            a2 += cf * b2f_lo(v & 0xffffu);
            a3 += cf * b2f_hi(v);
        }
    }
    if (OUT == 0) {
        u16* orow = outb + cls * ostride + (size_t)bn * KPAD;
        *(unsigned*)(orow + c0) = (unsigned)f2b(a0) | ((unsigned)f2b(a1) << 16);
        if (hi) *(unsigned*)(orow + c1) = (unsigned)f2b(a2) | ((unsigned)f2b(a3) << 16);
        if (tid >= 8 && tid < 16)                   // zero K-pad cols 528..543
            *(unsigned*)(orow + 528 + 2 * (tid - 8)) = 0;
    } else {
        float* orow = outf + cls * ostride + (size_t)bn * D_;
        orow[c0] = a0; orow[c0 + 1] = a1;
        if (hi) { orow[c1] = a2; orow[c1 + 1] = a3; }
    }
}

// fallback-only gather on f32 h planes. OUT: 1 fp32 +=; 2 fp32 =
template<int OUT>
__global__ __launch_bounds__(256)
void gcn_gather_f32(const float* __restrict__ h, size_t hstride,
                    const float* __restrict__ degf,
                    const int* __restrict__ csr_ptr, const int2* __restrict__ csr_sc,
                    const float* __restrict__ bias_base, size_t bias_stride,
                    float* __restrict__ outf, int cls0)
{
    const int bn = blockIdx.x;
    const int cls = cls0 + blockIdx.y;
    const int b = bn / NNODE, n = bn % NNODE;
    const int tid = threadIdx.x;
    const int base = b * NC * NNODE + cls * NNODE + n;
    const float d = degf[base];
    const int start = csr_ptr[base];
    const int cnt = (int)d - 1;
    const float inv = 1.0f / d;
    const float* hp = h + blockIdx.y * hstride;
    const float* bias = bias_base + cls * bias_stride;
    const float* hrow = hp + (size_t)bn * D_;
    const int c0 = tid, c1 = tid + 256, c2 = tid + 512;
    float a0 = hrow[c0] * inv + bias[c0];
    float a1 = hrow[c1] * inv + bias[c1];
    float a2 = (c2 < D_) ? hrow[c2] * inv + bias[c2] : 0.f;
    const int2* scp = csr_sc + (size_t)b * E_ + start;
    for (int i = 0; i < cnt; i++) {
        const int2 sc = scp[i];
        const float cf = __int_as_float(sc.y);
        const float* hs = hp + ((size_t)b * NNODE + sc.x) * D_;
        a0 += cf * hs[c0];
        a1 += cf * hs[c1];
        if (c2 < D_) a2 += cf * hs[c2];
    }
    if (OUT == 1) {
        float* orow = outf + (size_t)bn * D_;
        orow[c0] += a0; orow[c1] += a1; if (c2 < D_) orow[c2] += a2;
    } else {
        float* orow = outf + (size_t)bn * D_;
        orow[c0] = a0; orow[c1] = a1; if (c2 < D_) orow[c2] = a2;
    }
}

__global__ void rowdot3(const float* __restrict__ x, const float* __restrict__ w,
                        float* __restrict__ out)
{
    const int row = blockIdx.x;
    const int lane = threadIdx.x;
    float a0 = 0.f, a1 = 0.f, a2 = 0.f;
    for (int d = lane; d < D_; d += 64) {
        const float xv = x[(size_t)row * D_ + d];
        a0 += xv * w[d * 3 + 0];
        a1 += xv * w[d * 3 + 1];
        a2 += xv * w[d * 3 + 2];
    }
#pragma unroll
    for (int off = 32; off > 0; off >>= 1) {
        a0 += __shfl_down(a0, off, 64);
        a1 += __shfl_down(a1, off, 64);
        a2 += __shfl_down(a2, off, 64);
    }
    if (lane == 0) {
        out[(size_t)row * 3 + 0] = a0;
        out[(size_t)row * 3 + 1] = a1;
        out[(size_t)row * 3 + 2] = a2;
    }
}

// one kernel: Whw = W_head@W_out, Wtw = W_tail@W_out, bias6 = {b_head,b_tail}@W_out
__global__ void prep_heads(const float* __restrict__ W_head, const float* __restrict__ W_tail,
                           const float* __restrict__ b_head, const float* __restrict__ b_tail,
                           const float* __restrict__ W_out,
                           float* __restrict__ Whw, float* __restrict__ Wtw,
                           float* __restrict__ bias6)
{
    const int r = blockIdx.x;            // 0..2*D_+1
    const int lane = threadIdx.x;
    const float* x; float* o;
    if (r < D_)            { x = W_head + (size_t)r * D_;        o = Whw + (size_t)r * 3; }
    else if (r < 2 * D_)   { x = W_tail + (size_t)(r - D_) * D_; o = Wtw + (size_t)(r - D_) * 3; }
    else if (r == 2 * D_)  { x = b_head;                         o = bias6; }
    else                   { x = b_tail;                         o = bias6 + 3; }
    float a0 = 0.f, a1 = 0.f, a2 = 0.f;
    for (int d = lane; d < D_; d += 64) {
        const float xv = x[d];
        a0 += xv * W_out[d * 3 + 0];
        a1 += xv * W_out[d * 3 + 1];
        a2 += xv * W_out[d * 3 + 2];
    }
#pragma unroll
    for (int off = 32; off > 0; off >>= 1) {
        a0 += __shfl_down(a0, off, 64);
        a1 += __shfl_down(a1, off, 64);
        a2 += __shfl_down(a2, off, 64);
    }
    if (lane == 0) { o[0] = a0; o[1] = a1; o[2] = a2; }
}

// hw/tw from 3 class planes: x = (p0+p1+p2)/3; 4 rows per block (1 wave each)
__global__ __launch_bounds__(256)
void rowdot6(const float* __restrict__ x3, size_t zstride,
             const float* __restrict__ Whw, const float* __restrict__ Wtw,
             const float* __restrict__ bias6,
             float* __restrict__ hw, float* __restrict__ tw)
{
    const int row = blockIdx.x * 4 + (threadIdx.x >> 6);
    const int lane = threadIdx.x & 63;
    const float* p0 = x3 + (size_t)row * D_;
    const float* p1 = p0 + zstride;
    const float* p2 = p1 + zstride;
    float h0 = 0.f, h1 = 0.f, h2 = 0.f, t0 = 0.f, t1 = 0.f, t2 = 0.f;
    for (int d = lane; d < D_; d += 64) {
        const float xv = (p0[d] + p1[d] + p2[d]) * (1.f / 3.f);
        h0 += xv * Whw[d * 3 + 0]; h1 += xv * Whw[d * 3 + 1]; h2 += xv * Whw[d * 3 + 2];
        t0 += xv * Wtw[d * 3 + 0]; t1 += xv * Wtw[d * 3 + 1]; t2 += xv * Wtw[d * 3 + 2];
    }
#pragma unroll
    for (int off = 32; off > 0; off >>= 1) {
        h0 += __shfl_down(h0, off, 64); h1 += __shfl_down(h1, off, 64); h2 += __shfl_down(h2, off, 64);
        t0 += __shfl_down(t0, off, 64); t1 += __shfl_down(t1, off, 64); t2 += __shfl_down(t2, off, 64);
    }
    if (lane == 0) {
        hw[(size_t)row * 3 + 0] = h0 + bias6[0];
        hw[(size_t)row * 3 + 1] = h1 + bias6[1];
        hw[(size_t)row * 3 + 2] = h2 + bias6[2];
        tw[(size_t)row * 3 + 0] = t0 + bias6[3];
        tw[(size_t)row * 3 + 1] = t1 + bias6[4];
        tw[(size_t)row * 3 + 2] = t2 + bias6[5];
    }
}

__global__ __launch_bounds__(256)
void final_logits(const float* __restrict__ hw, const float* __restrict__ tw,
                  const int* __restrict__ cands, const float* __restrict__ b_out,
                  float* __restrict__ out)
{
    const int bi = blockIdx.x;
    const int b = bi / NNODE;
    const int j = threadIdx.x;
    const float h0 = hw[bi * 3 + 0], h1 = hw[bi * 3 + 1], h2 = hw[bi * 3 + 2];
    const int tj = b * NNODE + 1 + j;
    const float t0 = tw[tj * 3 + 0], t1 = tw[tj * 3 + 1], t2 = tw[tj * 3 + 2];
    const float m = (cands[(size_t)bi * NNODE + 1 + j] != 0) ? 1.f : 0.f;
    const float bo0 = b_out[0], bo1 = b_out[1], bo2 = b_out[2];
    const size_t o = ((size_t)bi * 256 + j) * 3;
    out[o + 0] = (h0 + t0) * m + bo0;
    out[o + 1] = (h1 + t1) * m + bo1;
    out[o + 2] = (h2 + t2) * m + bo2;
}

extern "C" void kernel_launch(void* const* d_in, const int* in_sizes, int n_in,
                              void* d_out, int out_size, void* d_ws, size_t ws_size,
                              hipStream_t stream)
{
    const float* emb       = (const float*)d_in[0];
    const int* ent_indices = (const int*)d_in[1];
    const int* ent_labels  = (const int*)d_in[2];
    const int* edge_index  = (const int*)d_in[3];
    const int* edge_attr   = (const int*)d_in[4];
    const int* cands       = (const int*)d_in[5];
    const float* W_red     = (const float*)d_in[6];
    const float* b_red     = (const float*)d_in[7];
    const float* tbl       = (const float*)d_in[8];
    const float* W_gcn     = (const float*)d_in[9];
    const float* b_gcn     = (const float*)d_in[10];
    const float* W_head    = (const float*)d_in[11];
    const float* b_head    = (const float*)d_in[12];
    const float* W_tail    = (const float*)d_in[13];
    const float* b_tail    = (const float*)d_in[14];
    const float* W_out     = (const float*)d_in[15];
    const float* b_out     = (const float*)d_in[16];

    char* ws = (char*)d_ws;
    size_t off = 0;
    auto alloc = [&](size_t nbytes) -> char* {
        char* p = ws + off; off = (off + nbytes + 255) & ~(size_t)255; return p;
    };
    const size_t ROWB  = (size_t)NROW * D_ * sizeof(float);
    const size_t RD    = (size_t)NROW * D_;         // f32 plane stride (pitch 528)
    const size_t RD2   = (size_t)NROW * KPAD;       // bf16 plane stride (pitch 544)
    const size_t WGZ   = (size_t)2 * D_ * KPAD;     // wgcnT z-stride (2 layers)

    // region R0: emb_bf (phase 1), then hbB[3 bf16 planes] + x1b[3 bf16 planes]
    char* R0      = alloc((size_t)B_ * S_ * ETR_ * sizeof(u16)); // 50.3 MB
    u16*  emb_bf  = (u16*)R0;
    u16*  hbB     = (u16*)R0;                                    // [3][NROW][544] bf16 = 13.4 MB
    u16*  x1b     = (u16*)(R0 + (size_t)16 * 1024 * 1024);       // [3][NROW][544] bf16 = 13.4 MB
    // region R1: redC bf16 (phase 1), then result3 [3][NROW][528] f32 (epilogue)
    char* R1      = alloc((size_t)B_ * S_ * H_ * sizeof(u16));   // 33.6 MB
    u16*  redC    = (u16*)R1;
    float* result3 = (float*)R1;                                 // 26.1 MB fits
    int*  rptr    = (int*)alloc((size_t)B_ * (NNODE + 1) * 4);
    int*  rlist   = (int*)alloc((size_t)B_ * S_ * 4);
    u16*  x0b     = (u16*)alloc((size_t)NROW * KPAD * sizeof(u16));
    u16*  wredT   = (u16*)alloc((size_t)H_ * ETR_ * sizeof(u16));    // [512][768]
    u16*  wgcnT   = (u16*)alloc((size_t)NC * WGZ * sizeof(u16));     // [3][2][528][544]
    float* Whw    = (float*)alloc((size_t)D_ * 3 * 4);
    float* Wtw    = (float*)alloc((size_t)D_ * 3 * 4);
    float* bias6  = (float*)alloc(6 * 4);
    float* degf   = (float*)alloc((size_t)B_ * NC * NNODE * 4);
    float* hwp    = (float*)alloc((size_t)NROW * 3 * 4);
    float* twp    = (float*)alloc((size_t)NROW * 3 * 4);
    int* csr_ptr  = (int*)alloc((size_t)B_ * NC * NNODE * 4);
    int2* csr_sc  = (int2*)alloc((size_t)B_ * E_ * 8);
    const bool fast = (ws_size >= off);

    if (fast) {
        const int n4e = (B_ * S_ * ETR_) / 4;
        cvt_bf16<<<(n4e + 255) / 256, 256, 0, stream>>>(emb, emb_bf, n4e);
        transpose_cvt<<<dim3(16, 24, 1), 256, 0, stream>>>(W_red, wredT, ETR_, H_, 0, 0, ETR_);
        // wgcnT K-pad (cols 528..543) written as zeros by transpose_cvt itself
        transpose_cvt<<<dim3(17, 17, 6), 256, 0, stream>>>(W_gcn, wgcnT, D_, D_, DD, (size_t)D_ * KPAD, KPAD);

        // fused head/tail weights (single launch)
        prep_heads<<<2 * D_ + 2, 64, 0, stream>>>(W_head, W_tail, b_head, b_tail, W_out,
                                                  Whw, Wtw, bias6);

        // merged row-bucket CSR + class CSR (one launch, parallel scans)
        csr_all<<<B_, 256, 0, stream>>>(ent_indices, rptr, rlist,
                                        edge_index, edge_attr, degf, csr_ptr, csr_sc);

        // 1) reduction GEMM (bf16 gll16 both sides, dbuf pipeline) -> bf16 redC
        gemm_mfma<1, 1><<<dim3(H_ / BN, (B_ * S_) / BM, 1), 256, 0, stream>>>(
            emb_bf, wredT, nullptr, 0, redC, B_ * S_, H_, ETR_, 1.f, 0, 0, 0, H_);
        // 2) fused exclusive-owner segment max + x0 build (zero atomics)
        segmax_x0<<<B_ * NNODE, 256, 0, stream>>>(redC, rptr, rlist, b_red,
                                                  ent_labels, tbl, x0b);

        // 3) GCN layer 1: GEMM (shared x0 A-plane) -> bf16 h; gather on bf16 h
        dim3 gmm((D_ + BN - 1) / BN, (NROW + BM - 1) / BM, NC);   // 5 x 33 x 3
        gemm_mfma<0, 1><<<gmm, 256, 0, stream>>>(
            x0b, wgcnT, nullptr, 0, hbB, NROW, D_, KPAD, 1.f, 0, WGZ, RD2, KPAD);
        gcn_gather<0><<<dim3(NROW, NC), 256, 0, stream>>>(
            hbB, RD2, degf, csr_ptr, csr_sc, b_gcn, (size_t)2 * D_,
            nullptr, x1b, RD2);
        // 4) GCN layer 2
        gemm_mfma<0, 1><<<gmm, 256, 0, stream>>>(
            x1b, wgcnT + (size_t)D_ * KPAD, nullptr, 0, hbB, NROW, D_, KPAD, 1.f,
            RD2, WGZ, RD2, KPAD);
        gcn_gather<2><<<dim3(NROW, NC), 256, 0, stream>>>(
            hbB, RD2, degf, csr_ptr, csr_sc, b_gcn + D_, (size_t)2 * D_,
            result3, nullptr, RD);

        // 5) fused epilogue: sum 3 planes inside rowdot6 (no atomics, no memset)
        rowdot6<<<NROW / 4, 256, 0, stream>>>(result3, RD, Whw, Wtw, bias6, hwp, twp);
        final_logits<<<NROW, 256, 0, stream>>>(hwp, twp, cands, b_out, (float*)d_out);
        return;
    }

    // -------- fallback: proven fp32 pipeline --------
    off = 0;
    float* bufA = (float*)alloc(ROWB);
    float* bufB = (float*)alloc(ROWB);
    float* bufC = (float*)alloc(ROWB);
    float* bufD = (float*)alloc(ROWB);
    degf = (float*)alloc((size_t)B_ * NC * NNODE * 4);
    hwp  = (float*)alloc((size_t)NROW * 3 * 4);
    twp  = (float*)alloc((size_t)NROW * 3 * 4);
    csr_ptr = (int*)alloc((size_t)B_ * NC * NNODE * 4);
    csr_sc  = (int2*)alloc((size_t)B_ * E_ * 8);
    int* rptr2  = (int*)alloc((size_t)B_ * (NNODE + 1) * 4);
    int* rlist2 = (int*)alloc((size_t)B_ * S_ * 4);

    hipMemsetAsync(bufA, 0, (size_t)B_ * NNODE * H_ * 4, stream);
    hipMemsetAsync(bufD, 0, ROWB, stream);
    gemm64<1><<<dim3(H_ / 64, (B_ * S_) / 64), 256, 0, stream>>>(
        emb, W_red, b_red, nullptr, B_ * S_, H_, ETR_, 1.f, ent_indices, bufA);
    build_x0<0><<<NROW, 256, 0, stream>>>(bufA, ent_labels, tbl, bufB, nullptr);
    csr_all<<<B_, 256, 0, stream>>>(ent_indices, rptr2, rlist2,
                                    edge_index, edge_attr, degf, csr_ptr, csr_sc);
    dim3 gridG((D_ + 63) / 64, (NROW + 63) / 64);
    for (int c = 0; c < NC; c++) {
        gemm64<0><<<gridG, 256, 0, stream>>>(bufB, W_gcn + (size_t)(c * 2 + 0) * DD,
            nullptr, bufA, NROW, D_, D_, 1.f, nullptr, nullptr);
        gcn_gather_f32<2><<<dim3(NROW, 1), 256, 0, stream>>>(bufA, 0, degf, csr_ptr, csr_sc,
            b_gcn, (size_t)2 * D_, bufC, c);
        gemm64<0><<<gridG, 256, 0, stream>>>(bufC, W_gcn + (size_t)(c * 2 + 1) * DD,
            nullptr, bufA, NROW, D_, D_, 1.f, nullptr, nullptr);
        gcn_gather_f32<1><<<dim3(NROW, 1), 256, 0, stream>>>(bufA, 0, degf, csr_ptr, csr_sc,
            b_gcn + D_, (size_t)2 * D_, bufD, c);
    }
    gemm64<0><<<gridG, 256, 0, stream>>>(bufD, W_head, b_head, bufB,
        NROW, D_, D_, 1.f / 3.f, nullptr, nullptr);
    gemm64<0><<<gridG, 256, 0, stream>>>(bufD, W_tail, b_tail, bufC,
        NROW, D_, D_, 1.f / 3.f, nullptr, nullptr);
    rowdot3<<<NROW, 64, 0, stream>>>(bufB, W_out, hwp);
    rowdot3<<<NROW, 64, 0, stream>>>(bufC, W_out, twp);
    final_logits<<<NROW, 256, 0, stream>>>(hwp, twp, cands, b_out, (float*)d_out);
}

// Round 13
// 396.219 us; speedup vs baseline: 1.0926x; 1.0098x over previous
//
#include <hip/hip_runtime.h>
#include <hip/hip_bf16.h>

typedef unsigned short u16;
typedef __attribute__((ext_vector_type(8))) short short8;
typedef __attribute__((ext_vector_type(4))) float floatx4;

#define B_ 16
#define S_ 2048
#define NNODE 257
#define E_ 4096
#define ETR_ 768
#define H_ 512
#define D_ 528
#define KPAD 544          // K padded to a BK multiple for MFMA GEMMs
#define NC 3
#define NROW (B_*NNODE)   // 4112
#define DD (D_*D_)

#define BM 128
#define BN 128
#define BK 32

__device__ inline u16 f2b(float x) {
    __hip_bfloat16 h = __float2bfloat16(x);
    return *(u16*)&h;
}
__device__ inline float b2f(u16 u) {
    return __uint_as_float(((unsigned)u) << 16);
}
__device__ inline float b2f_lo(unsigned v) { return __uint_as_float(v << 16); }
__device__ inline float b2f_hi(unsigned v) { return __uint_as_float(v & 0xffff0000u); }

// async global->LDS, 16B per lane (m97 structure). LDS dest must be linear:
// HW writes wave-uniform base + lane*16.
__device__ inline void gll16(const u16* g, u16* l) {
    __builtin_amdgcn_global_load_lds(
        (const __attribute__((address_space(1))) void*)g,
        (__attribute__((address_space(3))) void*)l,
        16, 0, 0);
}

__device__ inline int clampi(int v, int hi) { return v < hi ? v : hi; }

// 256-thread in-place EXCLUSIVE prefix sum of cnt[0..n), n <= 1024.
__device__ inline void exscan_lds(int* cnt, int n, int tid, int* wsums)
{
    const int lane = tid & 63, wave = tid >> 6;
    int v[4];
    int ts = 0;
#pragma unroll
    for (int j = 0; j < 4; j++) {
        const int i = tid * 4 + j;
        v[j] = (i < n) ? cnt[i] : 0;
        ts += v[j];
    }
    int inc = ts;
#pragma unroll
    for (int off = 1; off < 64; off <<= 1) {
        const int o = __shfl_up(inc, off, 64);
        if (lane >= off) inc += o;
    }
    if (lane == 63) wsums[wave] = inc;
    __syncthreads();
    int woff = 0;
#pragma unroll
    for (int w = 0; w < 4; w++) if (w < wave) woff += wsums[w];
    int run = woff + inc - ts;           // exclusive base of this thread's chunk
#pragma unroll
    for (int j = 0; j < 4; j++) {
        const int i = tid * 4 + j;
        if (i < n) { const int c = v[j]; cnt[i] = run; run += c; }
    }
}

__global__ void cvt_bf16(const float* __restrict__ in, u16* __restrict__ out, int n4)
{
    const int i = blockIdx.x * 256 + threadIdx.x;
    if (i < n4) {
        const float4 f = ((const float4*)in)[i];
        ushort4 o;
        o.x = f2b(f.x); o.y = f2b(f.y); o.z = f2b(f.z); o.w = f2b(f.w);
        ((ushort4*)out)[i] = o;
    }
}

// in f32 [R][C] (z-batched) -> out bf16 [C][R] with out pitch opitch (>= R).
// Pad columns r in [R, opitch) are written as 0 (grid-y must cover opitch).
__global__ void transpose_cvt(const float* __restrict__ in, u16* __restrict__ out,
                              int R, int Cc, size_t instride, size_t outstride,
                              int opitch)
{
    __shared__ float t[32][33];
    const int z = blockIdx.z;
    const int tx = threadIdx.x & 31, ty = threadIdx.x >> 5;  // 32 x 8
    const int c0 = blockIdx.x * 32, r0 = blockIdx.y * 32;
    const float* ip = in + z * instride;
    u16* op = out + z * outstride;
#pragma unroll
    for (int i = 0; i < 4; i++) {
        const int r = r0 + ty + i * 8, c = c0 + tx;
        if (r < R && c < Cc) t[ty + i * 8][tx] = ip[(size_t)r * Cc + c];
    }
    __syncthreads();
#pragma unroll
    for (int i = 0; i < 4; i++) {
        const int c = c0 + ty + i * 8, r = r0 + tx;
        if (c < Cc && r < opitch) {
            const u16 val = (r < R) ? f2b(t[tx][ty + i * 8]) : (u16)0;
            op[(size_t)c * opitch + r] = val;
        }
    }
}

// ---------------------------------------------------------------------------
// bf16 MFMA GEMM: 128x128 tile, BK=32, TRIPLE-BUFFERED 48KB LDS,
// prefetch-depth-2 with COUNTED vmcnt (T3+T4): the main loop never drains
// vmcnt to 0 -- loads get ~2 iterations to land.
// Per iter: vmcnt(4) -> s_barrier -> ds_read -> lgkmcnt(0)+sched_barrier ->
// s_barrier (WAR) -> issue stage(t+2) -> MFMA.
// LDS chunk-swizzle (source-permuted, read-XOR). A[M][K], Wt[N][K] bf16
// (row pitch K, K % 32 == 0), z-batched. SWZ: XCD remap (gridDim.x==4).
// OB16: bf16 output. Epilogue: C = acc*scale + bias[z][n].
// ---------------------------------------------------------------------------
template<int SWZ, int OB16>
__global__ __launch_bounds__(256)
void gemm_mfma(const u16* __restrict__ A, const u16* __restrict__ Wt,
               const float* __restrict__ bias_base, size_t bias_stride,
               void* __restrict__ Cv, int M, int N, int K, float scale,
               size_t astride, size_t wstride, size_t cstride, int cpitch)
{
    __shared__ u16 SS[24576];  // three 16KB buffers: buf b at b*8192 (u16 units)
    const int tid = threadIdx.x;
    const int wave = tid >> 6, lane = tid & 63;
    const int quad = lane >> 4, l16 = lane & 15;
    const int z = blockIdx.z;
    int bx = blockIdx.x, by = blockIdx.y;
    if (SWZ) {   // gridDim.x==4: keep the 4 col-blocks of a row-block on one XCD
        const int lin = blockIdx.x + (blockIdx.y << 2);
        bx = (lin >> 3) & 3;
        by = (lin & 7) + ((lin >> 5) << 3);
    }
    const int m0 = by * BM, n0 = bx * BN;

    floatx4 acc[2][8];
#pragma unroll
    for (int t = 0; t < 2; t++)
#pragma unroll
        for (int u = 0; u < 8; u++)
#pragma unroll
            for (int r = 0; r < 4; r++) acc[t][u][r] = 0.f;

    // staging map: LDS slot (tid&3) of row (tid>>2) receives GLOBAL chunk
    // (tid&3) ^ ((row>>1)&3) -- the bank-conflict swizzle, applied at the source.
    const int srow = tid >> 2;                                   // 0..63
    const int scol = (((tid & 3) ^ ((srow >> 1) & 3))) * 8;      // swizzled chunk
    const u16* aP0 = A + z * astride + (size_t)clampi(m0 + srow,      M - 1) * K + scol;
    const u16* aP1 = A + z * astride + (size_t)clampi(m0 + 64 + srow, M - 1) * K + scol;
    const u16* bP0 = Wt + z * wstride + (size_t)clampi(n0 + srow,      N - 1) * K + scol;
    const u16* bP1 = Wt + z * wstride + (size_t)clampi(n0 + 64 + srow, N - 1) * K + scol;
    const int lsw = wave * 512;       // per-wave offset within a buffer (u16)

    // read-side swizzle term: all fragment rows reduce to sw = (l16>>1)&3
    const int sw8 = ((l16 >> 1) & 3) * 8;

    const int nt = K / BK;

    // prologue: stage tiles 0 and 1
    {
        u16* d = &SS[lsw];
        gll16(aP0, d); gll16(aP1, d + 2048);
        gll16(bP0, d + 4096); gll16(bP1, d + 6144);
    }
    if (nt > 1) {
        const int k1 = BK;
        u16* d = &SS[8192 + lsw];
        gll16(aP0 + k1, d); gll16(aP1 + k1, d + 2048);
        gll16(bP0 + k1, d + 4096); gll16(bP1 + k1, d + 6144);
    }

    int cur = 0;
    for (int t = 0; t < nt; ++t) {
        // 1) ensure buf[cur] landed: only the newest 4 loads (tile t+1) may
        //    remain outstanding. When staging has stopped, drain fully.
        if (t + 1 < nt) asm volatile("s_waitcnt vmcnt(4)" ::: "memory");
        else            asm volatile("s_waitcnt vmcnt(0)" ::: "memory");
        __builtin_amdgcn_s_barrier();

        // 2) read fragments from buf[cur]
        const u16* Sb = &SS[cur * 8192];
        short8 af[2], bfv[8];
        af[0] = *(const short8*)&Sb[(wave * 32 + l16) * 32 + ((quad * 8) ^ sw8)];
        af[1] = *(const short8*)&Sb[(wave * 32 + 16 + l16) * 32 + ((quad * 8) ^ sw8)];
#pragma unroll
        for (int u = 0; u < 8; u++)
            bfv[u] = *(const short8*)&Sb[4096 + (u * 16 + l16) * 32 + ((quad * 8) ^ sw8)];
        asm volatile("s_waitcnt lgkmcnt(0)" ::: "memory");
        __builtin_amdgcn_sched_barrier(0);
        __builtin_amdgcn_s_barrier();      // all waves' reads done -> safe to overwrite

        // 3) issue stage for tile t+2 (overwrites buffer read at iter t-1)
        if (t + 2 < nt) {
            int s = cur + 2; if (s >= 3) s -= 3;
            const int kn = (t + 2) * BK;
            u16* d = &SS[s * 8192 + lsw];
            gll16(aP0 + kn, d); gll16(aP1 + kn, d + 2048);
            gll16(bP0 + kn, d + 4096); gll16(bP1 + kn, d + 6144);
        }

        // 4) MFMA (register-only; loads fly underneath)
#pragma unroll
        for (int t2 = 0; t2 < 2; t2++)
#pragma unroll
            for (int u = 0; u < 8; u++)
                acc[t2][u] = __builtin_amdgcn_mfma_f32_16x16x32_bf16(af[t2], bfv[u], acc[t2][u], 0, 0, 0);

        cur = (cur == 2) ? 0 : cur + 1;
    }

    const float* bias = bias_base ? (bias_base + z * bias_stride) : nullptr;
#pragma unroll
    for (int t = 0; t < 2; t++) {
#pragma unroll
        for (int r = 0; r < 4; r++) {
            const int m = m0 + wave * 32 + t * 16 + quad * 4 + r;
            if (m >= M) continue;
#pragma unroll
            for (int u = 0; u < 8; u++) {
                const int n = n0 + u * 16 + l16;
                if (n < N) {
                    const float v = acc[t][u][r] * scale + (bias ? bias[n] : 0.f);
                    if (OB16) {
                        u16* Cb = (u16*)Cv;
                        Cb[z * cstride + (size_t)m * cpitch + n] = f2b(v);
                    } else {
                        float* Cf = (float*)Cv;
                        Cf[z * cstride + (size_t)m * cpitch + n] = v;
                    }
                }
            }
        }
    }
}

// ---------------------------------------------------------------------------
// fp32 64x64 GEMM (fallback path only)
// ---------------------------------------------------------------------------
template<int MODE>
__global__ __launch_bounds__(256)
void gemm64(const float* __restrict__ A, const float* __restrict__ W,
            const float* __restrict__ bias, float* __restrict__ C,
            int M, int N, int K, float scale,
            const int* __restrict__ segidx, float* __restrict__ segout)
{
    __shared__ float Asl[16][68];
    __shared__ float Bsl[16][64];
    const int tid = threadIdx.x;
    const int tx = tid & 15, ty = tid >> 4;
    const int m0 = blockIdx.y * 64, n0 = blockIdx.x * 64;
    const int arow = tid >> 2, acol = (tid & 3) * 4;
    const int brow = tid >> 4, bcol = (tid & 15) * 4;

    float acc[4][4];
#pragma unroll
    for (int i = 0; i < 4; i++)
#pragma unroll
        for (int j = 0; j < 4; j++) acc[i][j] = 0.f;

    for (int kk = 0; kk < K; kk += 16) {
        float4 av = make_float4(0.f, 0.f, 0.f, 0.f);
        if (m0 + arow < M) av = *(const float4*)(A + (size_t)(m0 + arow) * K + kk + acol);
        Asl[acol + 0][arow] = av.x; Asl[acol + 1][arow] = av.y;
        Asl[acol + 2][arow] = av.z; Asl[acol + 3][arow] = av.w;
        float4 bv = make_float4(0.f, 0.f, 0.f, 0.f);
        if (n0 + bcol < N) bv = *(const float4*)(W + (size_t)(kk + brow) * N + n0 + bcol);
        *(float4*)&Bsl[brow][bcol] = bv;
        __syncthreads();
#pragma unroll
        for (int k = 0; k < 16; k++) {
            const float4 a = *(const float4*)&Asl[k][ty * 4];
            const float4 b = *(const float4*)&Bsl[k][tx * 4];
            const float af[4] = { a.x, a.y, a.z, a.w };
            const float bfv[4] = { b.x, b.y, b.z, b.w };
#pragma unroll
            for (int i = 0; i < 4; i++)
#pragma unroll
                for (int j = 0; j < 4; j++) acc[i][j] += af[i] * bfv[j];
        }
        __syncthreads();
    }

#pragma unroll
    for (int i = 0; i < 4; i++) {
        const int m = m0 + ty * 4 + i;
        if (m >= M) continue;
        if (MODE == 1) {
            const int bb = m >> 11;
            const int idx = segidx[m];
            float* const srow = segout + (((size_t)bb * NNODE + idx) << 9);
#pragma unroll
            for (int j = 0; j < 4; j++) {
                const int n = n0 + tx * 4 + j;
                const float v = acc[i][j] + (bias ? bias[n] : 0.f);
                atomicMax(((int*)srow) + n, __float_as_int(v));
            }
        } else {
#pragma unroll
            for (int j = 0; j < 4; j++) {
                const int n = n0 + tx * 4 + j;
                if (n < N) {
                    const float v = acc[i][j] * scale + (bias ? bias[n] : 0.f);
                    C[(size_t)m * N + n] = v;
                }
            }
        }
    }
}

// ---------------------------------------------------------------------------
// Merged CSR build: (A) row buckets over (batch,node) for segment ownership,
// (B) class CSR over (class,dst) + packed {src, coef}. One block per batch.
// ---------------------------------------------------------------------------
__global__ void csr_all(const int* __restrict__ ent_indices,
                        int* __restrict__ rptr, int* __restrict__ rlist,
                        const int* __restrict__ edge_index, const int* __restrict__ edge_attr,
                        float* __restrict__ degf, int* __restrict__ csr_ptr,
                        int2* __restrict__ csr_sc)
{
    __shared__ int cnt[NC * NNODE];
    __shared__ float dinvl[NC * NNODE];
    __shared__ int wsums[4];
    const int b = blockIdx.x;
    const int tid = threadIdx.x;

    // ---- phase A: row buckets ----
    const int* idx = ent_indices + (size_t)b * S_;
    for (int i = tid; i < NNODE; i += 256) cnt[i] = 0;
    __syncthreads();
    for (int r = tid; r < S_; r += 256) atomicAdd(&cnt[idx[r]], 1);
    __syncthreads();
    exscan_lds(cnt, NNODE, tid, wsums);
    __syncthreads();
    for (int i = tid; i < NNODE; i += 256) rptr[b * (NNODE + 1) + i] = cnt[i];
    if (tid == 0) rptr[b * (NNODE + 1) + NNODE] = S_;
    __syncthreads();
    for (int r = tid; r < S_; r += 256) {
        const int pos = atomicAdd(&cnt[idx[r]], 1);
        rlist[(size_t)b * S_ + pos] = r;
    }
    __syncthreads();

    // ---- phase B: class CSR ----
    const int* src = edge_index + (size_t)b * 2 * E_;
    const int* dst = src + E_;
    const int* attr = edge_attr + (size_t)b * E_;
    for (int i = tid; i < NC * NNODE; i += 256) cnt[i] = 0;
    __syncthreads();
    for (int e = tid; e < E_; e += 256) atomicAdd(&cnt[attr[e] * NNODE + dst[e]], 1);
    __syncthreads();
    for (int i = tid; i < NC * NNODE; i += 256) {
        const float d = (float)cnt[i] + 1.0f;
        degf[(size_t)b * NC * NNODE + i] = d;
        dinvl[i] = rsqrtf(d);
    }
    __syncthreads();
    exscan_lds(cnt, NC * NNODE, tid, wsums);
    __syncthreads();
    for (int i = tid; i < NC * NNODE; i += 256) csr_ptr[(size_t)b * NC * NNODE + i] = cnt[i];
    __syncthreads();
    for (int e = tid; e < E_; e += 256) {
        const int a = attr[e], d = dst[e], s = src[e];
        const int pos = atomicAdd(&cnt[a * NNODE + d], 1);
        const float cf = dinvl[a * NNODE + s] * dinvl[a * NNODE + d];
        csr_sc[(size_t)b * E_ + pos] = make_int2(s, __float_as_int(cf));
    }
}

// ---------------------------------------------------------------------------
// Fused segment-max (bf16 redC) + x0 build. One block owns one (batch,node):
// no atomics. x0b row = [label 16 | relu(max+bias) 512 | pad 16] bf16, pitch 544.
// ---------------------------------------------------------------------------
__global__ __launch_bounds__(256)
void segmax_x0(const u16* __restrict__ redC, const int* __restrict__ rptr,
               const int* __restrict__ rlist, const float* __restrict__ b_red,
               const int* __restrict__ ent_labels, const float* __restrict__ tbl,
               u16* __restrict__ x0b)
{
    const int bn = blockIdx.x;           // b*NNODE + n
    const int b = bn / NNODE, n = bn % NNODE;
    const int tid = threadIdx.x;
    const int c0 = tid * 2;              // two adjacent bf16 cols per thread
    const int start = rptr[b * (NNODE + 1) + n];
    const int end   = (n == 0) ? start : rptr[b * (NNODE + 1) + n + 1];
    float m0 = -INFINITY, m1 = -INFINITY;
    const int* rl = rlist + (size_t)b * S_;
    int nr = (start < end) ? rl[start] : 0;
    for (int i = start; i < end; i++) {
        const int r = nr;
        if (i + 1 < end) nr = rl[i + 1];          // prefetch: break dependent chain
        const u16* row = redC + ((size_t)b * S_ + r) * H_;
        const unsigned v = *(const unsigned*)(row + c0);
        m0 = fmaxf(m0, b2f_lo(v & 0xffffu));
        m1 = fmaxf(m1, b2f_hi(v));
    }
    float h0, h1;
    if (n == 0) { h0 = 0.f; h1 = 0.f; }
    else {
        h0 = fmaxf(m0 + b_red[c0], 0.f);
        h1 = fmaxf(m1 + b_red[c0 + 1], 0.f);
    }
    u16* orow = x0b + (size_t)bn * KPAD;
    *(unsigned*)(orow + 16 + c0) = (unsigned)f2b(h0) | ((unsigned)f2b(h1) << 16);
    if (tid < 16) {
        float v;
        if (n == 0) v = tbl[tid];
        else {
            const int lab = ent_labels[b * (NNODE - 1) + (n - 1)];
            v = (lab != 0) ? tbl[lab * 16 + tid] : 0.f;
        }
        orow[tid] = f2b(v);
    } else if (tid < 32) {
        orow[512 + tid] = 0;             // K-pad cols 528..543
    }
}

template<int OUTB>
__global__ void build_x0(const float* __restrict__ seg, const int* __restrict__ ent_labels,
                         const float* __restrict__ tbl, float* __restrict__ x0f,
                         u16* __restrict__ x0b)
{
    const int bn = blockIdx.x;
    const int b = bn / NNODE, n = bn % NNODE;
    const int CMAX = OUTB ? KPAD : D_;
    for (int col = threadIdx.x; col < CMAX; col += blockDim.x) {
        float v;
        if (col >= D_) {
            v = 0.f;
        } else if (col < 16) {
            if (n == 0) v = tbl[col];
            else {
                const int lab = ent_labels[b * (NNODE - 1) + (n - 1)];
                v = (lab != 0) ? tbl[lab * 16 + col] : 0.f;
            }
        } else {
            v = (n == 0) ? 0.f : seg[(((size_t)b * NNODE + n) << 9) + (col - 16)];
        }
        if (OUTB) x0b[(size_t)bn * KPAD + col] = f2b(v);
        else      x0f[(size_t)bn * D_ + col] = v;
    }
}

// ---------------------------------------------------------------------------
// GCN gather on bf16 h planes (pitch KPAD, z-strided). Paired-u32 loads.
// OUT: 0 bf16 write (pitch KPAD, zero K-pad); 2 f32 write (pitch D_, z-strided)
// ---------------------------------------------------------------------------
template<int OUT>
__global__ __launch_bounds__(256)
void gcn_gather(const u16* __restrict__ h, size_t hstride,
                const float* __restrict__ degf,
                const int* __restrict__ csr_ptr, const int2* __restrict__ csr_sc,
                const float* __restrict__ bias_base, size_t bias_stride,
                float* __restrict__ outf, u16* __restrict__ outb, size_t ostride)
{
    const int bn = blockIdx.x;
    const int cls = blockIdx.y;
    const int b = bn / NNODE, n = bn % NNODE;
    const int tid = threadIdx.x;
    const int base = b * NC * NNODE + cls * NNODE + n;
    const float d = degf[base];
    const int start = csr_ptr[base];
    const int cnt = (int)d - 1;
    const float inv = 1.0f / d;
    const u16* hp = h + cls * hstride;
    const float* bias = bias_base + cls * bias_stride;
    const u16* hrow = hp + (size_t)bn * KPAD;
    const int c0 = 2 * tid;                 // cols 0..511
    const int c1 = 512 + 2 * tid;           // cols 512..527 (tid < 8)
    const bool hi = (tid < 8);
    unsigned v = *(const unsigned*)(hrow + c0);
    float a0 = b2f_lo(v & 0xffffu) * inv + bias[c0];
    float a1 = b2f_hi(v) * inv + bias[c0 + 1];
    float a2 = 0.f, a3 = 0.f;
    if (hi) {
        v = *(const unsigned*)(hrow + c1);
        a2 = b2f_lo(v & 0xffffu) * inv + bias[c1];
        a3 = b2f_hi(v) * inv + bias[c1 + 1];
    }
    const int2* scp = csr_sc + (size_t)b * E_ + start;
    int2 sc = (cnt > 0) ? scp[0] : make_int2(0, 0);
    for (int i = 0; i < cnt; i++) {
        const int2 cur = sc;
        if (i + 1 < cnt) sc = scp[i + 1];     // prefetch: break dependent chain
        const float cf = __int_as_float(cur.y);
        const u16* hs = hp + ((size_t)b * NNODE + cur.x) * KPAD;
        v = *(const unsigned*)(hs + c0);
        a0 += cf * b2f_lo(v & 0xffffu);
        a1 += cf * b2f_hi(v);
        if (hi) {
            v = *(const unsigned*)(hs + c1);
            a2 += cf * b2f_lo(v & 0xffffu);
            a3 += cf * b2f_hi(v);
        }
    }
    if (OUT == 0) {
        u16* orow = outb + cls * ostride + (size_t)bn * KPAD;
        *(unsigned*)(orow + c0) = (unsigned)f2b(a0) | ((unsigned)f2b(a1) << 16);
        if (hi) *(unsigned*)(orow + c1) = (unsigned)f2b(a2) | ((unsigned)f2b(a3) << 16);
        if (tid >= 8 && tid < 16)                   // zero K-pad cols 528..543
            *(unsigned*)(orow + 528 + 2 * (tid - 8)) = 0;
    } else {
        float* orow = outf + cls * ostride + (size_t)bn * D_;
        orow[c0] = a0; orow[c0 + 1] = a1;
        if (hi) { orow[c1] = a2; orow[c1 + 1] = a3; }
    }
}

// fallback-only gather on f32 h planes. OUT: 1 fp32 +=; 2 fp32 =
template<int OUT>
__global__ __launch_bounds__(256)
void gcn_gather_f32(const float* __restrict__ h, size_t hstride,
                    const float* __restrict__ degf,
                    const int* __restrict__ csr_ptr, const int2* __restrict__ csr_sc,
                    const float* __restrict__ bias_base, size_t bias_stride,
                    float* __restrict__ outf, int cls0)
{
    const int bn = blockIdx.x;
    const int cls = cls0 + blockIdx.y;
    const int b = bn / NNODE, n = bn % NNODE;
    const int tid = threadIdx.x;
    const int base = b * NC * NNODE + cls * NNODE + n;
    const float d = degf[base];
    const int start = csr_ptr[base];
    const int cnt = (int)d - 1;
    const float inv = 1.0f / d;
    const float* hp = h + blockIdx.y * hstride;
    const float* bias = bias_base + cls * bias_stride;
    const float* hrow = hp + (size_t)bn * D_;
    const int c0 = tid, c1 = tid + 256, c2 = tid + 512;
    float a0 = hrow[c0] * inv + bias[c0];
    float a1 = hrow[c1] * inv + bias[c1];
    float a2 = (c2 < D_) ? hrow[c2] * inv + bias[c2] : 0.f;
    const int2* scp = csr_sc + (size_t)b * E_ + start;
    for (int i = 0; i < cnt; i++) {
        const int2 sc = scp[i];
        const float cf = __int_as_float(sc.y);
        const float* hs = hp + ((size_t)b * NNODE + sc.x) * D_;
        a0 += cf * hs[c0];
        a1 += cf * hs[c1];
        if (c2 < D_) a2 += cf * hs[c2];
    }
    if (OUT == 1) {
        float* orow = outf + (size_t)bn * D_;
        orow[c0] += a0; orow[c1] += a1; if (c2 < D_) orow[c2] += a2;
    } else {
        float* orow = outf + (size_t)bn * D_;
        orow[c0] = a0; orow[c1] = a1; if (c2 < D_) orow[c2] = a2;
    }
}

__global__ void rowdot3(const float* __restrict__ x, const float* __restrict__ w,
                        float* __restrict__ out)
{
    const int row = blockIdx.x;
    const int lane = threadIdx.x;
    float a0 = 0.f, a1 = 0.f, a2 = 0.f;
    for (int d = lane; d < D_; d += 64) {
        const float xv = x[(size_t)row * D_ + d];
        a0 += xv * w[d * 3 + 0];
        a1 += xv * w[d * 3 + 1];
        a2 += xv * w[d * 3 + 2];
    }
#pragma unroll
    for (int off = 32; off > 0; off >>= 1) {
        a0 += __shfl_down(a0, off, 64);
        a1 += __shfl_down(a1, off, 64);
        a2 += __shfl_down(a2, off, 64);
    }
    if (lane == 0) {
        out[(size_t)row * 3 + 0] = a0;
        out[(size_t)row * 3 + 1] = a1;
        out[(size_t)row * 3 + 2] = a2;
    }
}

// one kernel: Whw = W_head@W_out, Wtw = W_tail@W_out, bias6 = {b_head,b_tail}@W_out
__global__ void prep_heads(const float* __restrict__ W_head, const float* __restrict__ W_tail,
                           const float* __restrict__ b_head, const float* __restrict__ b_tail,
                           const float* __restrict__ W_out,
                           float* __restrict__ Whw, float* __restrict__ Wtw,
                           float* __restrict__ bias6)
{
    const int r = blockIdx.x;            // 0..2*D_+1
    const int lane = threadIdx.x;
    const float* x; float* o;
    if (r < D_)            { x = W_head + (size_t)r * D_;        o = Whw + (size_t)r * 3; }
    else if (r < 2 * D_)   { x = W_tail + (size_t)(r - D_) * D_; o = Wtw + (size_t)(r - D_) * 3; }
    else if (r == 2 * D_)  { x = b_head;                         o = bias6; }
    else                   { x = b_tail;                         o = bias6 + 3; }
    float a0 = 0.f, a1 = 0.f, a2 = 0.f;
    for (int d = lane; d < D_; d += 64) {
        const float xv = x[d];
        a0 += xv * W_out[d * 3 + 0];
        a1 += xv * W_out[d * 3 + 1];
        a2 += xv * W_out[d * 3 + 2];
    }
#pragma unroll
    for (int off = 32; off > 0; off >>= 1) {
        a0 += __shfl_down(a0, off, 64);
        a1 += __shfl_down(a1, off, 64);
        a2 += __shfl_down(a2, off, 64);
    }
    if (lane == 0) { o[0] = a0; o[1] = a1; o[2] = a2; }
}

// hw/tw from 3 class planes: x = (p0+p1+p2)/3; 4 rows per block (1 wave each)
__global__ __launch_bounds__(256)
void rowdot6(const float* __restrict__ x3, size_t zstride,
             const float* __restrict__ Whw, const float* __restrict__ Wtw,
             const float* __restrict__ bias6,
             float* __restrict__ hw, float* __restrict__ tw)
{
    const int row = blockIdx.x * 4 + (threadIdx.x >> 6);
    const int lane = threadIdx.x & 63;
    const float* p0 = x3 + (size_t)row * D_;
    const float* p1 = p0 + zstride;
    const float* p2 = p1 + zstride;
    float h0 = 0.f, h1 = 0.f, h2 = 0.f, t0 = 0.f, t1 = 0.f, t2 = 0.f;
    for (int d = lane; d < D_; d += 64) {
        const float xv = (p0[d] + p1[d] + p2[d]) * (1.f / 3.f);
        h0 += xv * Whw[d * 3 + 0]; h1 += xv * Whw[d * 3 + 1]; h2 += xv * Whw[d * 3 + 2];
        t0 += xv * Wtw[d * 3 + 0]; t1 += xv * Wtw[d * 3 + 1]; t2 += xv * Wtw[d * 3 + 2];
    }
#pragma unroll
    for (int off = 32; off > 0; off >>= 1) {
        h0 += __shfl_down(h0, off, 64); h1 += __shfl_down(h1, off, 64); h2 += __shfl_down(h2, off, 64);
        t0 += __shfl_down(t0, off, 64); t1 += __shfl_down(t1, off, 64); t2 += __shfl_down(t2, off, 64);
    }
    if (lane == 0) {
        hw[(size_t)row * 3 + 0] = h0 + bias6[0];
        hw[(size_t)row * 3 + 1] = h1 + bias6[1];
        hw[(size_t)row * 3 + 2] = h2 + bias6[2];
        tw[(size_t)row * 3 + 0] = t0 + bias6[3];
        tw[(size_t)row * 3 + 1] = t1 + bias6[4];
        tw[(size_t)row * 3 + 2] = t2 + bias6[5];
    }
}

__global__ __launch_bounds__(256)
void final_logits(const float* __restrict__ hw, const float* __restrict__ tw,
                  const int* __restrict__ cands, const float* __restrict__ b_out,
                  float* __restrict__ out)
{
    const int bi = blockIdx.x;
    const int b = bi / NNODE;
    const int j = threadIdx.x;
    const float h0 = hw[bi * 3 + 0], h1 = hw[bi * 3 + 1], h2 = hw[bi * 3 + 2];
    const int tj = b * NNODE + 1 + j;
    const float t0 = tw[tj * 3 + 0], t1 = tw[tj * 3 + 1], t2 = tw[tj * 3 + 2];
    const float m = (cands[(size_t)bi * NNODE + 1 + j] != 0) ? 1.f : 0.f;
    const float bo0 = b_out[0], bo1 = b_out[1], bo2 = b_out[2];
    const size_t o = ((size_t)bi * 256 + j) * 3;
    out[o + 0] = (h0 + t0) * m + bo0;
    out[o + 1] = (h1 + t1) * m + bo1;
    out[o + 2] = (h2 + t2) * m + bo2;
}

extern "C" void kernel_launch(void* const* d_in, const int* in_sizes, int n_in,
                              void* d_out, int out_size, void* d_ws, size_t ws_size,
                              hipStream_t stream)
{
    const float* emb       = (const float*)d_in[0];
    const int* ent_indices = (const int*)d_in[1];
    const int* ent_labels  = (const int*)d_in[2];
    const int* edge_index  = (const int*)d_in[3];
    const int* edge_attr   = (const int*)d_in[4];
    const int* cands       = (const int*)d_in[5];
    const float* W_red     = (const float*)d_in[6];
    const float* b_red     = (const float*)d_in[7];
    const float* tbl       = (const float*)d_in[8];
    const float* W_gcn     = (const float*)d_in[9];
    const float* b_gcn     = (const float*)d_in[10];
    const float* W_head    = (const float*)d_in[11];
    const float* b_head    = (const float*)d_in[12];
    const float* W_tail    = (const float*)d_in[13];
    const float* b_tail    = (const float*)d_in[14];
    const float* W_out     = (const float*)d_in[15];
    const float* b_out     = (const float*)d_in[16];

    char* ws = (char*)d_ws;
    size_t off = 0;
    auto alloc = [&](size_t nbytes) -> char* {
        char* p = ws + off; off = (off + nbytes + 255) & ~(size_t)255; return p;
    };
    const size_t ROWB  = (size_t)NROW * D_ * sizeof(float);
    const size_t RD    = (size_t)NROW * D_;         // f32 plane stride (pitch 528)
    const size_t RD2   = (size_t)NROW * KPAD;       // bf16 plane stride (pitch 544)
    const size_t WGZ   = (size_t)2 * D_ * KPAD;     // wgcnT z-stride (2 layers)

    // region R0: emb_bf (phase 1), then hbB[3 bf16 planes] + x1b[3 bf16 planes]
    char* R0      = alloc((size_t)B_ * S_ * ETR_ * sizeof(u16)); // 50.3 MB
    u16*  emb_bf  = (u16*)R0;
    u16*  hbB     = (u16*)R0;                                    // [3][NROW][544] bf16 = 13.4 MB
    u16*  x1b     = (u16*)(R0 + (size_t)16 * 1024 * 1024);       // [3][NROW][544] bf16 = 13.4 MB
    // region R1: redC bf16 (phase 1), then result3 [3][NROW][528] f32 (epilogue)
    char* R1      = alloc((size_t)B_ * S_ * H_ * sizeof(u16));   // 33.6 MB
    u16*  redC    = (u16*)R1;
    float* result3 = (float*)R1;                                 // 26.1 MB fits
    int*  rptr    = (int*)alloc((size_t)B_ * (NNODE + 1) * 4);
    int*  rlist   = (int*)alloc((size_t)B_ * S_ * 4);
    u16*  x0b     = (u16*)alloc((size_t)NROW * KPAD * sizeof(u16));
    u16*  wredT   = (u16*)alloc((size_t)H_ * ETR_ * sizeof(u16));    // [512][768]
    u16*  wgcnT   = (u16*)alloc((size_t)NC * WGZ * sizeof(u16));     // [3][2][528][544]
    float* Whw    = (float*)alloc((size_t)D_ * 3 * 4);
    float* Wtw    = (float*)alloc((size_t)D_ * 3 * 4);
    float* bias6  = (float*)alloc(6 * 4);
    float* degf   = (float*)alloc((size_t)B_ * NC * NNODE * 4);
    float* hwp    = (float*)alloc((size_t)NROW * 3 * 4);
    float* twp    = (float*)alloc((size_t)NROW * 3 * 4);
    int* csr_ptr  = (int*)alloc((size_t)B_ * NC * NNODE * 4);
    int2* csr_sc  = (int2*)alloc((size_t)B_ * E_ * 8);
    const bool fast = (ws_size >= off);

    if (fast) {
        const int n4e = (B_ * S_ * ETR_) / 4;
        cvt_bf16<<<(n4e + 255) / 256, 256, 0, stream>>>(emb, emb_bf, n4e);
        transpose_cvt<<<dim3(16, 24, 1), 256, 0, stream>>>(W_red, wredT, ETR_, H_, 0, 0, ETR_);
        // wgcnT K-pad (cols 528..543) written as zeros by transpose_cvt itself
        transpose_cvt<<<dim3(17, 17, 6), 256, 0, stream>>>(W_gcn, wgcnT, D_, D_, DD, (size_t)D_ * KPAD, KPAD);

        // fused head/tail weights (single launch)
        prep_heads<<<2 * D_ + 2, 64, 0, stream>>>(W_head, W_tail, b_head, b_tail, W_out,
                                                  Whw, Wtw, bias6);

        // merged row-bucket CSR + class CSR (one launch, parallel scans)
        csr_all<<<B_, 256, 0, stream>>>(ent_indices, rptr, rlist,
                                        edge_index, edge_attr, degf, csr_ptr, csr_sc);

        // 1) reduction GEMM (counted-vmcnt depth-2 pipeline) -> bf16 redC
        gemm_mfma<1, 1><<<dim3(H_ / BN, (B_ * S_) / BM, 1), 256, 0, stream>>>(
            emb_bf, wredT, nullptr, 0, redC, B_ * S_, H_, ETR_, 1.f, 0, 0, 0, H_);
        // 2) fused exclusive-owner segment max + x0 build (zero atomics)
        segmax_x0<<<B_ * NNODE, 256, 0, stream>>>(redC, rptr, rlist, b_red,
                                                  ent_labels, tbl, x0b);

        // 3) GCN layer 1: GEMM (shared x0 A-plane) -> bf16 h; gather on bf16 h
        dim3 gmm((D_ + BN - 1) / BN, (NROW + BM - 1) / BM, NC);   // 5 x 33 x 3
        gemm_mfma<0, 1><<<gmm, 256, 0, stream>>>(
            x0b, wgcnT, nullptr, 0, hbB, NROW, D_, KPAD, 1.f, 0, WGZ, RD2, KPAD);
        gcn_gather<0><<<dim3(NROW, NC), 256, 0, stream>>>(
            hbB, RD2, degf, csr_ptr, csr_sc, b_gcn, (size_t)2 * D_,
            nullptr, x1b, RD2);
        // 4) GCN layer 2
        gemm_mfma<0, 1><<<gmm, 256, 0, stream>>>(
            x1b, wgcnT + (size_t)D_ * KPAD, nullptr, 0, hbB, NROW, D_, KPAD, 1.f,
            RD2, WGZ, RD2, KPAD);
        gcn_gather<2><<<dim3(NROW, NC), 256, 0, stream>>>(
            hbB, RD2, degf, csr_ptr, csr_sc, b_gcn + D_, (size_t)2 * D_,
            result3, nullptr, RD);

        // 5) fused epilogue: sum 3 planes inside rowdot6 (no atomics, no memset)
        rowdot6<<<NROW / 4, 256, 0, stream>>>(result3, RD, Whw, Wtw, bias6, hwp, twp);
        final_logits<<<NROW, 256, 0, stream>>>(hwp, twp, cands, b_out, (float*)d_out);
        return;
    }

    // -------- fallback: proven fp32 pipeline --------
    off = 0;
    float* bufA = (float*)alloc(ROWB);
    float* bufB = (float*)alloc(ROWB);
    float* bufC = (float*)alloc(ROWB);
    float* bufD = (float*)alloc(ROWB);
    degf = (float*)alloc((size_t)B_ * NC * NNODE * 4);
    hwp  = (float*)alloc((size_t)NROW * 3 * 4);
    twp  = (float*)alloc((size_t)NROW * 3 * 4);
    csr_ptr = (int*)alloc((size_t)B_ * NC * NNODE * 4);
    csr_sc  = (int2*)alloc((size_t)B_ * E_ * 8);
    int* rptr2  = (int*)alloc((size_t)B_ * (NNODE + 1) * 4);
    int* rlist2 = (int*)alloc((size_t)B_ * S_ * 4);

    hipMemsetAsync(bufA, 0, (size_t)B_ * NNODE * H_ * 4, stream);
    hipMemsetAsync(bufD, 0, ROWB, stream);
    gemm64<1><<<dim3(H_ / 64, (B_ * S_) / 64), 256, 0, stream>>>(
        emb, W_red, b_red, nullptr, B_ * S_, H_, ETR_, 1.f, ent_indices, bufA);
    build_x0<0><<<NROW, 256, 0, stream>>>(bufA, ent_labels, tbl, bufB, nullptr);
    csr_all<<<B_, 256, 0, stream>>>(ent_indices, rptr2, rlist2,
                                    edge_index, edge_attr, degf, csr_ptr, csr_sc);
    dim3 gridG((D_ + 63) / 64, (NROW + 63) / 64);
    for (int c = 0; c < NC; c++) {
        gemm64<0><<<gridG, 256, 0, stream>>>(bufB, W_gcn + (size_t)(c * 2 + 0) * DD,
            nullptr, bufA, NROW, D_, D_, 1.f, nullptr, nullptr);
        gcn_gather_f32<2><<<dim3(NROW, 1), 256, 0, stream>>>(bufA, 0, degf, csr_ptr, csr_sc,
            b_gcn, (size_t)2 * D_, bufC, c);
        gemm64<0><<<gridG, 256, 0, stream>>>(bufC, W_gcn + (size_t)(c * 2 + 1) * DD,
            nullptr, bufA, NROW, D_, D_, 1.f, nullptr, nullptr);
        gcn_gather_f32<1><<<dim3(NROW, 1), 256, 0, stream>>>(bufA, 0, degf, csr_ptr, csr_sc,
            b_gcn + D_, (size_t)2 * D_, bufD, c);
    }
    gemm64<0><<<gridG, 256, 0, stream>>>(bufD, W_head, b_head, bufB,
        NROW, D_, D_, 1.f / 3.f, nullptr, nullptr);
    gemm64<0><<<gridG, 256, 0, stream>>>(bufD, W_tail, b_tail, bufC,
        NROW, D_, D_, 1.f / 3.f, nullptr, nullptr);
    rowdot3<<<NROW, 64, 0, stream>>>(bufB, W_out, hwp);
    rowdot3<<<NROW, 64, 0, stream>>>(bufC, W_out, twp);
    final_logits<<<NROW, 256, 0, stream>>>(hwp, twp, cands, b_out, (float*)d_out);
}

// Round 14
// 381.683 us; speedup vs baseline: 1.1342x; 1.0381x over previous
//
#include <hip/hip_runtime.h>
#include <hip/hip_bf16.h>

typedef unsigned short u16;
typedef __attribute__((ext_vector_type(8))) short short8;
typedef __attribute__((ext_vector_type(4))) float floatx4;

#define B_ 16
#define S_ 2048
#define NNODE 257
#define E_ 4096
#define ETR_ 768
#define H_ 512
#define D_ 528
#define KPAD 544          // K padded to a BK multiple for MFMA GEMMs
#define NC 3
#define NROW (B_*NNODE)   // 4112
#define DD (D_*D_)

#define BM 256            // 8-wave tall tile (512 threads)
#define BN 128
#define BK 32
#define BUFU 12288        // u16 per LDS buffer: A 256x32 + B 128x32

__device__ inline u16 f2b(float x) {
    __hip_bfloat16 h = __float2bfloat16(x);
    return *(u16*)&h;
}
__device__ inline float b2f(u16 u) {
    return __uint_as_float(((unsigned)u) << 16);
}
__device__ inline float b2f_lo(unsigned v) { return __uint_as_float(v << 16); }
__device__ inline float b2f_hi(unsigned v) { return __uint_as_float(v & 0xffff0000u); }

// async global->LDS, 16B per lane (m97 structure). LDS dest must be linear:
// HW writes wave-uniform base + lane*16.
__device__ inline void gll16(const u16* g, u16* l) {
    __builtin_amdgcn_global_load_lds(
        (const __attribute__((address_space(1))) void*)g,
        (__attribute__((address_space(3))) void*)l,
        16, 0, 0);
}

__device__ inline int clampi(int v, int hi) { return v < hi ? v : hi; }

// 256-thread in-place EXCLUSIVE prefix sum of cnt[0..n), n <= 1024.
__device__ inline void exscan_lds(int* cnt, int n, int tid, int* wsums)
{
    const int lane = tid & 63, wave = tid >> 6;
    int v[4];
    int ts = 0;
#pragma unroll
    for (int j = 0; j < 4; j++) {
        const int i = tid * 4 + j;
        v[j] = (i < n) ? cnt[i] : 0;
        ts += v[j];
    }
    int inc = ts;
#pragma unroll
    for (int off = 1; off < 64; off <<= 1) {
        const int o = __shfl_up(inc, off, 64);
        if (lane >= off) inc += o;
    }
    if (lane == 63) wsums[wave] = inc;
    __syncthreads();
    int woff = 0;
#pragma unroll
    for (int w = 0; w < 4; w++) if (w < wave) woff += wsums[w];
    int run = woff + inc - ts;           // exclusive base of this thread's chunk
#pragma unroll
    for (int j = 0; j < 4; j++) {
        const int i = tid * 4 + j;
        if (i < n) { const int c = v[j]; cnt[i] = run; run += c; }
    }
}

__global__ void cvt_bf16(const float* __restrict__ in, u16* __restrict__ out, int n4)
{
    const int i = blockIdx.x * 256 + threadIdx.x;
    if (i < n4) {
        const float4 f = ((const float4*)in)[i];
        ushort4 o;
        o.x = f2b(f.x); o.y = f2b(f.y); o.z = f2b(f.z); o.w = f2b(f.w);
        ((ushort4*)out)[i] = o;
    }
}

// in f32 [R][C] (z-batched) -> out bf16 [C][R] with out pitch opitch (>= R).
// Pad columns r in [R, opitch) are written as 0 (grid-y must cover opitch).
__global__ void transpose_cvt(const float* __restrict__ in, u16* __restrict__ out,
                              int R, int Cc, size_t instride, size_t outstride,
                              int opitch)
{
    __shared__ float t[32][33];
    const int z = blockIdx.z;
    const int tx = threadIdx.x & 31, ty = threadIdx.x >> 5;  // 32 x 8
    const int c0 = blockIdx.x * 32, r0 = blockIdx.y * 32;
    const float* ip = in + z * instride;
    u16* op = out + z * outstride;
#pragma unroll
    for (int i = 0; i < 4; i++) {
        const int r = r0 + ty + i * 8, c = c0 + tx;
        if (r < R && c < Cc) t[ty + i * 8][tx] = ip[(size_t)r * Cc + c];
    }
    __syncthreads();
#pragma unroll
    for (int i = 0; i < 4; i++) {
        const int c = c0 + ty + i * 8, r = r0 + tx;
        if (c < Cc && r < opitch) {
            const u16 val = (r < R) ? f2b(t[tx][ty + i * 8]) : (u16)0;
            op[(size_t)c * opitch + r] = val;
        }
    }
}

// ---------------------------------------------------------------------------
// bf16 MFMA GEMM: 256x128 tile (8 waves, 512 threads), BK=32, TRIPLE-BUFFERED
// 72KB LDS, prefetch-depth-2 with COUNTED vmcnt: the main loop never drains
// vmcnt to 0 -- loads get ~2 iterations to land. 3 gll16 calls per K-step
// (A: 2x8KB, B: 1x8KB -- B panel shared by 256 A-rows).
// Per iter: vmcnt(3) -> s_barrier -> ds_read -> lgkmcnt(0)+sched_barrier ->
// s_barrier (WAR) -> issue stage(t+2) -> MFMA.
// LDS chunk-swizzle (source-permuted, read-XOR). A[M][K], Wt[N][K] bf16
// (row pitch K, K % 32 == 0), z-batched. SWZ: XCD remap (gridDim.x==4).
// OB16: bf16 output. Epilogue: C = acc*scale + bias[z][n].
// ---------------------------------------------------------------------------
template<int SWZ, int OB16>
__global__ __launch_bounds__(512)
void gemm_mfma(const u16* __restrict__ A, const u16* __restrict__ Wt,
               const float* __restrict__ bias_base, size_t bias_stride,
               void* __restrict__ Cv, int M, int N, int K, float scale,
               size_t astride, size_t wstride, size_t cstride, int cpitch)
{
    __shared__ u16 SS[3 * BUFU];   // 72KB: buf b at b*BUFU (A @0, B @8192 within buf)
    const int tid = threadIdx.x;
    const int wave = tid >> 6, lane = tid & 63;
    const int quad = lane >> 4, l16 = lane & 15;
    const int z = blockIdx.z;
    int bx = blockIdx.x, by = blockIdx.y;
    if (SWZ) {   // gridDim.x==4: keep the 4 col-blocks of a row-block on one XCD
        const int lin = blockIdx.x + (blockIdx.y << 2);
        bx = (lin >> 3) & 3;
        by = (lin & 7) + ((lin >> 5) << 3);
    }
    const int m0 = by * BM, n0 = bx * BN;

    floatx4 acc[2][8];
#pragma unroll
    for (int t = 0; t < 2; t++)
#pragma unroll
        for (int u = 0; u < 8; u++)
#pragma unroll
            for (int r = 0; r < 4; r++) acc[t][u][r] = 0.f;

    // staging map: LDS slot (tid&3) of row (tid>>2) receives GLOBAL chunk
    // (tid&3) ^ ((row>>1)&3) -- the bank-conflict swizzle, applied at the source.
    const int srow = tid >> 2;                                   // 0..127
    const int scol = (((tid & 3) ^ ((srow >> 1) & 3))) * 8;      // swizzled chunk
    const u16* aP0 = A + z * astride + (size_t)clampi(m0 + srow,       M - 1) * K + scol;
    const u16* aP1 = A + z * astride + (size_t)clampi(m0 + 128 + srow, M - 1) * K + scol;
    const u16* bP0 = Wt + z * wstride + (size_t)clampi(n0 + srow,      N - 1) * K + scol;
    const int lsw = wave * 512;       // per-wave offset within a gll16 region (u16)

    // read-side swizzle term: all fragment rows reduce to sw = (l16>>1)&3
    const int sw8 = ((l16 >> 1) & 3) * 8;

    const int nt = K / BK;

    // prologue: stage tiles 0 and 1 (3 loads each)
    {
        u16* d = &SS[lsw];
        gll16(aP0, d); gll16(aP1, d + 4096); gll16(bP0, d + 8192);
    }
    if (nt > 1) {
        u16* d = &SS[BUFU + lsw];
        gll16(aP0 + BK, d); gll16(aP1 + BK, d + 4096); gll16(bP0 + BK, d + 8192);
    }

    int cur = 0;
    for (int t = 0; t < nt; ++t) {
        // 1) ensure buf[cur] landed: only the newest 3 loads (tile t+1) may
        //    remain outstanding. When staging has stopped, drain fully.
        if (t + 1 < nt) asm volatile("s_waitcnt vmcnt(3)" ::: "memory");
        else            asm volatile("s_waitcnt vmcnt(0)" ::: "memory");
        __builtin_amdgcn_s_barrier();

        // 2) read fragments from buf[cur]
        const u16* Sb = &SS[cur * BUFU];
        short8 af[2], bfv[8];
        af[0] = *(const short8*)&Sb[(wave * 32 + l16) * 32 + ((quad * 8) ^ sw8)];
        af[1] = *(const short8*)&Sb[(wave * 32 + 16 + l16) * 32 + ((quad * 8) ^ sw8)];
#pragma unroll
        for (int u = 0; u < 8; u++)
            bfv[u] = *(const short8*)&Sb[8192 + (u * 16 + l16) * 32 + ((quad * 8) ^ sw8)];
        asm volatile("s_waitcnt lgkmcnt(0)" ::: "memory");
        __builtin_amdgcn_sched_barrier(0);
        __builtin_amdgcn_s_barrier();      // all waves' reads done -> safe to overwrite

        // 3) issue stage for tile t+2 (overwrites buffer read at iter t-1)
        if (t + 2 < nt) {
            int s = cur + 2; if (s >= 3) s -= 3;
            const int kn = (t + 2) * BK;
            u16* d = &SS[s * BUFU + lsw];
            gll16(aP0 + kn, d); gll16(aP1 + kn, d + 4096); gll16(bP0 + kn, d + 8192);
        }

        // 4) MFMA (register-only; loads fly underneath)
#pragma unroll
        for (int t2 = 0; t2 < 2; t2++)
#pragma unroll
            for (int u = 0; u < 8; u++)
                acc[t2][u] = __builtin_amdgcn_mfma_f32_16x16x32_bf16(af[t2], bfv[u], acc[t2][u], 0, 0, 0);

        cur = (cur == 2) ? 0 : cur + 1;
    }

    const float* bias = bias_base ? (bias_base + z * bias_stride) : nullptr;
#pragma unroll
    for (int t = 0; t < 2; t++) {
#pragma unroll
        for (int r = 0; r < 4; r++) {
            const int m = m0 + wave * 32 + t * 16 + quad * 4 + r;
            if (m >= M) continue;
#pragma unroll
            for (int u = 0; u < 8; u++) {
                const int n = n0 + u * 16 + l16;
                if (n < N) {
                    const float v = acc[t][u][r] * scale + (bias ? bias[n] : 0.f);
                    if (OB16) {
                        u16* Cb = (u16*)Cv;
                        Cb[z * cstride + (size_t)m * cpitch + n] = f2b(v);
                    } else {
                        float* Cf = (float*)Cv;
                        Cf[z * cstride + (size_t)m * cpitch + n] = v;
                    }
                }
            }
        }
    }
}

// ---------------------------------------------------------------------------
// fp32 64x64 GEMM (fallback path only)
// ---------------------------------------------------------------------------
template<int MODE>
__global__ __launch_bounds__(256)
void gemm64(const float* __restrict__ A, const float* __restrict__ W,
            const float* __restrict__ bias, float* __restrict__ C,
            int M, int N, int K, float scale,
            const int* __restrict__ segidx, float* __restrict__ segout)
{
    __shared__ float Asl[16][68];
    __shared__ float Bsl[16][64];
    const int tid = threadIdx.x;
    const int tx = tid & 15, ty = tid >> 4;
    const int m0 = blockIdx.y * 64, n0 = blockIdx.x * 64;
    const int arow = tid >> 2, acol = (tid & 3) * 4;
    const int brow = tid >> 4, bcol = (tid & 15) * 4;

    float acc[4][4];
#pragma unroll
    for (int i = 0; i < 4; i++)
#pragma unroll
        for (int j = 0; j < 4; j++) acc[i][j] = 0.f;

    for (int kk = 0; kk < K; kk += 16) {
        float4 av = make_float4(0.f, 0.f, 0.f, 0.f);
        if (m0 + arow < M) av = *(const float4*)(A + (size_t)(m0 + arow) * K + kk + acol);
        Asl[acol + 0][arow] = av.x; Asl[acol + 1][arow] = av.y;
        Asl[acol + 2][arow] = av.z; Asl[acol + 3][arow] = av.w;
        float4 bv = make_float4(0.f, 0.f, 0.f, 0.f);
        if (n0 + bcol < N) bv = *(const float4*)(W + (size_t)(kk + brow) * N + n0 + bcol);
        *(float4*)&Bsl[brow][bcol] = bv;
        __syncthreads();
#pragma unroll
        for (int k = 0; k < 16; k++) {
            const float4 a = *(const float4*)&Asl[k][ty * 4];
            const float4 b = *(const float4*)&Bsl[k][tx * 4];
            const float af[4] = { a.x, a.y, a.z, a.w };
            const float bfv[4] = { b.x, b.y, b.z, b.w };
#pragma unroll
            for (int i = 0; i < 4; i++)
#pragma unroll
                for (int j = 0; j < 4; j++) acc[i][j] += af[i] * bfv[j];
        }
        __syncthreads();
    }

#pragma unroll
    for (int i = 0; i < 4; i++) {
        const int m = m0 + ty * 4 + i;
        if (m >= M) continue;
        if (MODE == 1) {
            const int bb = m >> 11;
            const int idx = segidx[m];
            float* const srow = segout + (((size_t)bb * NNODE + idx) << 9);
#pragma unroll
            for (int j = 0; j < 4; j++) {
                const int n = n0 + tx * 4 + j;
                const float v = acc[i][j] + (bias ? bias[n] : 0.f);
                atomicMax(((int*)srow) + n, __float_as_int(v));
            }
        } else {
#pragma unroll
            for (int j = 0; j < 4; j++) {
                const int n = n0 + tx * 4 + j;
                if (n < N) {
                    const float v = acc[i][j] * scale + (bias ? bias[n] : 0.f);
                    C[(size_t)m * N + n] = v;
                }
            }
        }
    }
}

// ---------------------------------------------------------------------------
// Merged CSR build: (A) row buckets over (batch,node) for segment ownership,
// (B) class CSR over (class,dst) + packed {src, coef}. One block per batch.
// ---------------------------------------------------------------------------
__global__ void csr_all(const int* __restrict__ ent_indices,
                        int* __restrict__ rptr, int* __restrict__ rlist,
                        const int* __restrict__ edge_index, const int* __restrict__ edge_attr,
                        float* __restrict__ degf, int* __restrict__ csr_ptr,
                        int2* __restrict__ csr_sc)
{
    __shared__ int cnt[NC * NNODE];
    __shared__ float dinvl[NC * NNODE];
    __shared__ int wsums[4];
    const int b = blockIdx.x;
    const int tid = threadIdx.x;

    // ---- phase A: row buckets ----
    const int* idx = ent_indices + (size_t)b * S_;
    for (int i = tid; i < NNODE; i += 256) cnt[i] = 0;
    __syncthreads();
    for (int r = tid; r < S_; r += 256) atomicAdd(&cnt[idx[r]], 1);
    __syncthreads();
    exscan_lds(cnt, NNODE, tid, wsums);
    __syncthreads();
    for (int i = tid; i < NNODE; i += 256) rptr[b * (NNODE + 1) + i] = cnt[i];
    if (tid == 0) rptr[b * (NNODE + 1) + NNODE] = S_;
    __syncthreads();
    for (int r = tid; r < S_; r += 256) {
        const int pos = atomicAdd(&cnt[idx[r]], 1);
        rlist[(size_t)b * S_ + pos] = r;
    }
    __syncthreads();

    // ---- phase B: class CSR ----
    const int* src = edge_index + (size_t)b * 2 * E_;
    const int* dst = src + E_;
    const int* attr = edge_attr + (size_t)b * E_;
    for (int i = tid; i < NC * NNODE; i += 256) cnt[i] = 0;
    __syncthreads();
    for (int e = tid; e < E_; e += 256) atomicAdd(&cnt[attr[e] * NNODE + dst[e]], 1);
    __syncthreads();
    for (int i = tid; i < NC * NNODE; i += 256) {
        const float d = (float)cnt[i] + 1.0f;
        degf[(size_t)b * NC * NNODE + i] = d;
        dinvl[i] = rsqrtf(d);
    }
    __syncthreads();
    exscan_lds(cnt, NC * NNODE, tid, wsums);
    __syncthreads();
    for (int i = tid; i < NC * NNODE; i += 256) csr_ptr[(size_t)b * NC * NNODE + i] = cnt[i];
    __syncthreads();
    for (int e = tid; e < E_; e += 256) {
        const int a = attr[e], d = dst[e], s = src[e];
        const int pos = atomicAdd(&cnt[a * NNODE + d], 1);
        const float cf = dinvl[a * NNODE + s] * dinvl[a * NNODE + d];
        csr_sc[(size_t)b * E_ + pos] = make_int2(s, __float_as_int(cf));
    }
}

// ---------------------------------------------------------------------------
// Fused segment-max (bf16 redC) + x0 build. One block owns one (batch,node):
// no atomics. x0b row = [label 16 | relu(max+bias) 512 | pad 16] bf16, pitch 544.
// ---------------------------------------------------------------------------
__global__ __launch_bounds__(256)
void segmax_x0(const u16* __restrict__ redC, const int* __restrict__ rptr,
               const int* __restrict__ rlist, const float* __restrict__ b_red,
               const int* __restrict__ ent_labels, const float* __restrict__ tbl,
               u16* __restrict__ x0b)
{
    const int bn = blockIdx.x;           // b*NNODE + n
    const int b = bn / NNODE, n = bn % NNODE;
    const int tid = threadIdx.x;
    const int c0 = tid * 2;              // two adjacent bf16 cols per thread
    const int start = rptr[b * (NNODE + 1) + n];
    const int end   = (n == 0) ? start : rptr[b * (NNODE + 1) + n + 1];
    float m0 = -INFINITY, m1 = -INFINITY;
    const int* rl = rlist + (size_t)b * S_;
    int nr = (start < end) ? rl[start] : 0;
    for (int i = start; i < end; i++) {
        const int r = nr;
        if (i + 1 < end) nr = rl[i + 1];          // prefetch: break dependent chain
        const u16* row = redC + ((size_t)b * S_ + r) * H_;
        const unsigned v = *(const unsigned*)(row + c0);
        m0 = fmaxf(m0, b2f_lo(v & 0xffffu));
        m1 = fmaxf(m1, b2f_hi(v));
    }
    float h0, h1;
    if (n == 0) { h0 = 0.f; h1 = 0.f; }
    else {
        h0 = fmaxf(m0 + b_red[c0], 0.f);
        h1 = fmaxf(m1 + b_red[c0 + 1], 0.f);
    }
    u16* orow = x0b + (size_t)bn * KPAD;
    *(unsigned*)(orow + 16 + c0) = (unsigned)f2b(h0) | ((unsigned)f2b(h1) << 16);
    if (tid < 16) {
        float v;
        if (n == 0) v = tbl[tid];
        else {
            const int lab = ent_labels[b * (NNODE - 1) + (n - 1)];
            v = (lab != 0) ? tbl[lab * 16 + tid] : 0.f;
        }
        orow[tid] = f2b(v);
    } else if (tid < 32) {
        orow[512 + tid] = 0;             // K-pad cols 528..543
    }
}

template<int OUTB>
__global__ void build_x0(const float* __restrict__ seg, const int* __restrict__ ent_labels,
                         const float* __restrict__ tbl, float* __restrict__ x0f,
                         u16* __restrict__ x0b)
{
    const int bn = blockIdx.x;
    const int b = bn / NNODE, n = bn % NNODE;
    const int CMAX = OUTB ? KPAD : D_;
    for (int col = threadIdx.x; col < CMAX; col += blockDim.x) {
        float v;
        if (col >= D_) {
            v = 0.f;
        } else if (col < 16) {
            if (n == 0) v = tbl[col];
            else {
                const int lab = ent_labels[b * (NNODE - 1) + (n - 1)];
                v = (lab != 0) ? tbl[lab * 16 + col] : 0.f;
            }
        } else {
            v = (n == 0) ? 0.f : seg[(((size_t)b * NNODE + n) << 9) + (col - 16)];
        }
        if (OUTB) x0b[(size_t)bn * KPAD + col] = f2b(v);
        else      x0f[(size_t)bn * D_ + col] = v;
    }
}

// ---------------------------------------------------------------------------
// GCN gather on bf16 h planes (pitch KPAD, z-strided). Paired-u32 loads.
// OUT: 0 bf16 write (pitch KPAD, zero K-pad); 2 f32 write (pitch D_, z-strided)
// ---------------------------------------------------------------------------
template<int OUT>
__global__ __launch_bounds__(256)
void gcn_gather(const u16* __restrict__ h, size_t hstride,
                const float* __restrict__ degf,
                const int* __restrict__ csr_ptr, const int2* __restrict__ csr_sc,
                const float* __restrict__ bias_base, size_t bias_stride,
                float* __restrict__ outf, u16* __restrict__ outb, size_t ostride)
{
    const int bn = blockIdx.x;
    const int cls = blockIdx.y;
    const int b = bn / NNODE, n = bn % NNODE;
    const int tid = threadIdx.x;
    const int base = b * NC * NNODE + cls * NNODE + n;
    const float d = degf[base];
    const int start = csr_ptr[base];
    const int cnt = (int)d - 1;
    const float inv = 1.0f / d;
    const u16* hp = h + cls * hstride;
    const float* bias = bias_base + cls * bias_stride;
    const u16* hrow = hp + (size_t)bn * KPAD;
    const int c0 = 2 * tid;                 // cols 0..511
    const int c1 = 512 + 2 * tid;           // cols 512..527 (tid < 8)
    const bool hi = (tid < 8);
    unsigned v = *(const unsigned*)(hrow + c0);
    float a0 = b2f_lo(v & 0xffffu) * inv + bias[c0];
    float a1 = b2f_hi(v) * inv + bias[c0 + 1];
    float a2 = 0.f, a3 = 0.f;
    if (hi) {
        v = *(const unsigned*)(hrow + c1);
        a2 = b2f_lo(v & 0xffffu) * inv + bias[c1];
        a3 = b2f_hi(v) * inv + bias[c1 + 1];
    }
    const int2* scp = csr_sc + (size_t)b * E_ + start;
    int2 sc = (cnt > 0) ? scp[0] : make_int2(0, 0);
    for (int i = 0; i < cnt; i++) {
        const int2 cur = sc;
        if (i + 1 < cnt) sc = scp[i + 1];     // prefetch: break dependent chain
        const float cf = __int_as_float(cur.y);
        const u16* hs = hp + ((size_t)b * NNODE + cur.x) * KPAD;
        v = *(const unsigned*)(hs + c0);
        a0 += cf * b2f_lo(v & 0xffffu);
        a1 += cf * b2f_hi(v);
        if (hi) {
            v = *(const unsigned*)(hs + c1);
            a2 += cf * b2f_lo(v & 0xffffu);
            a3 += cf * b2f_hi(v);
        }
    }
    if (OUT == 0) {
        u16* orow = outb + cls * ostride + (size_t)bn * KPAD;
        *(unsigned*)(orow + c0) = (unsigned)f2b(a0) | ((unsigned)f2b(a1) << 16);
        if (hi) *(unsigned*)(orow + c1) = (unsigned)f2b(a2) | ((unsigned)f2b(a3) << 16);
        if (tid >= 8 && tid < 16)                   // zero K-pad cols 528..543
            *(unsigned*)(orow + 528 + 2 * (tid - 8)) = 0;
    } else {
        float* orow = outf + cls * ostride + (size_t)bn * D_;
        orow[c0] = a0; orow[c0 + 1] = a1;
        if (hi) { orow[c1] = a2; orow[c1 + 1] = a3; }
    }
}

// fallback-only gather on f32 h planes. OUT: 1 fp32 +=; 2 fp32 =
template<int OUT>
__global__ __launch_bounds__(256)
void gcn_gather_f32(const float* __restrict__ h, size_t hstride,
                    const float* __restrict__ degf,
                    const int* __restrict__ csr_ptr, const int2* __restrict__ csr_sc,
                    const float* __restrict__ bias_base, size_t bias_stride,
                    float* __restrict__ outf, int cls0)
{
    const int bn = blockIdx.x;
    const int cls = cls0 + blockIdx.y;
    const int b = bn / NNODE, n = bn % NNODE;
    const int tid = threadIdx.x;
    const int base = b * NC * NNODE + cls * NNODE + n;
    const float d = degf[base];
    const int start = csr_ptr[base];
    const int cnt = (int)d - 1;
    const float inv = 1.0f / d;
    const float* hp = h + blockIdx.y * hstride;
    const float* bias = bias_base + cls * bias_stride;
    const float* hrow = hp + (size_t)bn * D_;
    const int c0 = tid, c1 = tid + 256, c2 = tid + 512;
    float a0 = hrow[c0] * inv + bias[c0];
    float a1 = hrow[c1] * inv + bias[c1];
    float a2 = (c2 < D_) ? hrow[c2] * inv + bias[c2] : 0.f;
    const int2* scp = csr_sc + (size_t)b * E_ + start;
    for (int i = 0; i < cnt; i++) {
        const int2 sc = scp[i];
        const float cf = __int_as_float(sc.y);
        const float* hs = hp + ((size_t)b * NNODE + sc.x) * D_;
        a0 += cf * hs[c0];
        a1 += cf * hs[c1];
        if (c2 < D_) a2 += cf * hs[c2];
    }
    if (OUT == 1) {
        float* orow = outf + (size_t)bn * D_;
        orow[c0] += a0; orow[c1] += a1; if (c2 < D_) orow[c2] += a2;
    } else {
        float* orow = outf + (size_t)bn * D_;
        orow[c0] = a0; orow[c1] = a1; if (c2 < D_) orow[c2] = a2;
    }
}

__global__ void rowdot3(const float* __restrict__ x, const float* __restrict__ w,
                        float* __restrict__ out)
{
    const int row = blockIdx.x;
    const int lane = threadIdx.x;
    float a0 = 0.f, a1 = 0.f, a2 = 0.f;
    for (int d = lane; d < D_; d += 64) {
        const float xv = x[(size_t)row * D_ + d];
        a0 += xv * w[d * 3 + 0];
        a1 += xv * w[d * 3 + 1];
        a2 += xv * w[d * 3 + 2];
    }
#pragma unroll
    for (int off = 32; off > 0; off >>= 1) {
        a0 += __shfl_down(a0, off, 64);
        a1 += __shfl_down(a1, off, 64);
        a2 += __shfl_down(a2, off, 64);
    }
    if (lane == 0) {
        out[(size_t)row * 3 + 0] = a0;
        out[(size_t)row * 3 + 1] = a1;
        out[(size_t)row * 3 + 2] = a2;
    }
}

// one kernel: Whw = W_head@W_out, Wtw = W_tail@W_out, bias6 = {b_head,b_tail}@W_out
__global__ void prep_heads(const float* __restrict__ W_head, const float* __restrict__ W_tail,
                           const float* __restrict__ b_head, const float* __restrict__ b_tail,
                           const float* __restrict__ W_out,
                           float* __restrict__ Whw, float* __restrict__ Wtw,
                           float* __restrict__ bias6)
{
    const int r = blockIdx.x;            // 0..2*D_+1
    const int lane = threadIdx.x;
    const float* x; float* o;
    if (r < D_)            { x = W_head + (size_t)r * D_;        o = Whw + (size_t)r * 3; }
    else if (r < 2 * D_)   { x = W_tail + (size_t)(r - D_) * D_; o = Wtw + (size_t)(r - D_) * 3; }
    else if (r == 2 * D_)  { x = b_head;                         o = bias6; }
    else                   { x = b_tail;                         o = bias6 + 3; }
    float a0 = 0.f, a1 = 0.f, a2 = 0.f;
    for (int d = lane; d < D_; d += 64) {
        const float xv = x[d];
        a0 += xv * W_out[d * 3 + 0];
        a1 += xv * W_out[d * 3 + 1];
        a2 += xv * W_out[d * 3 + 2];
    }
#pragma unroll
    for (int off = 32; off > 0; off >>= 1) {
        a0 += __shfl_down(a0, off, 64);
        a1 += __shfl_down(a1, off, 64);
        a2 += __shfl_down(a2, off, 64);
    }
    if (lane == 0) { o[0] = a0; o[1] = a1; o[2] = a2; }
}

// hw/tw from 3 class planes: x = (p0+p1+p2)/3; 4 rows per block (1 wave each)
__global__ __launch_bounds__(256)
void rowdot6(const float* __restrict__ x3, size_t zstride,
             const float* __restrict__ Whw, const float* __restrict__ Wtw,
             const float* __restrict__ bias6,
             float* __restrict__ hw, float* __restrict__ tw)
{
    const int row = blockIdx.x * 4 + (threadIdx.x >> 6);
    const int lane = threadIdx.x & 63;
    const float* p0 = x3 + (size_t)row * D_;
    const float* p1 = p0 + zstride;
    const float* p2 = p1 + zstride;
    float h0 = 0.f, h1 = 0.f, h2 = 0.f, t0 = 0.f, t1 = 0.f, t2 = 0.f;
    for (int d = lane; d < D_; d += 64) {
        const float xv = (p0[d] + p1[d] + p2[d]) * (1.f / 3.f);
        h0 += xv * Whw[d * 3 + 0]; h1 += xv * Whw[d * 3 + 1]; h2 += xv * Whw[d * 3 + 2];
        t0 += xv * Wtw[d * 3 + 0]; t1 += xv * Wtw[d * 3 + 1]; t2 += xv * Wtw[d * 3 + 2];
    }
#pragma unroll
    for (int off = 32; off > 0; off >>= 1) {
        h0 += __shfl_down(h0, off, 64); h1 += __shfl_down(h1, off, 64); h2 += __shfl_down(h2, off, 64);
        t0 += __shfl_down(t0, off, 64); t1 += __shfl_down(t1, off, 64); t2 += __shfl_down(t2, off, 64);
    }
    if (lane == 0) {
        hw[(size_t)row * 3 + 0] = h0 + bias6[0];
        hw[(size_t)row * 3 + 1] = h1 + bias6[1];
        hw[(size_t)row * 3 + 2] = h2 + bias6[2];
        tw[(size_t)row * 3 + 0] = t0 + bias6[3];
        tw[(size_t)row * 3 + 1] = t1 + bias6[4];
        tw[(size_t)row * 3 + 2] = t2 + bias6[5];
    }
}

__global__ __launch_bounds__(256)
void final_logits(const float* __restrict__ hw, const float* __restrict__ tw,
                  const int* __restrict__ cands, const float* __restrict__ b_out,
                  float* __restrict__ out)
{
    const int bi = blockIdx.x;
    const int b = bi / NNODE;
    const int j = threadIdx.x;
    const float h0 = hw[bi * 3 + 0], h1 = hw[bi * 3 + 1], h2 = hw[bi * 3 + 2];
    const int tj = b * NNODE + 1 + j;
    const float t0 = tw[tj * 3 + 0], t1 = tw[tj * 3 + 1], t2 = tw[tj * 3 + 2];
    const float m = (cands[(size_t)bi * NNODE + 1 + j] != 0) ? 1.f : 0.f;
    const float bo0 = b_out[0], bo1 = b_out[1], bo2 = b_out[2];
    const size_t o = ((size_t)bi * 256 + j) * 3;
    out[o + 0] = (h0 + t0) * m + bo0;
    out[o + 1] = (h1 + t1) * m + bo1;
    out[o + 2] = (h2 + t2) * m + bo2;
}

extern "C" void kernel_launch(void* const* d_in, const int* in_sizes, int n_in,
                              void* d_out, int out_size, void* d_ws, size_t ws_size,
                              hipStream_t stream)
{
    const float* emb       = (const float*)d_in[0];
    const int* ent_indices = (const int*)d_in[1];
    const int* ent_labels  = (const int*)d_in[2];
    const int* edge_index  = (const int*)d_in[3];
    const int* edge_attr   = (const int*)d_in[4];
    const int* cands       = (const int*)d_in[5];
    const float* W_red     = (const float*)d_in[6];
    const float* b_red     = (const float*)d_in[7];
    const float* tbl       = (const float*)d_in[8];
    const float* W_gcn     = (const float*)d_in[9];
    const float* b_gcn     = (const float*)d_in[10];
    const float* W_head    = (const float*)d_in[11];
    const float* b_head    = (const float*)d_in[12];
    const float* W_tail    = (const float*)d_in[13];
    const float* b_tail    = (const float*)d_in[14];
    const float* W_out     = (const float*)d_in[15];
    const float* b_out     = (const float*)d_in[16];

    char* ws = (char*)d_ws;
    size_t off = 0;
    auto alloc = [&](size_t nbytes) -> char* {
        char* p = ws + off; off = (off + nbytes + 255) & ~(size_t)255; return p;
    };
    const size_t ROWB  = (size_t)NROW * D_ * sizeof(float);
    const size_t RD    = (size_t)NROW * D_;         // f32 plane stride (pitch 528)
    const size_t RD2   = (size_t)NROW * KPAD;       // bf16 plane stride (pitch 544)
    const size_t WGZ   = (size_t)2 * D_ * KPAD;     // wgcnT z-stride (2 layers)

    // region R0: emb_bf (phase 1), then hbB[3 bf16 planes] + x1b[3 bf16 planes]
    char* R0      = alloc((size_t)B_ * S_ * ETR_ * sizeof(u16)); // 50.3 MB
    u16*  emb_bf  = (u16*)R0;
    u16*  hbB     = (u16*)R0;                                    // [3][NROW][544] bf16 = 13.4 MB
    u16*  x1b     = (u16*)(R0 + (size_t)16 * 1024 * 1024);       // [3][NROW][544] bf16 = 13.4 MB
    // region R1: redC bf16 (phase 1), then result3 [3][NROW][528] f32 (epilogue)
    char* R1      = alloc((size_t)B_ * S_ * H_ * sizeof(u16));   // 33.6 MB
    u16*  redC    = (u16*)R1;
    float* result3 = (float*)R1;                                 // 26.1 MB fits
    int*  rptr    = (int*)alloc((size_t)B_ * (NNODE + 1) * 4);
    int*  rlist   = (int*)alloc((size_t)B_ * S_ * 4);
    u16*  x0b     = (u16*)alloc((size_t)NROW * KPAD * sizeof(u16));
    u16*  wredT   = (u16*)alloc((size_t)H_ * ETR_ * sizeof(u16));    // [512][768]
    u16*  wgcnT   = (u16*)alloc((size_t)NC * WGZ * sizeof(u16));     // [3][2][528][544]
    float* Whw    = (float*)alloc((size_t)D_ * 3 * 4);
    float* Wtw    = (float*)alloc((size_t)D_ * 3 * 4);
    float* bias6  = (float*)alloc(6 * 4);
    float* degf   = (float*)alloc((size_t)B_ * NC * NNODE * 4);
    float* hwp    = (float*)alloc((size_t)NROW * 3 * 4);
    float* twp    = (float*)alloc((size_t)NROW * 3 * 4);
    int* csr_ptr  = (int*)alloc((size_t)B_ * NC * NNODE * 4);
    int2* csr_sc  = (int2*)alloc((size_t)B_ * E_ * 8);
    const bool fast = (ws_size >= off);

    if (fast) {
        const int n4e = (B_ * S_ * ETR_) / 4;
        cvt_bf16<<<(n4e + 255) / 256, 256, 0, stream>>>(emb, emb_bf, n4e);
        transpose_cvt<<<dim3(16, 24, 1), 256, 0, stream>>>(W_red, wredT, ETR_, H_, 0, 0, ETR_);
        // wgcnT K-pad (cols 528..543) written as zeros by transpose_cvt itself
        transpose_cvt<<<dim3(17, 17, 6), 256, 0, stream>>>(W_gcn, wgcnT, D_, D_, DD, (size_t)D_ * KPAD, KPAD);

        // fused head/tail weights (single launch)
        prep_heads<<<2 * D_ + 2, 64, 0, stream>>>(W_head, W_tail, b_head, b_tail, W_out,
                                                  Whw, Wtw, bias6);

        // merged row-bucket CSR + class CSR (one launch, parallel scans)
        csr_all<<<B_, 256, 0, stream>>>(ent_indices, rptr, rlist,
                                        edge_index, edge_attr, degf, csr_ptr, csr_sc);

        // 1) reduction GEMM (256x128 tile, counted-vmcnt depth-2) -> bf16 redC
        gemm_mfma<1, 1><<<dim3(H_ / BN, (B_ * S_) / BM, 1), 512, 0, stream>>>(
            emb_bf, wredT, nullptr, 0, redC, B_ * S_, H_, ETR_, 1.f, 0, 0, 0, H_);
        // 2) fused exclusive-owner segment max + x0 build (zero atomics)
        segmax_x0<<<B_ * NNODE, 256, 0, stream>>>(redC, rptr, rlist, b_red,
                                                  ent_labels, tbl, x0b);

        // 3) GCN layer 1: GEMM (shared x0 A-plane) -> bf16 h; gather on bf16 h
        dim3 gmm((D_ + BN - 1) / BN, (NROW + BM - 1) / BM, NC);   // 5 x 17 x 3
        gemm_mfma<0, 1><<<gmm, 512, 0, stream>>>(
            x0b, wgcnT, nullptr, 0, hbB, NROW, D_, KPAD, 1.f, 0, WGZ, RD2, KPAD);
        gcn_gather<0><<<dim3(NROW, NC), 256, 0, stream>>>(
            hbB, RD2, degf, csr_ptr, csr_sc, b_gcn, (size_t)2 * D_,
            nullptr, x1b, RD2);
        // 4) GCN layer 2
        gemm_mfma<0, 1><<<gmm, 512, 0, stream>>>(
            x1b, wgcnT + (size_t)D_ * KPAD, nullptr, 0, hbB, NROW, D_, KPAD, 1.f,
            RD2, WGZ, RD2, KPAD);
        gcn_gather<2><<<dim3(NROW, NC), 256, 0, stream>>>(
            hbB, RD2, degf, csr_ptr, csr_sc, b_gcn + D_, (size_t)2 * D_,
            result3, nullptr, RD);

        // 5) fused epilogue: sum 3 planes inside rowdot6 (no atomics, no memset)
        rowdot6<<<NROW / 4, 256, 0, stream>>>(result3, RD, Whw, Wtw, bias6, hwp, twp);
        final_logits<<<NROW, 256, 0, stream>>>(hwp, twp, cands, b_out, (float*)d_out);
        return;
    }

    // -------- fallback: proven fp32 pipeline --------
    off = 0;
    float* bufA = (float*)alloc(ROWB);
    float* bufB = (float*)alloc(ROWB);
    float* bufC = (float*)alloc(ROWB);
    float* bufD = (float*)alloc(ROWB);
    degf = (float*)alloc((size_t)B_ * NC * NNODE * 4);
    hwp  = (float*)alloc((size_t)NROW * 3 * 4);
    twp  = (float*)alloc((size_t)NROW * 3 * 4);
    csr_ptr = (int*)alloc((size_t)B_ * NC * NNODE * 4);
    csr_sc  = (int2*)alloc((size_t)B_ * E_ * 8);
    int* rptr2  = (int*)alloc((size_t)B_ * (NNODE + 1) * 4);
    int* rlist2 = (int*)alloc((size_t)B_ * S_ * 4);

    hipMemsetAsync(bufA, 0, (size_t)B_ * NNODE * H_ * 4, stream);
    hipMemsetAsync(bufD, 0, ROWB, stream);
    gemm64<1><<<dim3(H_ / 64, (B_ * S_) / 64), 256, 0, stream>>>(
        emb, W_red, b_red, nullptr, B_ * S_, H_, ETR_, 1.f, ent_indices, bufA);
    build_x0<0><<<NROW, 256, 0, stream>>>(bufA, ent_labels, tbl, bufB, nullptr);
    csr_all<<<B_, 256, 0, stream>>>(ent_indices, rptr2, rlist2,
                                    edge_index, edge_attr, degf, csr_ptr, csr_sc);
    dim3 gridG((D_ + 63) / 64, (NROW + 63) / 64);
    for (int c = 0; c < NC; c++) {
        gemm64<0><<<gridG, 256, 0, stream>>>(bufB, W_gcn + (size_t)(c * 2 + 0) * DD,
            nullptr, bufA, NROW, D_, D_, 1.f, nullptr, nullptr);
        gcn_gather_f32<2><<<dim3(NROW, 1), 256, 0, stream>>>(bufA, 0, degf, csr_ptr, csr_sc,
            b_gcn, (size_t)2 * D_, bufC, c);
        gemm64<0><<<gridG, 256, 0, stream>>>(bufC, W_gcn + (size_t)(c * 2 + 1) * DD,
            nullptr, bufA, NROW, D_, D_, 1.f, nullptr, nullptr);
        gcn_gather_f32<1><<<dim3(NROW, 1), 256, 0, stream>>>(bufA, 0, degf, csr_ptr, csr_sc,
            b_gcn + D_, (size_t)2 * D_, bufD, c);
    }
    gemm64<0><<<gridG, 256, 0, stream>>>(bufD, W_head, b_head, bufB,
        NROW, D_, D_, 1.f / 3.f, nullptr, nullptr);
    gemm64<0><<<gridG, 256, 0, stream>>>(bufD, W_tail, b_tail, bufC,
        NROW, D_, D_, 1.f / 3.f, nullptr, nullptr);
    rowdot3<<<NROW, 64, 0, stream>>>(bufB, W_out, hwp);
    rowdot3<<<NROW, 64, 0, stream>>>(bufC, W_out, twp);
    final_logits<<<NROW, 256, 0, stream>>>(hwp, twp, cands, b_out, (float*)d_out);
}